// Round 11
// baseline (366.149 us; speedup 1.0000x reference)
//
#include <hip/hip_runtime.h>

#define NPAR 384
#define NEPI 384
#define DD   256
#define NTAB 4096
#define SMAX 96.0f
#define SDELTA (SMAX / NTAB)
#define SINVD (NTAB / SMAX)

using bf16x8 = __bf16 __attribute__((ext_vector_type(8)));
using bf16x2 = __bf16 __attribute__((ext_vector_type(2)));
using f32x4  = float __attribute__((ext_vector_type(4)));

#if defined(__has_builtin)
#if __has_builtin(__builtin_amdgcn_cvt_pk_bf16_f32)
#define HAVE_PK_BF16 1
#endif
#endif

__device__ __forceinline__ float sigm(float x) { return 1.0f / (1.0f + __expf(-x)); }
__device__ __forceinline__ float silu(float x) { return x / (1.0f + __expf(-x)); }
__device__ __forceinline__ unsigned short f2bf(float f) {
  unsigned u = __float_as_uint(f);
  u += 0x7fffu + ((u >> 16) & 1u);
  return (unsigned short)(u >> 16);
}
__device__ __forceinline__ float bf2f(unsigned u16) {
  return __uint_as_float(u16 << 16);
}
__device__ __forceinline__ float bf2f_lo(unsigned w) {
  return __uint_as_float(w << 16);
}
__device__ __forceinline__ float bf2f_hi(unsigned w) {
  return __uint_as_float(w & 0xffff0000u);
}
__device__ __forceinline__ uint2 pack4(float a, float b, float c, float d) {
  uint2 r;
#ifdef HAVE_PK_BF16
  bf16x2 lo = __builtin_amdgcn_cvt_pk_bf16_f32(a, b);
  bf16x2 hi = __builtin_amdgcn_cvt_pk_bf16_f32(c, d);
  r.x = __builtin_bit_cast(unsigned, lo);
  r.y = __builtin_bit_cast(unsigned, hi);
#else
  r.x = (unsigned)f2bf(a) | ((unsigned)f2bf(b) << 16);
  r.y = (unsigned)f2bf(c) | ((unsigned)f2bf(d) << 16);
#endif
  return r;
}

// ---------------- fused precompute kernel ----------------
// block ranges: [0,512) fold Mr/Ma ; [512,520) cvec ; [520,584) gvec ;
// [584,2120) mm_rows4 (Hpl/Her/P1/P2)

__global__ void prep_kernel(
    const float* __restrict__ H, const float* __restrict__ wl,
    const float* __restrict__ wr, const float* __restrict__ int_w1,
    const float* __restrict__ res_w2, const float* __restrict__ atom_w2,
    const float* __restrict__ res_b2, const float* __restrict__ atom_b2,
    const float* __restrict__ int_b1, const float* __restrict__ simw,
    const float* __restrict__ wq_b, const float* __restrict__ wk_w,
    float* __restrict__ Hpl, float* __restrict__ Her,
    float* __restrict__ P1, float* __restrict__ P2,
    float* __restrict__ MrF, float* __restrict__ MaF,
    float* __restrict__ cvec, float* __restrict__ gv) {
  const int b = blockIdx.x, t = threadIdx.x;
  if (b < 512) {
    const int i = b & 255;
    const bool isMa = b >= 256;
    const float wmix = 1.0f / (1.0f + __expf(-simw[0]));
    const float sc = isMa ? (1.0f - wmix) : wmix;
    const float* W2 = isMa ? atom_w2 : res_w2;
    float acc = 0.f;
#pragma unroll 8
    for (int k = 0; k < 256; ++k)
      acc += W2[i * 256 + k] * int_w1[(512 + k) * 256 + t];
    (isMa ? MaF : MrF)[i * 256 + t] = acc * sc;
  } else if (b < 520) {
    const int bb = b - 512;
    const float wmix = 1.0f / (1.0f + __expf(-simw[0]));
    float acc = (bb == 0) ? int_b1[t] : 0.f;
#pragma unroll
    for (int k = bb * 32; k < bb * 32 + 32; ++k) {
      float bm = wmix * res_b2[k] + (1.0f - wmix) * atom_b2[k];
      acc += bm * int_w1[(512 + k) * 256 + t];
    }
    atomicAdd(&cvec[t], acc);
  } else if (b < 584) {
    const int lane = t & 63, w = t >> 6;
    const int d = (b - 520) * 4 + w;
    float acc = 0.f;
#pragma unroll
    for (int i = 0; i < 4; ++i) {
      const int c = i * 64 + lane;
      acc += wk_w[d * 256 + c] * wq_b[c];
    }
    acc += __shfl_xor(acc, 1);
    acc += __shfl_xor(acc, 2);
    acc += __shfl_xor(acc, 4);
    acc += __shfl_xor(acc, 8);
    acc += __shfl_xor(acc, 16);
    acc += __shfl_xor(acc, 32);
    if (lane == 0) gv[d] = acc;
  } else {
    const int idx = b - 584;
    const int seg = idx / 384, r = idx % 384;
    const float* A;
    const float* B;
    float* C;
    switch (seg) {
      case 0:  A = H + r * 256;            B = wl;              C = Hpl + r * 256; break;
      case 1:  A = H + (NPAR + r) * 256;   B = wr;              C = Her + r * 256; break;
      case 2:  A = H + r * 256;            B = int_w1;          C = P1 + r * 256;  break;
      default: A = H + (NPAR + r) * 256;   B = int_w1 + 65536;  C = P2 + r * 256;  break;
    }
    float acc = 0.f;
#pragma unroll 8
    for (int k = 0; k < 256; ++k)
      acc += A[k] * B[k * 256 + t];
    C[t] = acc;
  }
}

// pack 6 [256,256] matrices into MFMA fragment order:
// wpack[m][((ks*16+tile)*64 + lane)*8 + j] = W[k][n], k = ks*32+(lane>>4)*8+j, n = tile*16+(lane&15)
// slots: 0=Mr 1=Ma 2=int_w2 3=wg 4=wq 5=wk^T (index-swapped read)
__global__ void pack_kernel(const float* __restrict__ MrF, const float* __restrict__ MaF,
                            const float* __restrict__ w2, const float* __restrict__ wg,
                            const float* __restrict__ wq, const float* __restrict__ wk,
                            unsigned short* __restrict__ wpack) {
  const int idx = blockIdx.x * 256 + threadIdx.x;
  const int m = idx >> 16;
  const int r = idx & 65535;
  const int chunk = r >> 9;
  const int lane = (r >> 3) & 63;
  const int j = r & 7;
  const int k = (chunk >> 4) * 32 + (lane >> 4) * 8 + j;
  const int n = (chunk & 15) * 16 + (lane & 15);
  const float* src;
  bool swap = false;
  switch (m) {
    case 0: src = MrF; break;
    case 1: src = MaF; break;
    case 2: src = w2; break;
    case 3: src = wg; break;
    case 4: src = wq; break;
    default: src = wk; swap = true; break;
  }
  wpack[idx] = f2bf(swap ? src[n * 256 + k] : src[k * 256 + n]);
}

// ---------------- shared GEMM helpers ----------------

__device__ __forceinline__ void zero_acc4(f32x4 (&acc)[4][4]) {
#pragma unroll
  for (int mt = 0; mt < 4; ++mt)
#pragma unroll
    for (int nt = 0; nt < 4; ++nt)
      acc[mt][nt] = (f32x4){0.f, 0.f, 0.f, 0.f};
}

// transposed-acc: mfma(Wfrag, ActFrag) -> acc^T[d][e]
// d = wv*64 + mt*16 + l4*4 + r, e = nt*16 + l15
__device__ __forceinline__ void gemm4(f32x4 (&acc)[4][4],
                                      const unsigned short* __restrict__ wp,
                                      const unsigned short* ub, int lane, int wv) {
  const int l15 = lane & 15, l4 = lane >> 4;
#pragma unroll
  for (int ks = 0; ks < 8; ++ks) {
    bf16x8 a[4];
#pragma unroll
    for (int mt = 0; mt < 4; ++mt)
      a[mt] = *reinterpret_cast<const bf16x8*>(wp + ((ks * 16 + wv * 4 + mt) * 64 + lane) * 8);
#pragma unroll
    for (int nt = 0; nt < 4; ++nt) {
      bf16x8 b = *reinterpret_cast<const bf16x8*>(ub + (nt * 16 + l15) * 264 + ks * 32 + l4 * 8);
#pragma unroll
      for (int mt = 0; mt < 4; ++mt)
        acc[mt][nt] = __builtin_amdgcn_mfma_f32_16x16x32_bf16(a[mt], b, acc[mt][nt], 0, 0, 0);
    }
  }
}

// fill ubuf[e][d] = silu(Sv[e]*w1[d] + b1[d])
__device__ __forceinline__ void fill_u(unsigned short* ub, const float* Sv,
                                       const float* __restrict__ w1,
                                       const float* __restrict__ b1, int t) {
  const int dg = t & 31, rb = t >> 5;
  const f32x4 w1a = *reinterpret_cast<const f32x4*>(&w1[dg * 8]);
  const f32x4 w1b = *reinterpret_cast<const f32x4*>(&w1[dg * 8 + 4]);
  const f32x4 b1a = *reinterpret_cast<const f32x4*>(&b1[dg * 8]);
  const f32x4 b1b = *reinterpret_cast<const f32x4*>(&b1[dg * 8 + 4]);
#pragma unroll
  for (int i = 0; i < 8; ++i) {
    const int e = rb + i * 8;
    const float s = Sv[e];
    uint2 lo = pack4(silu(fmaf(s, w1a[0], b1a[0])), silu(fmaf(s, w1a[1], b1a[1])),
                     silu(fmaf(s, w1a[2], b1a[2])), silu(fmaf(s, w1a[3], b1a[3])));
    uint2 hi = pack4(silu(fmaf(s, w1b[0], b1b[0])), silu(fmaf(s, w1b[1], b1b[1])),
                     silu(fmaf(s, w1b[2], b1b[2])), silu(fmaf(s, w1b[3], b1b[3])));
    uint4 pk = {lo.x, lo.y, hi.x, hi.y};
    *reinterpret_cast<uint4*>(&ub[e * 264 + dg * 8]) = pk;
  }
}

// ---------------- table build: tab[n][d] = F(n*SDELTA)[d] (wpack slots 0,1) ----------------

__global__ __launch_bounds__(256, 3) void tab_kernel(
    const float* __restrict__ res_w1, const float* __restrict__ res_b1,
    const float* __restrict__ atom_w1, const float* __restrict__ atom_b1,
    const unsigned short* __restrict__ wpack, unsigned short* __restrict__ tab) {
  __shared__ __align__(16) unsigned short ubuf[64 * 264];
  __shared__ float Sv[64];
  const int t = threadIdx.x, lane = t & 63, wv = t >> 6;
  const int l15 = lane & 15, l4 = lane >> 4;
  const int n0 = blockIdx.x * 64;
  if (t < 64) Sv[t] = (n0 + t) * SDELTA;
  __syncthreads();
  f32x4 acc[4][4];
  zero_acc4(acc);
  fill_u(ubuf, Sv, res_w1, res_b1, t);
  __syncthreads();
  gemm4(acc, wpack + 0 * 65536, ubuf, lane, wv);
  __syncthreads();
  fill_u(ubuf, Sv, atom_w1, atom_b1, t);
  __syncthreads();
  gemm4(acc, wpack + 1 * 65536, ubuf, lane, wv);
#pragma unroll
  for (int mt = 0; mt < 4; ++mt) {
    const int d = wv * 64 + mt * 16 + l4 * 4;
#pragma unroll
    for (int nt = 0; nt < 4; ++nt) {
      const int n = n0 + nt * 16 + l15;
      *reinterpret_cast<uint2*>(&tab[n * 256 + d]) =
          pack4(acc[mt][nt][0], acc[mt][nt][1], acc[mt][nt][2], acc[mt][nt][3]);
    }
  }
}

// ---------------- pairwise kernel (64-row tiles): table-interp h + 2 GEMMs ----------------

__global__ __launch_bounds__(256, 3) void pair_kernel(
    const float* __restrict__ Xg, const unsigned short* __restrict__ tab,
    const float* __restrict__ int_b2, const float* __restrict__ wg_b,
    const unsigned short* __restrict__ wpack, const float* __restrict__ cvec,
    const float* __restrict__ P1, const float* __restrict__ P2,
    const float* __restrict__ Hpl, const float* __restrict__ Her,
    float* __restrict__ ftri, unsigned short* __restrict__ Zsw) {
  __shared__ __align__(16) unsigned short ubuf[64 * 264];
  __shared__ float Sv[64];
  __shared__ float pc[DD];
  const int t = threadIdx.x, lane = t & 63, wv = t >> 6;
  const int l15 = lane & 15, l4 = lane >> 4;
  const int p = blockIdx.x / 6, cc = blockIdx.x % 6, e0 = cc * 64;
  const int d0 = wv * 64;

  if (t < 64) {
    const int e = e0 + t;
    float dx = Xg[p * 42 + 3] - Xg[(NPAR + e) * 42 + 3];
    float dy = Xg[p * 42 + 4] - Xg[(NPAR + e) * 42 + 4];
    float dz = Xg[p * 42 + 5] - Xg[(NPAR + e) * 42 + 5];
    Sv[t] = dx * dx + dy * dy + dz * dz;
  }
  pc[t] = P1[p * DD + t] + cvec[t];
  __syncthreads();

  // h-fill: h[e][d] = silu(lerp(tab, S[e])[d] + pc[d] + P2[e][d]) -> ubuf
  {
    const int dg = t & 31, rb = t >> 5;
    const f32x4 pca = *reinterpret_cast<const f32x4*>(&pc[dg * 8]);
    const f32x4 pcb = *reinterpret_cast<const f32x4*>(&pc[dg * 8 + 4]);
#pragma unroll
    for (int i = 0; i < 8; ++i) {
      const int e = rb + i * 8;
      float sv = Sv[e] * SINVD;
      int idx = (int)sv;
      idx = idx > (NTAB - 2) ? (NTAB - 2) : idx;
      const float fr = sv - (float)idx;
      const uint4 t0 = *reinterpret_cast<const uint4*>(&tab[idx * 256 + dg * 8]);
      const uint4 t1 = *reinterpret_cast<const uint4*>(&tab[(idx + 1) * 256 + dg * 8]);
      const f32x4 p2a = *reinterpret_cast<const f32x4*>(&P2[(e0 + e) * DD + dg * 8]);
      const f32x4 p2b = *reinterpret_cast<const f32x4*>(&P2[(e0 + e) * DD + dg * 8 + 4]);
      float z0 = bf2f_lo(t0.x), z1 = bf2f_hi(t0.x), z2 = bf2f_lo(t0.y), z3 = bf2f_hi(t0.y);
      float z4 = bf2f_lo(t0.z), z5 = bf2f_hi(t0.z), z6 = bf2f_lo(t0.w), z7 = bf2f_hi(t0.w);
      z0 = fmaf(fr, bf2f_lo(t1.x) - z0, z0) + pca[0] + p2a[0];
      z1 = fmaf(fr, bf2f_hi(t1.x) - z1, z1) + pca[1] + p2a[1];
      z2 = fmaf(fr, bf2f_lo(t1.y) - z2, z2) + pca[2] + p2a[2];
      z3 = fmaf(fr, bf2f_hi(t1.y) - z3, z3) + pca[3] + p2a[3];
      z4 = fmaf(fr, bf2f_lo(t1.z) - z4, z4) + pcb[0] + p2b[0];
      z5 = fmaf(fr, bf2f_hi(t1.z) - z5, z5) + pcb[1] + p2b[1];
      z6 = fmaf(fr, bf2f_lo(t1.w) - z6, z6) + pcb[2] + p2b[2];
      z7 = fmaf(fr, bf2f_hi(t1.w) - z7, z7) + pcb[3] + p2b[3];
      uint2 lo = pack4(silu(z0), silu(z1), silu(z2), silu(z3));
      uint2 hi = pack4(silu(z4), silu(z5), silu(z6), silu(z7));
      uint4 pk = {lo.x, lo.y, hi.x, hi.y};
      *reinterpret_cast<uint4*>(&ubuf[e * 264 + dg * 8]) = pk;
    }
  }
  __syncthreads();

  // Z = h @ int_w2 + int_b2 -> ubuf
  f32x4 acc[4][4];
  zero_acc4(acc);
  gemm4(acc, wpack + 2 * 65536, ubuf, lane, wv);
  __syncthreads();
#pragma unroll
  for (int mt = 0; mt < 4; ++mt) {
    const int d = d0 + mt * 16 + l4 * 4;
    const f32x4 bb = *reinterpret_cast<const f32x4*>(&int_b2[d]);
#pragma unroll
    for (int nt = 0; nt < 4; ++nt) {
      const int e = nt * 16 + l15;
      *reinterpret_cast<uint2*>(&ubuf[e * 264 + d]) =
          pack4(acc[mt][nt][0] + bb[0], acc[mt][nt][1] + bb[1],
                acc[mt][nt][2] + bb[2], acc[mt][nt][3] + bb[3]);
    }
  }
  __syncthreads();

  // swizzled MFMA-fragment-order store: grp = cc*4 + wv, e = grp*16 + l15
  {
    unsigned short* Zd = Zsw + (size_t)p * 98304 + (size_t)(cc * 4 + wv) * 4096 + lane * 8;
#pragma unroll
    for (int ks = 0; ks < 8; ++ks) {
      *reinterpret_cast<uint4*>(Zd + ks * 512) =
          *reinterpret_cast<const uint4*>(&ubuf[(wv * 16 + l15) * 264 + ks * 32 + l4 * 8]);
    }
  }

  // gate: f_tri[d] += Hpl[p][d] * sum_e sigm(Z@wg + b) * Her[e][d]
  zero_acc4(acc);
  gemm4(acc, wpack + 3 * 65536, ubuf, lane, wv);
#pragma unroll
  for (int mt = 0; mt < 4; ++mt) {
    const int d = d0 + mt * 16 + l4 * 4;
    const f32x4 bb = *reinterpret_cast<const f32x4*>(&wg_b[d]);
    const f32x4 hl = *reinterpret_cast<const f32x4*>(&Hpl[p * DD + d]);
    f32x4 fs = (f32x4){0.f, 0.f, 0.f, 0.f};
#pragma unroll
    for (int nt = 0; nt < 4; ++nt) {
      const int e = e0 + nt * 16 + l15;
      const f32x4 hr = *reinterpret_cast<const f32x4*>(&Her[e * DD + d]);
#pragma unroll
      for (int r = 0; r < 4; ++r)
        fs[r] += sigm(acc[mt][nt][r] + bb[r]) * hr[r];
    }
#pragma unroll
    for (int r = 0; r < 4; ++r) {
      float v = fs[r] * hl[r];
      v += __shfl_xor(v, 1);
      v += __shfl_xor(v, 2);
      v += __shfl_xor(v, 4);
      v += __shfl_xor(v, 8);
      if (l15 == 0) atomicAdd(&ftri[p * DD + d + r], v);
    }
  }
}

// ---------------- fused attention kernel: block = (p, 64-row chunk) ----------------
// Q = Zc@wq ; T = (Q@wk^T + gv)/16 ; S = T Z^T ; softmax col-sums cpart ;
// upart[d] = sum_f cpart[f] Z[f][d] -> atomicAdd ubuf[p].

__global__ __launch_bounds__(256, 3) void attn_kernel(
    const unsigned short* __restrict__ Zsw, const float* __restrict__ gv,
    const unsigned short* __restrict__ wpack, float* __restrict__ ubufg) {
  __shared__ __align__(16) unsigned short Tc[64 * 264];   // aliased by cpart/part later
  __shared__ float red[256];
  __shared__ float red2[256];
  const int t = threadIdx.x, lane = t & 63, wv = t >> 6;
  const int l15 = lane & 15, l4 = lane >> 4;
  const int xcd = blockIdx.x & 7, inner = blockIdx.x >> 3;
  const int p = (inner / 6) * 8 + xcd, c = inner % 6;
  const unsigned short* Zsp = Zsw + (size_t)p * 98304;
  const unsigned short* wq_p = wpack + 4 * 65536;
  const unsigned short* wkT_p = wpack + 5 * 65536;

  // Phase A: Q = Zc @ wq (b-frags double-buffered from Zsw) -> Tc
  {
    f32x4 ta[4][4];
    zero_acc4(ta);
    const unsigned short* Tb = Zsp + (size_t)(c * 4) * 4096 + lane * 8;
    bf16x8 bcur[4], bnxt[4];
#pragma unroll
    for (int nt = 0; nt < 4; ++nt)
      bcur[nt] = *reinterpret_cast<const bf16x8*>(Tb + nt * 4096);
#pragma unroll
    for (int ks = 0; ks < 8; ++ks) {
      if (ks < 7) {
#pragma unroll
        for (int nt = 0; nt < 4; ++nt)
          bnxt[nt] = *reinterpret_cast<const bf16x8*>(Tb + nt * 4096 + (ks + 1) * 512);
      }
      bf16x8 a[4];
#pragma unroll
      for (int mt = 0; mt < 4; ++mt)
        a[mt] = *reinterpret_cast<const bf16x8*>(wq_p + ((ks * 16 + wv * 4 + mt) * 64 + lane) * 8);
#pragma unroll
      for (int nt = 0; nt < 4; ++nt)
#pragma unroll
        for (int mt = 0; mt < 4; ++mt)
          ta[mt][nt] = __builtin_amdgcn_mfma_f32_16x16x32_bf16(a[mt], bcur[nt], ta[mt][nt], 0, 0, 0);
      if (ks < 7) {
#pragma unroll
        for (int nt = 0; nt < 4; ++nt) bcur[nt] = bnxt[nt];
      }
    }
#pragma unroll
    for (int mt = 0; mt < 4; ++mt) {
      const int d = wv * 64 + mt * 16 + l4 * 4;
#pragma unroll
      for (int nt = 0; nt < 4; ++nt) {
        const int e = nt * 16 + l15;
        *reinterpret_cast<uint2*>(&Tc[e * 264 + d]) =
            pack4(ta[mt][nt][0], ta[mt][nt][1], ta[mt][nt][2], ta[mt][nt][3]);
      }
    }
  }
  __syncthreads();

  // Phase B: T = Q @ wk^T, then T' = (T + gv)/16 -> Tc
  {
    f32x4 ta[4][4];
    zero_acc4(ta);
    gemm4(ta, wkT_p, Tc, lane, wv);
    __syncthreads();  // all reads of Q from Tc complete before overwrite
#pragma unroll
    for (int mt = 0; mt < 4; ++mt) {
      const int d = wv * 64 + mt * 16 + l4 * 4;
      const f32x4 gq = *reinterpret_cast<const f32x4*>(&gv[d]);
#pragma unroll
      for (int nt = 0; nt < 4; ++nt) {
        const int e = nt * 16 + l15;
        *reinterpret_cast<uint2*>(&Tc[e * 264 + d]) =
            pack4((ta[mt][nt][0] + gq[0]) * 0.0625f, (ta[mt][nt][1] + gq[1]) * 0.0625f,
                  (ta[mt][nt][2] + gq[2]) * 0.0625f, (ta[mt][nt][3] + gq[3]) * 0.0625f);
      }
    }
  }
  __syncthreads();

  // Phase C: S = Tc @ Z^T; a-frags from LDS, b-frags rolling 3+3 prefetch
  f32x4 sc[4][6];
#pragma unroll
  for (int mt = 0; mt < 4; ++mt)
#pragma unroll
    for (int s = 0; s < 6; ++s) sc[mt][s] = (f32x4){0.f, 0.f, 0.f, 0.f};
  {
    const unsigned short* Sb = Zsp + (size_t)wv * 4096 + lane * 8;
    bf16x8 b0[3], b1[3];
#pragma unroll
    for (int j = 0; j < 3; ++j)
      b0[j] = *reinterpret_cast<const bf16x8*>(Sb + j * 16384);
#pragma unroll
    for (int ks = 0; ks < 8; ++ks) {
#pragma unroll
      for (int j = 0; j < 3; ++j)
        b1[j] = *reinterpret_cast<const bf16x8*>(Sb + (3 + j) * 16384 + ks * 512);
      bf16x8 a[4];
#pragma unroll
      for (int mt = 0; mt < 4; ++mt)
        a[mt] = *reinterpret_cast<const bf16x8*>(&Tc[(mt * 16 + l15) * 264 + ks * 32 + l4 * 8]);
#pragma unroll
      for (int j = 0; j < 3; ++j)
#pragma unroll
        for (int mt = 0; mt < 4; ++mt)
          sc[mt][j] = __builtin_amdgcn_mfma_f32_16x16x32_bf16(a[mt], b0[j], sc[mt][j], 0, 0, 0);
      if (ks < 7) {
#pragma unroll
        for (int j = 0; j < 3; ++j)
          b0[j] = *reinterpret_cast<const bf16x8*>(Sb + j * 16384 + (ks + 1) * 512);
      }
#pragma unroll
      for (int j = 0; j < 3; ++j)
#pragma unroll
        for (int mt = 0; mt < 4; ++mt)
          sc[mt][3 + j] = __builtin_amdgcn_mfma_f32_16x16x32_bf16(a[mt], b1[j], sc[mt][3 + j], 0, 0, 0);
    }
  }

  // softmax over f (384 cols), rows e = mt*16 + l4*4 + r
  float rmax[4][4];
#pragma unroll
  for (int mt = 0; mt < 4; ++mt) {
#pragma unroll
    for (int r = 0; r < 4; ++r) {
      float m = -1e30f;
#pragma unroll
      for (int s = 0; s < 6; ++s) m = fmaxf(m, sc[mt][s][r]);
      m = fmaxf(m, __shfl_xor(m, 1));
      m = fmaxf(m, __shfl_xor(m, 2));
      m = fmaxf(m, __shfl_xor(m, 4));
      m = fmaxf(m, __shfl_xor(m, 8));
      rmax[mt][r] = m;
    }
  }
  if (l15 == 0) {
#pragma unroll
    for (int mt = 0; mt < 4; ++mt)
#pragma unroll
      for (int r = 0; r < 4; ++r)
        red[wv * 64 + mt * 16 + l4 * 4 + r] = rmax[mt][r];
  }
  __syncthreads();
#pragma unroll
  for (int mt = 0; mt < 4; ++mt) {
#pragma unroll
    for (int r = 0; r < 4; ++r) {
      const int row = mt * 16 + l4 * 4 + r;
      rmax[mt][r] = fmaxf(fmaxf(red[row], red[64 + row]), fmaxf(red[128 + row], red[192 + row]));
    }
  }

  float rsum[4][4];
#pragma unroll
  for (int mt = 0; mt < 4; ++mt) {
#pragma unroll
    for (int r = 0; r < 4; ++r) {
      float sSum = 0.f;
#pragma unroll
      for (int s = 0; s < 6; ++s) {
        float e = __expf(sc[mt][s][r] - rmax[mt][r]);
        sc[mt][s][r] = e;
        sSum += e;
      }
      sSum += __shfl_xor(sSum, 1);
      sSum += __shfl_xor(sSum, 2);
      sSum += __shfl_xor(sSum, 4);
      sSum += __shfl_xor(sSum, 8);
      rsum[mt][r] = sSum;
    }
  }
  if (l15 == 0) {
#pragma unroll
    for (int mt = 0; mt < 4; ++mt)
#pragma unroll
      for (int r = 0; r < 4; ++r)
        red2[wv * 64 + mt * 16 + l4 * 4 + r] = rsum[mt][r];
  }
  __syncthreads();
  float rinv[4][4];
#pragma unroll
  for (int mt = 0; mt < 4; ++mt) {
#pragma unroll
    for (int r = 0; r < 4; ++r) {
      const int row = mt * 16 + l4 * 4 + r;
      rinv[mt][r] = 1.0f / (red2[row] + red2[64 + row] + red2[128 + row] + red2[192 + row]);
    }
  }

  // col-sums of A over this chunk's 64 rows -> cpart (LDS, aliases Tc)
  float* cpart = reinterpret_cast<float*>(&Tc[0]);          // 384 floats
  float* part = reinterpret_cast<float*>(&Tc[1024]);        // [16][257] floats
#pragma unroll
  for (int s = 0; s < 6; ++s) {
    float v = 0.f;
#pragma unroll
    for (int mt = 0; mt < 4; ++mt)
#pragma unroll
      for (int r = 0; r < 4; ++r)
        v += sc[mt][s][r] * rinv[mt][r];
    v += __shfl_xor(v, 16);
    v += __shfl_xor(v, 32);
    if (lane < 16) cpart[s * 64 + wv * 16 + lane] = v;
  }
  __syncthreads();

  // upart[d] = sum_f cpart[f] * Z[f][d] (Z_p is L2-hot) -> atomicAdd ubufg[p]
  float a16[16];
#pragma unroll
  for (int j = 0; j < 16; ++j) a16[j] = 0.f;
#pragma unroll 4
  for (int grp = 0; grp < 24; ++grp) {
    const float w = cpart[grp * 16 + l15];
    const uint4 z0 = *reinterpret_cast<const uint4*>(Zsp + grp * 4096 + wv * 512 + lane * 8);
    const uint4 z1 = *reinterpret_cast<const uint4*>(Zsp + grp * 4096 + (wv + 4) * 512 + lane * 8);
    a16[0] = fmaf(w, bf2f(z0.x & 0xffffu), a16[0]);
    a16[1] = fmaf(w, bf2f(z0.x >> 16), a16[1]);
    a16[2] = fmaf(w, bf2f(z0.y & 0xffffu), a16[2]);
    a16[3] = fmaf(w, bf2f(z0.y >> 16), a16[3]);
    a16[4] = fmaf(w, bf2f(z0.z & 0xffffu), a16[4]);
    a16[5] = fmaf(w, bf2f(z0.z >> 16), a16[5]);
    a16[6] = fmaf(w, bf2f(z0.w & 0xffffu), a16[6]);
    a16[7] = fmaf(w, bf2f(z0.w >> 16), a16[7]);
    a16[8]  = fmaf(w, bf2f(z1.x & 0xffffu), a16[8]);
    a16[9]  = fmaf(w, bf2f(z1.x >> 16), a16[9]);
    a16[10] = fmaf(w, bf2f(z1.y & 0xffffu), a16[10]);
    a16[11] = fmaf(w, bf2f(z1.y >> 16), a16[11]);
    a16[12] = fmaf(w, bf2f(z1.z & 0xffffu), a16[12]);
    a16[13] = fmaf(w, bf2f(z1.z >> 16), a16[13]);
    a16[14] = fmaf(w, bf2f(z1.w & 0xffffu), a16[14]);
    a16[15] = fmaf(w, bf2f(z1.w >> 16), a16[15]);
  }
#pragma unroll
  for (int j = 0; j < 8; ++j) part[l15 * 257 + wv * 32 + l4 * 8 + j] = a16[j];
#pragma unroll
  for (int j = 0; j < 8; ++j) part[l15 * 257 + 128 + wv * 32 + l4 * 8 + j] = a16[8 + j];
  __syncthreads();
  float uu = 0.f;
#pragma unroll
  for (int g = 0; g < 16; ++g) uu += part[g * 257 + t];
  atomicAdd(&ubufg[p * DD + t], uu);
}

// ---------------- output kernel: out[p] = (ftri + u@wv + 384*bv)/384 ----------------

__global__ __launch_bounds__(256) void out2_kernel(
    const float* __restrict__ ubufg, const float* __restrict__ ftri,
    const float* __restrict__ wvw, const float* __restrict__ wvb,
    float* __restrict__ out) {
  __shared__ float u[DD];
  const int p = blockIdx.x, t = threadIdx.x;
  u[t] = ubufg[p * DD + t];
  __syncthreads();
  float acc = ftri[p * DD + t] + 384.0f * wvb[t];
#pragma unroll 8
  for (int d = 0; d < DD; ++d)
    acc = fmaf(u[d], wvw[d * DD + t], acc);
  out[p * DD + t] = acc * (1.0f / 384.0f);
}

// ---------------- launch ----------------

extern "C" void kernel_launch(void* const* d_in, const int* in_sizes, int n_in,
                              void* d_out, int out_size, void* d_ws, size_t ws_size,
                              hipStream_t stream) {
  (void)in_sizes; (void)n_in; (void)out_size; (void)ws_size;
  const float* H = (const float*)d_in[0];
  const float* X = (const float*)d_in[1];
  const float* res_w1 = (const float*)d_in[4];
  const float* res_b1 = (const float*)d_in[5];
  const float* res_w2 = (const float*)d_in[6];
  const float* res_b2 = (const float*)d_in[7];
  const float* atom_w1 = (const float*)d_in[8];
  const float* atom_b1 = (const float*)d_in[9];
  const float* atom_w2 = (const float*)d_in[10];
  const float* atom_b2 = (const float*)d_in[11];
  const float* simw = (const float*)d_in[12];
  const float* int_w1 = (const float*)d_in[13];
  const float* int_b1 = (const float*)d_in[14];
  const float* int_w2 = (const float*)d_in[15];
  const float* int_b2 = (const float*)d_in[16];
  const float* wl = (const float*)d_in[17];
  const float* wr = (const float*)d_in[18];
  const float* wg_w = (const float*)d_in[19];
  const float* wg_b = (const float*)d_in[20];
  const float* wq_w = (const float*)d_in[21];
  const float* wq_b = (const float*)d_in[22];
  const float* wk_w = (const float*)d_in[23];
  const float* wv_w = (const float*)d_in[25];
  const float* wv_b = (const float*)d_in[26];

  char* ws = (char*)d_ws;
  unsigned short* wpack = (unsigned short*)(ws + 0);      //  786432 B (6 slots)
  float* MrF   = (float*)(ws + 786432);                   //  262144 B
  float* MaF   = (float*)(ws + 1048576);                  //  262144 B
  float* cvec  = (float*)(ws + 1310720);                  //    1024 B
  float* gv    = (float*)(ws + 1311744);                  //    1024 B
  float* P1    = (float*)(ws + 1312768);                  //  393216 B
  float* P2    = (float*)(ws + 1705984);                  //  393216 B
  float* Hpl   = (float*)(ws + 2099200);                  //  393216 B
  float* Her   = (float*)(ws + 2492416);                  //  393216 B
  float* ftri  = (float*)(ws + 2885632);                  //  393216 B
  float* ubufg = (float*)(ws + 3278848);                  //  393216 B
  unsigned short* Zsw = (unsigned short*)(ws + 3672064);  // 75497472 B
  unsigned short* tab = (unsigned short*)(ws + 79169536); //  2097152 B

  hipMemsetAsync(ftri, 0, 393216 + 393216, stream);       // ftri + ubufg (contiguous)
  hipMemsetAsync(cvec, 0, DD * sizeof(float), stream);
  prep_kernel<<<2120, 256, 0, stream>>>(H, wl, wr, int_w1, res_w2, atom_w2,
                                        res_b2, atom_b2, int_b1, simw, wq_b, wk_w,
                                        Hpl, Her, P1, P2, MrF, MaF, cvec, gv);
  pack_kernel<<<1536, 256, 0, stream>>>(MrF, MaF, int_w2, wg_w, wq_w, wk_w, wpack);
  tab_kernel<<<NTAB / 64, 256, 0, stream>>>(res_w1, res_b1, atom_w1, atom_b1, wpack, tab);
  pair_kernel<<<2304, 256, 0, stream>>>(X, tab, int_b2, wg_b, wpack, cvec,
                                        P1, P2, Hpl, Her, ftri, Zsw);
  attn_kernel<<<2304, 256, 0, stream>>>(Zsw, gv, wpack, ubufg);
  out2_kernel<<<384, 256, 0, stream>>>(ubufg, ftri, wv_w, wv_b, (float*)d_out);
  hipMemcpyAsync((float*)d_out + NPAR * DD, H + NPAR * DD,
                 (1024 - NPAR) * DD * sizeof(float), hipMemcpyDeviceToDevice, stream);
}

// Round 12
// 344.482 us; speedup vs baseline: 1.0629x; 1.0629x over previous
//
#include <hip/hip_runtime.h>

#define NPAR 384
#define NEPI 384
#define DD   256
#define NTAB 4096
#define SMAX 96.0f
#define SDELTA (SMAX / NTAB)
#define SINVD (NTAB / SMAX)

using bf16x8 = __bf16 __attribute__((ext_vector_type(8)));
using bf16x2 = __bf16 __attribute__((ext_vector_type(2)));
using f32x4  = float __attribute__((ext_vector_type(4)));

#if defined(__has_builtin)
#if __has_builtin(__builtin_amdgcn_cvt_pk_bf16_f32)
#define HAVE_PK_BF16 1
#endif
#endif

__device__ __forceinline__ float sigm(float x) { return 1.0f / (1.0f + __expf(-x)); }
__device__ __forceinline__ float silu(float x) { return x / (1.0f + __expf(-x)); }
__device__ __forceinline__ unsigned short f2bf(float f) {
  unsigned u = __float_as_uint(f);
  u += 0x7fffu + ((u >> 16) & 1u);
  return (unsigned short)(u >> 16);
}
__device__ __forceinline__ float bf2f(unsigned u16) {
  return __uint_as_float(u16 << 16);
}
__device__ __forceinline__ float bf2f_lo(unsigned w) {
  return __uint_as_float(w << 16);
}
__device__ __forceinline__ float bf2f_hi(unsigned w) {
  return __uint_as_float(w & 0xffff0000u);
}
__device__ __forceinline__ uint2 pack4(float a, float b, float c, float d) {
  uint2 r;
#ifdef HAVE_PK_BF16
  bf16x2 lo = __builtin_amdgcn_cvt_pk_bf16_f32(a, b);
  bf16x2 hi = __builtin_amdgcn_cvt_pk_bf16_f32(c, d);
  r.x = __builtin_bit_cast(unsigned, lo);
  r.y = __builtin_bit_cast(unsigned, hi);
#else
  r.x = (unsigned)f2bf(a) | ((unsigned)f2bf(b) << 16);
  r.y = (unsigned)f2bf(c) | ((unsigned)f2bf(d) << 16);
#endif
  return r;
}

// ---------------- fused precompute kernel ----------------
// block ranges: [0,64) transpose wk->wkT ; [64,576) fold Mr/Ma ; [576,584) cvec ;
// [584,648) gvec ; [648,2184) mm_rows4 (Hpl/Her/P1/P2)

__global__ void prep_kernel(
    const float* __restrict__ H, const float* __restrict__ wl,
    const float* __restrict__ wr, const float* __restrict__ int_w1,
    const float* __restrict__ res_w2, const float* __restrict__ atom_w2,
    const float* __restrict__ res_b2, const float* __restrict__ atom_b2,
    const float* __restrict__ int_b1, const float* __restrict__ simw,
    const float* __restrict__ wq_b, const float* __restrict__ wk_w,
    float* __restrict__ Hpl, float* __restrict__ Her,
    float* __restrict__ P1, float* __restrict__ P2,
    float* __restrict__ MrF, float* __restrict__ MaF,
    float* __restrict__ cvec, float* __restrict__ gv,
    float* __restrict__ wkT) {
  __shared__ float tile[32][33];
  const int b = blockIdx.x, t = threadIdx.x;
  if (b < 64) {
    const int bx = b & 7, by = b >> 3;
    const int tx = t & 31, ty = t >> 5;
    for (int r = 0; r < 32; r += 8)
      tile[ty + r][tx] = wk_w[(by * 32 + ty + r) * 256 + bx * 32 + tx];
    __syncthreads();
    for (int r = 0; r < 32; r += 8)
      wkT[(bx * 32 + ty + r) * 256 + by * 32 + tx] = tile[tx][ty + r];
  } else if (b < 576) {
    const int bb = b - 64;
    const int i = bb & 255;
    const bool isMa = bb >= 256;
    const float wmix = 1.0f / (1.0f + __expf(-simw[0]));
    const float sc = isMa ? (1.0f - wmix) : wmix;
    const float* W2 = isMa ? atom_w2 : res_w2;
    float acc = 0.f;
#pragma unroll 8
    for (int k = 0; k < 256; ++k)
      acc += W2[i * 256 + k] * int_w1[(512 + k) * 256 + t];
    (isMa ? MaF : MrF)[i * 256 + t] = acc * sc;
  } else if (b < 584) {
    const int bb = b - 576;
    const float wmix = 1.0f / (1.0f + __expf(-simw[0]));
    float acc = (bb == 0) ? int_b1[t] : 0.f;
#pragma unroll
    for (int k = bb * 32; k < bb * 32 + 32; ++k) {
      float bm = wmix * res_b2[k] + (1.0f - wmix) * atom_b2[k];
      acc += bm * int_w1[(512 + k) * 256 + t];
    }
    atomicAdd(&cvec[t], acc);
  } else if (b < 648) {
    const int lane = t & 63, w = t >> 6;
    const int d = (b - 584) * 4 + w;
    float acc = 0.f;
#pragma unroll
    for (int i = 0; i < 4; ++i) {
      const int c = i * 64 + lane;
      acc += wk_w[d * 256 + c] * wq_b[c];
    }
    acc += __shfl_xor(acc, 1);
    acc += __shfl_xor(acc, 2);
    acc += __shfl_xor(acc, 4);
    acc += __shfl_xor(acc, 8);
    acc += __shfl_xor(acc, 16);
    acc += __shfl_xor(acc, 32);
    if (lane == 0) gv[d] = acc;
  } else {
    const int idx = b - 648;
    const int seg = idx / 384, r = idx % 384;
    const float* A;
    const float* B;
    float* C;
    switch (seg) {
      case 0:  A = H + r * 256;            B = wl;              C = Hpl + r * 256; break;
      case 1:  A = H + (NPAR + r) * 256;   B = wr;              C = Her + r * 256; break;
      case 2:  A = H + r * 256;            B = int_w1;          C = P1 + r * 256;  break;
      default: A = H + (NPAR + r) * 256;   B = int_w1 + 65536;  C = P2 + r * 256;  break;
    }
    float acc = 0.f;
#pragma unroll 8
    for (int k = 0; k < 256; ++k)
      acc += A[k] * B[k * 256 + t];
    C[t] = acc;
  }
}

// C[r][j] = sum_k A[r][k] * B[k][j]  (grid = #rows) — for Wqk = wq @ wkT
__global__ void mm_rows(const float* __restrict__ A, const float* __restrict__ B,
                        float* __restrict__ C) {
  const int r = blockIdx.x, j = threadIdx.x;
  float acc = 0.f;
#pragma unroll 8
  for (int k = 0; k < 256; ++k)
    acc += A[r * 256 + k] * B[k * 256 + j];
  C[r * 256 + j] = acc;
}

// pack 5 [256,256] matrices into MFMA fragment order:
// wpack[m][((ks*16+tile)*64 + lane)*8 + j] = W[k = ks*32 + (lane>>4)*8 + j][n = tile*16 + (lane&15)]
// slots: 0=Mr 1=Ma 2=int_w2 3=wg 4=Wqk
__global__ void pack_kernel(const float* __restrict__ MrF, const float* __restrict__ MaF,
                            const float* __restrict__ w2, const float* __restrict__ wg,
                            const float* __restrict__ WqkF, unsigned short* __restrict__ wpack) {
  const int idx = blockIdx.x * 256 + threadIdx.x;
  const int m = idx >> 16;
  const int r = idx & 65535;
  const int chunk = r >> 9;
  const int lane = (r >> 3) & 63;
  const int j = r & 7;
  const int k = (chunk >> 4) * 32 + (lane >> 4) * 8 + j;
  const int n = (chunk & 15) * 16 + (lane & 15);
  const float* src;
  switch (m) {
    case 0: src = MrF; break;
    case 1: src = MaF; break;
    case 2: src = w2; break;
    case 3: src = wg; break;
    default: src = WqkF; break;
  }
  wpack[idx] = f2bf(src[k * 256 + n]);
}

// ---------------- shared GEMM helpers ----------------

__device__ __forceinline__ void zero_acc4(f32x4 (&acc)[4][4]) {
#pragma unroll
  for (int mt = 0; mt < 4; ++mt)
#pragma unroll
    for (int nt = 0; nt < 4; ++nt)
      acc[mt][nt] = (f32x4){0.f, 0.f, 0.f, 0.f};
}

// transposed-acc: mfma(Wfrag, ActFrag) -> acc^T[d][e]
// d = wv*64 + mt*16 + l4*4 + r, e = nt*16 + l15
__device__ __forceinline__ void gemm4(f32x4 (&acc)[4][4],
                                      const unsigned short* __restrict__ wp,
                                      const unsigned short* ub, int lane, int wv) {
  const int l15 = lane & 15, l4 = lane >> 4;
#pragma unroll
  for (int ks = 0; ks < 8; ++ks) {
    bf16x8 a[4];
#pragma unroll
    for (int mt = 0; mt < 4; ++mt)
      a[mt] = *reinterpret_cast<const bf16x8*>(wp + ((ks * 16 + wv * 4 + mt) * 64 + lane) * 8);
#pragma unroll
    for (int nt = 0; nt < 4; ++nt) {
      bf16x8 b = *reinterpret_cast<const bf16x8*>(ub + (nt * 16 + l15) * 264 + ks * 32 + l4 * 8);
#pragma unroll
      for (int mt = 0; mt < 4; ++mt)
        acc[mt][nt] = __builtin_amdgcn_mfma_f32_16x16x32_bf16(a[mt], b, acc[mt][nt], 0, 0, 0);
    }
  }
}

// fill ubuf[e][d] = silu(Sv[e]*w1[d] + b1[d])
__device__ __forceinline__ void fill_u(unsigned short* ub, const float* Sv,
                                       const float* __restrict__ w1,
                                       const float* __restrict__ b1, int t) {
  const int dg = t & 31, rb = t >> 5;
  const f32x4 w1a = *reinterpret_cast<const f32x4*>(&w1[dg * 8]);
  const f32x4 w1b = *reinterpret_cast<const f32x4*>(&w1[dg * 8 + 4]);
  const f32x4 b1a = *reinterpret_cast<const f32x4*>(&b1[dg * 8]);
  const f32x4 b1b = *reinterpret_cast<const f32x4*>(&b1[dg * 8 + 4]);
#pragma unroll
  for (int i = 0; i < 8; ++i) {
    const int e = rb + i * 8;
    const float s = Sv[e];
    uint2 lo = pack4(silu(fmaf(s, w1a[0], b1a[0])), silu(fmaf(s, w1a[1], b1a[1])),
                     silu(fmaf(s, w1a[2], b1a[2])), silu(fmaf(s, w1a[3], b1a[3])));
    uint2 hi = pack4(silu(fmaf(s, w1b[0], b1b[0])), silu(fmaf(s, w1b[1], b1b[1])),
                     silu(fmaf(s, w1b[2], b1b[2])), silu(fmaf(s, w1b[3], b1b[3])));
    uint4 pk = {lo.x, lo.y, hi.x, hi.y};
    *reinterpret_cast<uint4*>(&ub[e * 264 + dg * 8]) = pk;
  }
}

// ---------------- table build: tab[n][d] = F(n*SDELTA)[d] (wpack slots 0,1) ----------------

__global__ __launch_bounds__(256, 3) void tab_kernel(
    const float* __restrict__ res_w1, const float* __restrict__ res_b1,
    const float* __restrict__ atom_w1, const float* __restrict__ atom_b1,
    const unsigned short* __restrict__ wpack, unsigned short* __restrict__ tab) {
  __shared__ __align__(16) unsigned short ubuf[64 * 264];
  __shared__ float Sv[64];
  const int t = threadIdx.x, lane = t & 63, wv = t >> 6;
  const int l15 = lane & 15, l4 = lane >> 4;
  const int n0 = blockIdx.x * 64;
  if (t < 64) Sv[t] = (n0 + t) * SDELTA;
  __syncthreads();
  f32x4 acc[4][4];
  zero_acc4(acc);
  fill_u(ubuf, Sv, res_w1, res_b1, t);
  __syncthreads();
  gemm4(acc, wpack + 0 * 65536, ubuf, lane, wv);
  __syncthreads();
  fill_u(ubuf, Sv, atom_w1, atom_b1, t);
  __syncthreads();
  gemm4(acc, wpack + 1 * 65536, ubuf, lane, wv);
#pragma unroll
  for (int mt = 0; mt < 4; ++mt) {
    const int d = wv * 64 + mt * 16 + l4 * 4;
#pragma unroll
    for (int nt = 0; nt < 4; ++nt) {
      const int n = n0 + nt * 16 + l15;
      *reinterpret_cast<uint2*>(&tab[n * 256 + d]) =
          pack4(acc[mt][nt][0], acc[mt][nt][1], acc[mt][nt][2], acc[mt][nt][3]);
    }
  }
}

// ---------------- pairwise kernel (64-row tiles): table-interp h + 2 GEMMs ----------------

__global__ __launch_bounds__(256, 3) void pair_kernel(
    const float* __restrict__ Xg, const unsigned short* __restrict__ tab,
    const float* __restrict__ int_b2, const float* __restrict__ wg_b,
    const unsigned short* __restrict__ wpack, const float* __restrict__ cvec,
    const float* __restrict__ P1, const float* __restrict__ P2,
    const float* __restrict__ Hpl, const float* __restrict__ Her,
    float* __restrict__ ftri, unsigned short* __restrict__ Zsw) {
  __shared__ __align__(16) unsigned short ubuf[64 * 264];
  __shared__ float Sv[64];
  __shared__ float pc[DD];
  const int t = threadIdx.x, lane = t & 63, wv = t >> 6;
  const int l15 = lane & 15, l4 = lane >> 4;
  const int p = blockIdx.x / 6, cc = blockIdx.x % 6, e0 = cc * 64;
  const int d0 = wv * 64;

  if (t < 64) {
    const int e = e0 + t;
    float dx = Xg[p * 42 + 3] - Xg[(NPAR + e) * 42 + 3];
    float dy = Xg[p * 42 + 4] - Xg[(NPAR + e) * 42 + 4];
    float dz = Xg[p * 42 + 5] - Xg[(NPAR + e) * 42 + 5];
    Sv[t] = dx * dx + dy * dy + dz * dz;
  }
  pc[t] = P1[p * DD + t] + cvec[t];
  __syncthreads();

  // h-fill: h[e][d] = silu(lerp(tab, S[e])[d] + pc[d] + P2[e][d]) -> ubuf
  {
    const int dg = t & 31, rb = t >> 5;
    const f32x4 pca = *reinterpret_cast<const f32x4*>(&pc[dg * 8]);
    const f32x4 pcb = *reinterpret_cast<const f32x4*>(&pc[dg * 8 + 4]);
#pragma unroll
    for (int i = 0; i < 8; ++i) {
      const int e = rb + i * 8;
      float sv = Sv[e] * SINVD;
      int idx = (int)sv;
      idx = idx > (NTAB - 2) ? (NTAB - 2) : idx;
      const float fr = sv - (float)idx;
      const uint4 t0 = *reinterpret_cast<const uint4*>(&tab[idx * 256 + dg * 8]);
      const uint4 t1 = *reinterpret_cast<const uint4*>(&tab[(idx + 1) * 256 + dg * 8]);
      const f32x4 p2a = *reinterpret_cast<const f32x4*>(&P2[(e0 + e) * DD + dg * 8]);
      const f32x4 p2b = *reinterpret_cast<const f32x4*>(&P2[(e0 + e) * DD + dg * 8 + 4]);
      float z0 = bf2f_lo(t0.x), z1 = bf2f_hi(t0.x), z2 = bf2f_lo(t0.y), z3 = bf2f_hi(t0.y);
      float z4 = bf2f_lo(t0.z), z5 = bf2f_hi(t0.z), z6 = bf2f_lo(t0.w), z7 = bf2f_hi(t0.w);
      z0 = fmaf(fr, bf2f_lo(t1.x) - z0, z0) + pca[0] + p2a[0];
      z1 = fmaf(fr, bf2f_hi(t1.x) - z1, z1) + pca[1] + p2a[1];
      z2 = fmaf(fr, bf2f_lo(t1.y) - z2, z2) + pca[2] + p2a[2];
      z3 = fmaf(fr, bf2f_hi(t1.y) - z3, z3) + pca[3] + p2a[3];
      z4 = fmaf(fr, bf2f_lo(t1.z) - z4, z4) + pcb[0] + p2b[0];
      z5 = fmaf(fr, bf2f_hi(t1.z) - z5, z5) + pcb[1] + p2b[1];
      z6 = fmaf(fr, bf2f_lo(t1.w) - z6, z6) + pcb[2] + p2b[2];
      z7 = fmaf(fr, bf2f_hi(t1.w) - z7, z7) + pcb[3] + p2b[3];
      uint2 lo = pack4(silu(z0), silu(z1), silu(z2), silu(z3));
      uint2 hi = pack4(silu(z4), silu(z5), silu(z6), silu(z7));
      uint4 pk = {lo.x, lo.y, hi.x, hi.y};
      *reinterpret_cast<uint4*>(&ubuf[e * 264 + dg * 8]) = pk;
    }
  }
  __syncthreads();

  // Z = h @ int_w2 + int_b2 -> ubuf
  f32x4 acc[4][4];
  zero_acc4(acc);
  gemm4(acc, wpack + 2 * 65536, ubuf, lane, wv);
  __syncthreads();
#pragma unroll
  for (int mt = 0; mt < 4; ++mt) {
    const int d = d0 + mt * 16 + l4 * 4;
    const f32x4 bb = *reinterpret_cast<const f32x4*>(&int_b2[d]);
#pragma unroll
    for (int nt = 0; nt < 4; ++nt) {
      const int e = nt * 16 + l15;
      *reinterpret_cast<uint2*>(&ubuf[e * 264 + d]) =
          pack4(acc[mt][nt][0] + bb[0], acc[mt][nt][1] + bb[1],
                acc[mt][nt][2] + bb[2], acc[mt][nt][3] + bb[3]);
    }
  }
  __syncthreads();

  // swizzled MFMA-fragment-order store: grp = cc*4 + wv, e = grp*16 + l15
  {
    unsigned short* Zd = Zsw + (size_t)p * 98304 + (size_t)(cc * 4 + wv) * 4096 + lane * 8;
#pragma unroll
    for (int ks = 0; ks < 8; ++ks) {
      *reinterpret_cast<uint4*>(Zd + ks * 512) =
          *reinterpret_cast<const uint4*>(&ubuf[(wv * 16 + l15) * 264 + ks * 32 + l4 * 8]);
    }
  }

  // gate: f_tri[d] += Hpl[p][d] * sum_e sigm(Z@wg + b) * Her[e][d]
  zero_acc4(acc);
  gemm4(acc, wpack + 3 * 65536, ubuf, lane, wv);
#pragma unroll
  for (int mt = 0; mt < 4; ++mt) {
    const int d = d0 + mt * 16 + l4 * 4;
    const f32x4 bb = *reinterpret_cast<const f32x4*>(&wg_b[d]);
    const f32x4 hl = *reinterpret_cast<const f32x4*>(&Hpl[p * DD + d]);
    f32x4 fs = (f32x4){0.f, 0.f, 0.f, 0.f};
#pragma unroll
    for (int nt = 0; nt < 4; ++nt) {
      const int e = e0 + nt * 16 + l15;
      const f32x4 hr = *reinterpret_cast<const f32x4*>(&Her[e * DD + d]);
#pragma unroll
      for (int r = 0; r < 4; ++r)
        fs[r] += sigm(acc[mt][nt][r] + bb[r]) * hr[r];
    }
#pragma unroll
    for (int r = 0; r < 4; ++r) {
      float v = fs[r] * hl[r];
      v += __shfl_xor(v, 1);
      v += __shfl_xor(v, 2);
      v += __shfl_xor(v, 4);
      v += __shfl_xor(v, 8);
      if (l15 == 0) atomicAdd(&ftri[p * DD + d + r], v);
    }
  }
}

// ---------------- fused attention kernel: block = (p, 64-row chunk) ----------------
// scores = (Z_c Wqk + 1*gv^T) Z^T / 16 — gv and 1/16 folded into T.
// col-sums of softmax -> cbufg[p].  r12: S-phase full 6+6 double-buffer.

__global__ __launch_bounds__(256, 3) void attn_kernel(
    const unsigned short* __restrict__ Zsw, const float* __restrict__ gv,
    const unsigned short* __restrict__ wpack, float* __restrict__ cbufg) {
  __shared__ __align__(16) unsigned short Tc[64 * 264];
  __shared__ float red[256];
  __shared__ float red2[256];
  const int t = threadIdx.x, lane = t & 63, wv = t >> 6;
  const int l15 = lane & 15, l4 = lane >> 4;
  // XCD swizzle: all 6 chunks of one p land on the same XCD (xcd = blk % 8)
  const int xcd = blockIdx.x & 7, inner = blockIdx.x >> 3;
  const int p = (inner / 6) * 8 + xcd, c = inner % 6;
  const unsigned short* Zsp = Zsw + (size_t)p * 98304;
  const unsigned short* wqk = wpack + 4 * 65536;

  // T' = (Zc @ Wqk + gv) / 16, b-frags double-buffered from Zsw
  {
    f32x4 ta[4][4];
    zero_acc4(ta);
    const unsigned short* Tb = Zsp + (size_t)(c * 4) * 4096 + lane * 8;
    bf16x8 bcur[4], bnxt[4];
#pragma unroll
    for (int nt = 0; nt < 4; ++nt)
      bcur[nt] = *reinterpret_cast<const bf16x8*>(Tb + nt * 4096);
#pragma unroll
    for (int ks = 0; ks < 8; ++ks) {
      if (ks < 7) {
#pragma unroll
        for (int nt = 0; nt < 4; ++nt)
          bnxt[nt] = *reinterpret_cast<const bf16x8*>(Tb + nt * 4096 + (ks + 1) * 512);
      }
      bf16x8 a[4];
#pragma unroll
      for (int mt = 0; mt < 4; ++mt)
        a[mt] = *reinterpret_cast<const bf16x8*>(wqk + ((ks * 16 + wv * 4 + mt) * 64 + lane) * 8);
#pragma unroll
      for (int nt = 0; nt < 4; ++nt)
#pragma unroll
        for (int mt = 0; mt < 4; ++mt)
          ta[mt][nt] = __builtin_amdgcn_mfma_f32_16x16x32_bf16(a[mt], bcur[nt], ta[mt][nt], 0, 0, 0);
      if (ks < 7) {
#pragma unroll
        for (int nt = 0; nt < 4; ++nt) bcur[nt] = bnxt[nt];
      }
    }
#pragma unroll
    for (int mt = 0; mt < 4; ++mt) {
      const int d = wv * 64 + mt * 16 + l4 * 4;
      const f32x4 gq = *reinterpret_cast<const f32x4*>(&gv[d]);
#pragma unroll
      for (int nt = 0; nt < 4; ++nt) {
        const int e = nt * 16 + l15;
        *reinterpret_cast<uint2*>(&Tc[e * 264 + d]) =
            pack4((ta[mt][nt][0] + gq[0]) * 0.0625f, (ta[mt][nt][1] + gq[1]) * 0.0625f,
                  (ta[mt][nt][2] + gq[2]) * 0.0625f, (ta[mt][nt][3] + gq[3]) * 0.0625f);
      }
    }
  }
  __syncthreads();

  // S = Tc @ Z^T; a-frags from LDS, b-frags full 6+6 double-buffer from Zsw
  f32x4 sc[4][6];
#pragma unroll
  for (int mt = 0; mt < 4; ++mt)
#pragma unroll
    for (int s = 0; s < 6; ++s) sc[mt][s] = (f32x4){0.f, 0.f, 0.f, 0.f};

  {
    const unsigned short* Sb = Zsp + (size_t)wv * 4096 + lane * 8;
    bf16x8 bcur[6], bnxt[6];
#pragma unroll
    for (int s = 0; s < 6; ++s)
      bcur[s] = *reinterpret_cast<const bf16x8*>(Sb + s * 16384);
#pragma unroll
    for (int ks = 0; ks < 8; ++ks) {
      if (ks < 7) {
#pragma unroll
        for (int s = 0; s < 6; ++s)
          bnxt[s] = *reinterpret_cast<const bf16x8*>(Sb + s * 16384 + (ks + 1) * 512);
      }
      bf16x8 a[4];
#pragma unroll
      for (int mt = 0; mt < 4; ++mt)
        a[mt] = *reinterpret_cast<const bf16x8*>(&Tc[(mt * 16 + l15) * 264 + ks * 32 + l4 * 8]);
#pragma unroll
      for (int s = 0; s < 6; ++s)
#pragma unroll
        for (int mt = 0; mt < 4; ++mt)
          sc[mt][s] = __builtin_amdgcn_mfma_f32_16x16x32_bf16(a[mt], bcur[s], sc[mt][s], 0, 0, 0);
      if (ks < 7) {
#pragma unroll
        for (int s = 0; s < 6; ++s) bcur[s] = bnxt[s];
      }
    }
  }

  // softmax over f (384 cols), rows e = mt*16 + l4*4 + r; sc already scaled
  float rmax[4][4];
#pragma unroll
  for (int mt = 0; mt < 4; ++mt) {
#pragma unroll
    for (int r = 0; r < 4; ++r) {
      float m = -1e30f;
#pragma unroll
      for (int s = 0; s < 6; ++s) m = fmaxf(m, sc[mt][s][r]);
      m = fmaxf(m, __shfl_xor(m, 1));
      m = fmaxf(m, __shfl_xor(m, 2));
      m = fmaxf(m, __shfl_xor(m, 4));
      m = fmaxf(m, __shfl_xor(m, 8));
      rmax[mt][r] = m;
    }
  }
  if (l15 == 0) {
#pragma unroll
    for (int mt = 0; mt < 4; ++mt)
#pragma unroll
      for (int r = 0; r < 4; ++r)
        red[wv * 64 + mt * 16 + l4 * 4 + r] = rmax[mt][r];
  }
  __syncthreads();
#pragma unroll
  for (int mt = 0; mt < 4; ++mt) {
#pragma unroll
    for (int r = 0; r < 4; ++r) {
      const int row = mt * 16 + l4 * 4 + r;
      rmax[mt][r] = fmaxf(fmaxf(red[row], red[64 + row]), fmaxf(red[128 + row], red[192 + row]));
    }
  }

  float rsum[4][4];
#pragma unroll
  for (int mt = 0; mt < 4; ++mt) {
#pragma unroll
    for (int r = 0; r < 4; ++r) {
      float sSum = 0.f;
#pragma unroll
      for (int s = 0; s < 6; ++s) {
        float e = __expf(sc[mt][s][r] - rmax[mt][r]);
        sc[mt][s][r] = e;
        sSum += e;
      }
      sSum += __shfl_xor(sSum, 1);
      sSum += __shfl_xor(sSum, 2);
      sSum += __shfl_xor(sSum, 4);
      sSum += __shfl_xor(sSum, 8);
      rsum[mt][r] = sSum;
    }
  }
  if (l15 == 0) {
#pragma unroll
    for (int mt = 0; mt < 4; ++mt)
#pragma unroll
      for (int r = 0; r < 4; ++r)
        red2[wv * 64 + mt * 16 + l4 * 4 + r] = rsum[mt][r];
  }
  __syncthreads();
  float rinv[4][4];
#pragma unroll
  for (int mt = 0; mt < 4; ++mt) {
#pragma unroll
    for (int r = 0; r < 4; ++r) {
      const int row = mt * 16 + l4 * 4 + r;
      rinv[mt][r] = 1.0f / (red2[row] + red2[64 + row] + red2[128 + row] + red2[192 + row]);
    }
  }

  // column sums of A over this chunk's 64 rows -> cbufg
#pragma unroll
  for (int s = 0; s < 6; ++s) {
    float v = 0.f;
#pragma unroll
    for (int mt = 0; mt < 4; ++mt)
#pragma unroll
      for (int r = 0; r < 4; ++r)
        v += sc[mt][s][r] * rinv[mt][r];
    v += __shfl_xor(v, 16);
    v += __shfl_xor(v, 32);
    if (lane < 16)
      atomicAdd(&cbufg[p * NEPI + s * 64 + wv * 16 + lane], v);
  }
}

// ---------------- output kernel ----------------
// out[p] = (ftri[p] + (c^T Z_p) @ wv + 384*bv) / 384
// Z read from swizzled Zsw — 1 KB contiguous per wave-load.

__global__ __launch_bounds__(256) void out_kernel(
    const unsigned short* __restrict__ Zsw, const float* __restrict__ ftri,
    const float* __restrict__ cbufg, const float* __restrict__ wvw,
    const float* __restrict__ wvb, float* __restrict__ out) {
  __shared__ float cb[NEPI];
  __shared__ float part[16][257];
  __shared__ float u[DD];
  const int p = blockIdx.x, t = threadIdx.x;
  const int lane = t & 63, wv = t >> 6;
  const int l15 = lane & 15, l4 = lane >> 4;
  for (int i = t; i < NEPI; i += 256) cb[i] = cbufg[p * NEPI + i];
  __syncthreads();
  const unsigned short* Zsp = Zsw + (size_t)p * 98304;
  float a16[16];
#pragma unroll
  for (int j = 0; j < 16; ++j) a16[j] = 0.f;
#pragma unroll 4
  for (int grp = 0; grp < 24; ++grp) {
    const float w = cb[grp * 16 + l15];
    const uint4 z0 = *reinterpret_cast<const uint4*>(Zsp + grp * 4096 + wv * 512 + lane * 8);
    const uint4 z1 = *reinterpret_cast<const uint4*>(Zsp + grp * 4096 + (wv + 4) * 512 + lane * 8);
    a16[0] = fmaf(w, bf2f(z0.x & 0xffffu), a16[0]);
    a16[1] = fmaf(w, bf2f(z0.x >> 16), a16[1]);
    a16[2] = fmaf(w, bf2f(z0.y & 0xffffu), a16[2]);
    a16[3] = fmaf(w, bf2f(z0.y >> 16), a16[3]);
    a16[4] = fmaf(w, bf2f(z0.z & 0xffffu), a16[4]);
    a16[5] = fmaf(w, bf2f(z0.z >> 16), a16[5]);
    a16[6] = fmaf(w, bf2f(z0.w & 0xffffu), a16[6]);
    a16[7] = fmaf(w, bf2f(z0.w >> 16), a16[7]);
    a16[8]  = fmaf(w, bf2f(z1.x & 0xffffu), a16[8]);
    a16[9]  = fmaf(w, bf2f(z1.x >> 16), a16[9]);
    a16[10] = fmaf(w, bf2f(z1.y & 0xffffu), a16[10]);
    a16[11] = fmaf(w, bf2f(z1.y >> 16), a16[11]);
    a16[12] = fmaf(w, bf2f(z1.z & 0xffffu), a16[12]);
    a16[13] = fmaf(w, bf2f(z1.z >> 16), a16[13]);
    a16[14] = fmaf(w, bf2f(z1.w & 0xffffu), a16[14]);
    a16[15] = fmaf(w, bf2f(z1.w >> 16), a16[15]);
  }
#pragma unroll
  for (int j = 0; j < 8; ++j) part[l15][wv * 32 + l4 * 8 + j] = a16[j];
#pragma unroll
  for (int j = 0; j < 8; ++j) part[l15][128 + wv * 32 + l4 * 8 + j] = a16[8 + j];
  __syncthreads();
  float uu = 0.f;
#pragma unroll
  for (int g = 0; g < 16; ++g) uu += part[g][t];
  u[t] = uu;
  __syncthreads();
  float acc = ftri[p * DD + t] + 384.0f * wvb[t];
#pragma unroll 8
  for (int d = 0; d < DD; ++d)
    acc = fmaf(u[d], wvw[d * DD + t], acc);
  out[p * DD + t] = acc * (1.0f / 384.0f);
}

// ---------------- launch ----------------

extern "C" void kernel_launch(void* const* d_in, const int* in_sizes, int n_in,
                              void* d_out, int out_size, void* d_ws, size_t ws_size,
                              hipStream_t stream) {
  (void)in_sizes; (void)n_in; (void)out_size; (void)ws_size;
  const float* H = (const float*)d_in[0];
  const float* X = (const float*)d_in[1];
  const float* res_w1 = (const float*)d_in[4];
  const float* res_b1 = (const float*)d_in[5];
  const float* res_w2 = (const float*)d_in[6];
  const float* res_b2 = (const float*)d_in[7];
  const float* atom_w1 = (const float*)d_in[8];
  const float* atom_b1 = (const float*)d_in[9];
  const float* atom_w2 = (const float*)d_in[10];
  const float* atom_b2 = (const float*)d_in[11];
  const float* simw = (const float*)d_in[12];
  const float* int_w1 = (const float*)d_in[13];
  const float* int_b1 = (const float*)d_in[14];
  const float* int_w2 = (const float*)d_in[15];
  const float* int_b2 = (const float*)d_in[16];
  const float* wl = (const float*)d_in[17];
  const float* wr = (const float*)d_in[18];
  const float* wg_w = (const float*)d_in[19];
  const float* wg_b = (const float*)d_in[20];
  const float* wq_w = (const float*)d_in[21];
  const float* wq_b = (const float*)d_in[22];
  const float* wk_w = (const float*)d_in[23];
  const float* wv_w = (const float*)d_in[25];
  const float* wv_b = (const float*)d_in[26];

  char* ws = (char*)d_ws;
  unsigned short* wpack = (unsigned short*)(ws + 0);      //  655360 B (5 slots)
  float* MrF   = (float*)(ws + 655360);
  float* MaF   = (float*)(ws + 917504);
  float* WqkF  = (float*)(ws + 1179648);
  float* wkT   = (float*)(ws + 1441792);
  float* cvec  = (float*)(ws + 1703936);
  float* gv    = (float*)(ws + 1704960);
  float* P1    = (float*)(ws + 1705984);
  float* P2    = (float*)(ws + 2099200);
  float* Hpl   = (float*)(ws + 2492416);
  float* Her   = (float*)(ws + 2885632);
  float* ftri  = (float*)(ws + 3278848);                  //  393216 B
  float* cbufg = (float*)(ws + 3672064);                  //  589824 B
  unsigned short* Zsw = (unsigned short*)(ws + 4261888);  // 75497472 B (MFMA frag order)
  unsigned short* tab = (unsigned short*)(ws + 79759360); //  2097152 B (NTAB x 256 bf16)

  hipMemsetAsync(ftri, 0, 393216 + 589824, stream);       // ftri + cbufg (contiguous)
  hipMemsetAsync(cvec, 0, DD * sizeof(float), stream);
  prep_kernel<<<2184, 256, 0, stream>>>(H, wl, wr, int_w1, res_w2, atom_w2,
                                        res_b2, atom_b2, int_b1, simw, wq_b, wk_w,
                                        Hpl, Her, P1, P2, MrF, MaF, cvec, gv, wkT);
  mm_rows<<<256, 256, 0, stream>>>(wq_w, wkT, WqkF);        // Wqk = wq @ wk^T
  pack_kernel<<<1280, 256, 0, stream>>>(MrF, MaF, int_w2, wg_w, WqkF, wpack);
  tab_kernel<<<NTAB / 64, 256, 0, stream>>>(res_w1, res_b1, atom_w1, atom_b1, wpack, tab);
  pair_kernel<<<2304, 256, 0, stream>>>(X, tab, int_b2, wg_b, wpack, cvec,
                                        P1, P2, Hpl, Her, ftri, Zsw);
  attn_kernel<<<2304, 256, 0, stream>>>(Zsw, gv, wpack, cbufg);
  out_kernel<<<384, 256, 0, stream>>>(Zsw, ftri, cbufg, wv_w, wv_b, (float*)d_out);
  hipMemcpyAsync((float*)d_out + NPAR * DD, H + NPAR * DD,
                 (1024 - NPAR) * DD * sizeof(float), hipMemcpyDeviceToDevice, stream);
}

// Round 13
// 343.181 us; speedup vs baseline: 1.0669x; 1.0038x over previous
//
#include <hip/hip_runtime.h>

#define NPAR 384
#define NEPI 384
#define DD   256
#define NTAB 4096
#define SMAX 96.0f
#define SDELTA (SMAX / NTAB)
#define SINVD (NTAB / SMAX)

using bf16x8 = __bf16 __attribute__((ext_vector_type(8)));
using bf16x2 = __bf16 __attribute__((ext_vector_type(2)));
using f32x4  = float __attribute__((ext_vector_type(4)));

#if defined(__has_builtin)
#if __has_builtin(__builtin_amdgcn_cvt_pk_bf16_f32)
#define HAVE_PK_BF16 1
#endif
#endif

__device__ __forceinline__ float sigm(float x) { return 1.0f / (1.0f + __expf(-x)); }
__device__ __forceinline__ float silu(float x) { return x / (1.0f + __expf(-x)); }
__device__ __forceinline__ unsigned short f2bf(float f) {
  unsigned u = __float_as_uint(f);
  u += 0x7fffu + ((u >> 16) & 1u);
  return (unsigned short)(u >> 16);
}
__device__ __forceinline__ float bf2f(unsigned u16) {
  return __uint_as_float(u16 << 16);
}
__device__ __forceinline__ float bf2f_lo(unsigned w) {
  return __uint_as_float(w << 16);
}
__device__ __forceinline__ float bf2f_hi(unsigned w) {
  return __uint_as_float(w & 0xffff0000u);
}
__device__ __forceinline__ uint2 pack4(float a, float b, float c, float d) {
  uint2 r;
#ifdef HAVE_PK_BF16
  bf16x2 lo = __builtin_amdgcn_cvt_pk_bf16_f32(a, b);
  bf16x2 hi = __builtin_amdgcn_cvt_pk_bf16_f32(c, d);
  r.x = __builtin_bit_cast(unsigned, lo);
  r.y = __builtin_bit_cast(unsigned, hi);
#else
  r.x = (unsigned)f2bf(a) | ((unsigned)f2bf(b) << 16);
  r.y = (unsigned)f2bf(c) | ((unsigned)f2bf(d) << 16);
#endif
  return r;
}

// ---------------- fused precompute kernel ----------------
// block ranges: [0,512) fold Mr/Ma ; [512] cvec (single block) ;
// [513,577) gvec ; [577,833) Wqk = wq@wk^T ; [833,2369) mm_rows4

__global__ void prep_kernel(
    const float* __restrict__ H, const float* __restrict__ wl,
    const float* __restrict__ wr, const float* __restrict__ int_w1,
    const float* __restrict__ res_w2, const float* __restrict__ atom_w2,
    const float* __restrict__ res_b2, const float* __restrict__ atom_b2,
    const float* __restrict__ int_b1, const float* __restrict__ simw,
    const float* __restrict__ wq_b, const float* __restrict__ wk_w,
    const float* __restrict__ wq_w,
    float* __restrict__ Hpl, float* __restrict__ Her,
    float* __restrict__ P1, float* __restrict__ P2,
    float* __restrict__ MrF, float* __restrict__ MaF,
    float* __restrict__ cvec, float* __restrict__ gv,
    float* __restrict__ WqkF) {
  __shared__ float sbuf[256];
  const int b = blockIdx.x, t = threadIdx.x;
  if (b < 512) {
    const int i = b & 255;
    const bool isMa = b >= 256;
    const float wmix = 1.0f / (1.0f + __expf(-simw[0]));
    const float sc = isMa ? (1.0f - wmix) : wmix;
    const float* W2 = isMa ? atom_w2 : res_w2;
    float acc = 0.f;
#pragma unroll 8
    for (int k = 0; k < 256; ++k)
      acc += W2[i * 256 + k] * int_w1[(512 + k) * 256 + t];
    (isMa ? MaF : MrF)[i * 256 + t] = acc * sc;
  } else if (b == 512) {
    const float wmix = 1.0f / (1.0f + __expf(-simw[0]));
    float acc = int_b1[t];
#pragma unroll 8
    for (int k = 0; k < 256; ++k) {
      float bm = wmix * res_b2[k] + (1.0f - wmix) * atom_b2[k];
      acc += bm * int_w1[(512 + k) * 256 + t];
    }
    cvec[t] = acc;
  } else if (b < 577) {
    const int lane = t & 63, w = t >> 6;
    const int d = (b - 513) * 4 + w;
    float acc = 0.f;
#pragma unroll
    for (int i = 0; i < 4; ++i) {
      const int c = i * 64 + lane;
      acc += wk_w[d * 256 + c] * wq_b[c];
    }
    acc += __shfl_xor(acc, 1);
    acc += __shfl_xor(acc, 2);
    acc += __shfl_xor(acc, 4);
    acc += __shfl_xor(acc, 8);
    acc += __shfl_xor(acc, 16);
    acc += __shfl_xor(acc, 32);
    if (lane == 0) gv[d] = acc;
  } else if (b < 833) {
    // Wqk[r][j] = sum_k wq[r][k] * wk[j][k]; r = b-577, j = t
    const int r = b - 577;
    sbuf[t] = wq_w[r * 256 + t];
    __syncthreads();
    const float* wkrow = wk_w + t * 256;
    float a0 = 0.f, a1 = 0.f, a2 = 0.f, a3 = 0.f;
#pragma unroll 4
    for (int k = 0; k < 256; k += 4) {
      const f32x4 wv4 = *reinterpret_cast<const f32x4*>(&wkrow[k]);
      a0 = fmaf(sbuf[k + 0], wv4[0], a0);
      a1 = fmaf(sbuf[k + 1], wv4[1], a1);
      a2 = fmaf(sbuf[k + 2], wv4[2], a2);
      a3 = fmaf(sbuf[k + 3], wv4[3], a3);
    }
    WqkF[r * 256 + t] = (a0 + a1) + (a2 + a3);
  } else {
    const int idx = b - 833;
    const int seg = idx / 384, r = idx % 384;
    const float* A;
    const float* B;
    float* C;
    switch (seg) {
      case 0:  A = H + r * 256;            B = wl;              C = Hpl + r * 256; break;
      case 1:  A = H + (NPAR + r) * 256;   B = wr;              C = Her + r * 256; break;
      case 2:  A = H + r * 256;            B = int_w1;          C = P1 + r * 256;  break;
      default: A = H + (NPAR + r) * 256;   B = int_w1 + 65536;  C = P2 + r * 256;  break;
    }
    float acc = 0.f;
#pragma unroll 8
    for (int k = 0; k < 256; ++k)
      acc += A[k] * B[k * 256 + t];
    C[t] = acc;
  }
}

// pack 5 [256,256] matrices into MFMA fragment order:
// wpack[m][((ks*16+tile)*64 + lane)*8 + j] = W[k = ks*32 + (lane>>4)*8 + j][n = tile*16 + (lane&15)]
// slots: 0=Mr 1=Ma 2=int_w2 3=wg 4=Wqk
__global__ void pack_kernel(const float* __restrict__ MrF, const float* __restrict__ MaF,
                            const float* __restrict__ w2, const float* __restrict__ wg,
                            const float* __restrict__ WqkF, unsigned short* __restrict__ wpack) {
  const int idx = blockIdx.x * 256 + threadIdx.x;
  const int m = idx >> 16;
  const int r = idx & 65535;
  const int chunk = r >> 9;
  const int lane = (r >> 3) & 63;
  const int j = r & 7;
  const int k = (chunk >> 4) * 32 + (lane >> 4) * 8 + j;
  const int n = (chunk & 15) * 16 + (lane & 15);
  const float* src;
  switch (m) {
    case 0: src = MrF; break;
    case 1: src = MaF; break;
    case 2: src = w2; break;
    case 3: src = wg; break;
    default: src = WqkF; break;
  }
  wpack[idx] = f2bf(src[k * 256 + n]);
}

// ---------------- shared GEMM helpers ----------------

__device__ __forceinline__ void zero_acc4(f32x4 (&acc)[4][4]) {
#pragma unroll
  for (int mt = 0; mt < 4; ++mt)
#pragma unroll
    for (int nt = 0; nt < 4; ++nt)
      acc[mt][nt] = (f32x4){0.f, 0.f, 0.f, 0.f};
}

// transposed-acc: mfma(Wfrag, ActFrag) -> acc^T[d][e]
// d = wv*64 + mt*16 + l4*4 + r, e = nt*16 + l15
__device__ __forceinline__ void gemm4(f32x4 (&acc)[4][4],
                                      const unsigned short* __restrict__ wp,
                                      const unsigned short* ub, int lane, int wv) {
  const int l15 = lane & 15, l4 = lane >> 4;
#pragma unroll
  for (int ks = 0; ks < 8; ++ks) {
    bf16x8 a[4];
#pragma unroll
    for (int mt = 0; mt < 4; ++mt)
      a[mt] = *reinterpret_cast<const bf16x8*>(wp + ((ks * 16 + wv * 4 + mt) * 64 + lane) * 8);
#pragma unroll
    for (int nt = 0; nt < 4; ++nt) {
      bf16x8 b = *reinterpret_cast<const bf16x8*>(ub + (nt * 16 + l15) * 264 + ks * 32 + l4 * 8);
#pragma unroll
      for (int mt = 0; mt < 4; ++mt)
        acc[mt][nt] = __builtin_amdgcn_mfma_f32_16x16x32_bf16(a[mt], b, acc[mt][nt], 0, 0, 0);
    }
  }
}

// fill ubuf[e][d] = silu(Sv[e]*w1[d] + b1[d])
__device__ __forceinline__ void fill_u(unsigned short* ub, const float* Sv,
                                       const float* __restrict__ w1,
                                       const float* __restrict__ b1, int t) {
  const int dg = t & 31, rb = t >> 5;
  const f32x4 w1a = *reinterpret_cast<const f32x4*>(&w1[dg * 8]);
  const f32x4 w1b = *reinterpret_cast<const f32x4*>(&w1[dg * 8 + 4]);
  const f32x4 b1a = *reinterpret_cast<const f32x4*>(&b1[dg * 8]);
  const f32x4 b1b = *reinterpret_cast<const f32x4*>(&b1[dg * 8 + 4]);
#pragma unroll
  for (int i = 0; i < 8; ++i) {
    const int e = rb + i * 8;
    const float s = Sv[e];
    uint2 lo = pack4(silu(fmaf(s, w1a[0], b1a[0])), silu(fmaf(s, w1a[1], b1a[1])),
                     silu(fmaf(s, w1a[2], b1a[2])), silu(fmaf(s, w1a[3], b1a[3])));
    uint2 hi = pack4(silu(fmaf(s, w1b[0], b1b[0])), silu(fmaf(s, w1b[1], b1b[1])),
                     silu(fmaf(s, w1b[2], b1b[2])), silu(fmaf(s, w1b[3], b1b[3])));
    uint4 pk = {lo.x, lo.y, hi.x, hi.y};
    *reinterpret_cast<uint4*>(&ub[e * 264 + dg * 8]) = pk;
  }
}

// ---------------- table build: tab[n][d] = F(n*SDELTA)[d] (wpack slots 0,1) ----------------

__global__ __launch_bounds__(256, 3) void tab_kernel(
    const float* __restrict__ res_w1, const float* __restrict__ res_b1,
    const float* __restrict__ atom_w1, const float* __restrict__ atom_b1,
    const unsigned short* __restrict__ wpack, unsigned short* __restrict__ tab) {
  __shared__ __align__(16) unsigned short ubuf[64 * 264];
  __shared__ float Sv[64];
  const int t = threadIdx.x, lane = t & 63, wv = t >> 6;
  const int l15 = lane & 15, l4 = lane >> 4;
  const int n0 = blockIdx.x * 64;
  if (t < 64) Sv[t] = (n0 + t) * SDELTA;
  __syncthreads();
  f32x4 acc[4][4];
  zero_acc4(acc);
  fill_u(ubuf, Sv, res_w1, res_b1, t);
  __syncthreads();
  gemm4(acc, wpack + 0 * 65536, ubuf, lane, wv);
  __syncthreads();
  fill_u(ubuf, Sv, atom_w1, atom_b1, t);
  __syncthreads();
  gemm4(acc, wpack + 1 * 65536, ubuf, lane, wv);
#pragma unroll
  for (int mt = 0; mt < 4; ++mt) {
    const int d = wv * 64 + mt * 16 + l4 * 4;
#pragma unroll
    for (int nt = 0; nt < 4; ++nt) {
      const int n = n0 + nt * 16 + l15;
      *reinterpret_cast<uint2*>(&tab[n * 256 + d]) =
          pack4(acc[mt][nt][0], acc[mt][nt][1], acc[mt][nt][2], acc[mt][nt][3]);
    }
  }
}

// ---------------- pairwise kernel (64-row tiles): table-interp h + 2 GEMMs ----------------

__global__ __launch_bounds__(256, 3) void pair_kernel(
    const float* __restrict__ Xg, const unsigned short* __restrict__ tab,
    const float* __restrict__ int_b2, const float* __restrict__ wg_b,
    const unsigned short* __restrict__ wpack, const float* __restrict__ cvec,
    const float* __restrict__ P1, const float* __restrict__ P2,
    const float* __restrict__ Hpl, const float* __restrict__ Her,
    float* __restrict__ ftri, unsigned short* __restrict__ Zsw) {
  __shared__ __align__(16) unsigned short ubuf[64 * 264];
  __shared__ float Sv[64];
  __shared__ float pc[DD];
  const int t = threadIdx.x, lane = t & 63, wv = t >> 6;
  const int l15 = lane & 15, l4 = lane >> 4;
  const int p = blockIdx.x / 6, cc = blockIdx.x % 6, e0 = cc * 64;
  const int d0 = wv * 64;

  if (t < 64) {
    const int e = e0 + t;
    float dx = Xg[p * 42 + 3] - Xg[(NPAR + e) * 42 + 3];
    float dy = Xg[p * 42 + 4] - Xg[(NPAR + e) * 42 + 4];
    float dz = Xg[p * 42 + 5] - Xg[(NPAR + e) * 42 + 5];
    Sv[t] = dx * dx + dy * dy + dz * dz;
  }
  pc[t] = P1[p * DD + t] + cvec[t];
  __syncthreads();

  // h-fill: h[e][d] = silu(lerp(tab, S[e])[d] + pc[d] + P2[e][d]) -> ubuf
  {
    const int dg = t & 31, rb = t >> 5;
    const f32x4 pca = *reinterpret_cast<const f32x4*>(&pc[dg * 8]);
    const f32x4 pcb = *reinterpret_cast<const f32x4*>(&pc[dg * 8 + 4]);
#pragma unroll
    for (int i = 0; i < 8; ++i) {
      const int e = rb + i * 8;
      float sv = Sv[e] * SINVD;
      int idx = (int)sv;
      idx = idx > (NTAB - 2) ? (NTAB - 2) : idx;
      const float fr = sv - (float)idx;
      const uint4 t0 = *reinterpret_cast<const uint4*>(&tab[idx * 256 + dg * 8]);
      const uint4 t1 = *reinterpret_cast<const uint4*>(&tab[(idx + 1) * 256 + dg * 8]);
      const f32x4 p2a = *reinterpret_cast<const f32x4*>(&P2[(e0 + e) * DD + dg * 8]);
      const f32x4 p2b = *reinterpret_cast<const f32x4*>(&P2[(e0 + e) * DD + dg * 8 + 4]);
      float z0 = bf2f_lo(t0.x), z1 = bf2f_hi(t0.x), z2 = bf2f_lo(t0.y), z3 = bf2f_hi(t0.y);
      float z4 = bf2f_lo(t0.z), z5 = bf2f_hi(t0.z), z6 = bf2f_lo(t0.w), z7 = bf2f_hi(t0.w);
      z0 = fmaf(fr, bf2f_lo(t1.x) - z0, z0) + pca[0] + p2a[0];
      z1 = fmaf(fr, bf2f_hi(t1.x) - z1, z1) + pca[1] + p2a[1];
      z2 = fmaf(fr, bf2f_lo(t1.y) - z2, z2) + pca[2] + p2a[2];
      z3 = fmaf(fr, bf2f_hi(t1.y) - z3, z3) + pca[3] + p2a[3];
      z4 = fmaf(fr, bf2f_lo(t1.z) - z4, z4) + pcb[0] + p2b[0];
      z5 = fmaf(fr, bf2f_hi(t1.z) - z5, z5) + pcb[1] + p2b[1];
      z6 = fmaf(fr, bf2f_lo(t1.w) - z6, z6) + pcb[2] + p2b[2];
      z7 = fmaf(fr, bf2f_hi(t1.w) - z7, z7) + pcb[3] + p2b[3];
      uint2 lo = pack4(silu(z0), silu(z1), silu(z2), silu(z3));
      uint2 hi = pack4(silu(z4), silu(z5), silu(z6), silu(z7));
      uint4 pk = {lo.x, lo.y, hi.x, hi.y};
      *reinterpret_cast<uint4*>(&ubuf[e * 264 + dg * 8]) = pk;
    }
  }
  __syncthreads();

  // Z = h @ int_w2 + int_b2 -> ubuf
  f32x4 acc[4][4];
  zero_acc4(acc);
  gemm4(acc, wpack + 2 * 65536, ubuf, lane, wv);
  __syncthreads();
#pragma unroll
  for (int mt = 0; mt < 4; ++mt) {
    const int d = d0 + mt * 16 + l4 * 4;
    const f32x4 bb = *reinterpret_cast<const f32x4*>(&int_b2[d]);
#pragma unroll
    for (int nt = 0; nt < 4; ++nt) {
      const int e = nt * 16 + l15;
      *reinterpret_cast<uint2*>(&ubuf[e * 264 + d]) =
          pack4(acc[mt][nt][0] + bb[0], acc[mt][nt][1] + bb[1],
                acc[mt][nt][2] + bb[2], acc[mt][nt][3] + bb[3]);
    }
  }
  __syncthreads();

  // swizzled MFMA-fragment-order store: grp = cc*4 + wv, e = grp*16 + l15
  {
    unsigned short* Zd = Zsw + (size_t)p * 98304 + (size_t)(cc * 4 + wv) * 4096 + lane * 8;
#pragma unroll
    for (int ks = 0; ks < 8; ++ks) {
      *reinterpret_cast<uint4*>(Zd + ks * 512) =
          *reinterpret_cast<const uint4*>(&ubuf[(wv * 16 + l15) * 264 + ks * 32 + l4 * 8]);
    }
  }

  // gate: f_tri[d] += Hpl[p][d] * sum_e sigm(Z@wg + b) * Her[e][d]
  zero_acc4(acc);
  gemm4(acc, wpack + 3 * 65536, ubuf, lane, wv);
#pragma unroll
  for (int mt = 0; mt < 4; ++mt) {
    const int d = d0 + mt * 16 + l4 * 4;
    const f32x4 bb = *reinterpret_cast<const f32x4*>(&wg_b[d]);
    const f32x4 hl = *reinterpret_cast<const f32x4*>(&Hpl[p * DD + d]);
    f32x4 fs = (f32x4){0.f, 0.f, 0.f, 0.f};
#pragma unroll
    for (int nt = 0; nt < 4; ++nt) {
      const int e = e0 + nt * 16 + l15;
      const f32x4 hr = *reinterpret_cast<const f32x4*>(&Her[e * DD + d]);
#pragma unroll
      for (int r = 0; r < 4; ++r)
        fs[r] += sigm(acc[mt][nt][r] + bb[r]) * hr[r];
    }
#pragma unroll
    for (int r = 0; r < 4; ++r) {
      float v = fs[r] * hl[r];
      v += __shfl_xor(v, 1);
      v += __shfl_xor(v, 2);
      v += __shfl_xor(v, 4);
      v += __shfl_xor(v, 8);
      if (l15 == 0) atomicAdd(&ftri[p * DD + d + r], v);
    }
  }
}

// ---------------- fused attention kernel: block = (p, 64-row chunk) ----------------
// scores = (Z_c Wqk + 1*gv^T) Z^T / 16 — gv and 1/16 folded into T.
// col-sums of softmax -> cbufg[p].  S-phase full 6+6 double-buffer.

__global__ __launch_bounds__(256, 3) void attn_kernel(
    const unsigned short* __restrict__ Zsw, const float* __restrict__ gv,
    const unsigned short* __restrict__ wpack, float* __restrict__ cbufg) {
  __shared__ __align__(16) unsigned short Tc[64 * 264];
  __shared__ float red[256];
  __shared__ float red2[256];
  const int t = threadIdx.x, lane = t & 63, wv = t >> 6;
  const int l15 = lane & 15, l4 = lane >> 4;
  // XCD swizzle: all 6 chunks of one p land on the same XCD (xcd = blk % 8)
  const int xcd = blockIdx.x & 7, inner = blockIdx.x >> 3;
  const int p = (inner / 6) * 8 + xcd, c = inner % 6;
  const unsigned short* Zsp = Zsw + (size_t)p * 98304;
  const unsigned short* wqk = wpack + 4 * 65536;

  // T' = (Zc @ Wqk + gv) / 16, b-frags double-buffered from Zsw
  {
    f32x4 ta[4][4];
    zero_acc4(ta);
    const unsigned short* Tb = Zsp + (size_t)(c * 4) * 4096 + lane * 8;
    bf16x8 bcur[4], bnxt[4];
#pragma unroll
    for (int nt = 0; nt < 4; ++nt)
      bcur[nt] = *reinterpret_cast<const bf16x8*>(Tb + nt * 4096);
#pragma unroll
    for (int ks = 0; ks < 8; ++ks) {
      if (ks < 7) {
#pragma unroll
        for (int nt = 0; nt < 4; ++nt)
          bnxt[nt] = *reinterpret_cast<const bf16x8*>(Tb + nt * 4096 + (ks + 1) * 512);
      }
      bf16x8 a[4];
#pragma unroll
      for (int mt = 0; mt < 4; ++mt)
        a[mt] = *reinterpret_cast<const bf16x8*>(wqk + ((ks * 16 + wv * 4 + mt) * 64 + lane) * 8);
#pragma unroll
      for (int nt = 0; nt < 4; ++nt)
#pragma unroll
        for (int mt = 0; mt < 4; ++mt)
          ta[mt][nt] = __builtin_amdgcn_mfma_f32_16x16x32_bf16(a[mt], bcur[nt], ta[mt][nt], 0, 0, 0);
      if (ks < 7) {
#pragma unroll
        for (int nt = 0; nt < 4; ++nt) bcur[nt] = bnxt[nt];
      }
    }
#pragma unroll
    for (int mt = 0; mt < 4; ++mt) {
      const int d = wv * 64 + mt * 16 + l4 * 4;
      const f32x4 gq = *reinterpret_cast<const f32x4*>(&gv[d]);
#pragma unroll
      for (int nt = 0; nt < 4; ++nt) {
        const int e = nt * 16 + l15;
        *reinterpret_cast<uint2*>(&Tc[e * 264 + d]) =
            pack4((ta[mt][nt][0] + gq[0]) * 0.0625f, (ta[mt][nt][1] + gq[1]) * 0.0625f,
                  (ta[mt][nt][2] + gq[2]) * 0.0625f, (ta[mt][nt][3] + gq[3]) * 0.0625f);
      }
    }
  }
  __syncthreads();

  // S = Tc @ Z^T; a-frags from LDS, b-frags full 6+6 double-buffer from Zsw
  f32x4 sc[4][6];
#pragma unroll
  for (int mt = 0; mt < 4; ++mt)
#pragma unroll
    for (int s = 0; s < 6; ++s) sc[mt][s] = (f32x4){0.f, 0.f, 0.f, 0.f};

  {
    const unsigned short* Sb = Zsp + (size_t)wv * 4096 + lane * 8;
    bf16x8 bcur[6], bnxt[6];
#pragma unroll
    for (int s = 0; s < 6; ++s)
      bcur[s] = *reinterpret_cast<const bf16x8*>(Sb + s * 16384);
#pragma unroll
    for (int ks = 0; ks < 8; ++ks) {
      if (ks < 7) {
#pragma unroll
        for (int s = 0; s < 6; ++s)
          bnxt[s] = *reinterpret_cast<const bf16x8*>(Sb + s * 16384 + (ks + 1) * 512);
      }
      bf16x8 a[4];
#pragma unroll
      for (int mt = 0; mt < 4; ++mt)
        a[mt] = *reinterpret_cast<const bf16x8*>(&Tc[(mt * 16 + l15) * 264 + ks * 32 + l4 * 8]);
#pragma unroll
      for (int s = 0; s < 6; ++s)
#pragma unroll
        for (int mt = 0; mt < 4; ++mt)
          sc[mt][s] = __builtin_amdgcn_mfma_f32_16x16x32_bf16(a[mt], bcur[s], sc[mt][s], 0, 0, 0);
      if (ks < 7) {
#pragma unroll
        for (int s = 0; s < 6; ++s) bcur[s] = bnxt[s];
      }
    }
  }

  // softmax over f (384 cols), rows e = mt*16 + l4*4 + r; sc already scaled
  float rmax[4][4];
#pragma unroll
  for (int mt = 0; mt < 4; ++mt) {
#pragma unroll
    for (int r = 0; r < 4; ++r) {
      float m = -1e30f;
#pragma unroll
      for (int s = 0; s < 6; ++s) m = fmaxf(m, sc[mt][s][r]);
      m = fmaxf(m, __shfl_xor(m, 1));
      m = fmaxf(m, __shfl_xor(m, 2));
      m = fmaxf(m, __shfl_xor(m, 4));
      m = fmaxf(m, __shfl_xor(m, 8));
      rmax[mt][r] = m;
    }
  }
  if (l15 == 0) {
#pragma unroll
    for (int mt = 0; mt < 4; ++mt)
#pragma unroll
      for (int r = 0; r < 4; ++r)
        red[wv * 64 + mt * 16 + l4 * 4 + r] = rmax[mt][r];
  }
  __syncthreads();
#pragma unroll
  for (int mt = 0; mt < 4; ++mt) {
#pragma unroll
    for (int r = 0; r < 4; ++r) {
      const int row = mt * 16 + l4 * 4 + r;
      rmax[mt][r] = fmaxf(fmaxf(red[row], red[64 + row]), fmaxf(red[128 + row], red[192 + row]));
    }
  }

  float rsum[4][4];
#pragma unroll
  for (int mt = 0; mt < 4; ++mt) {
#pragma unroll
    for (int r = 0; r < 4; ++r) {
      float sSum = 0.f;
#pragma unroll
      for (int s = 0; s < 6; ++s) {
        float e = __expf(sc[mt][s][r] - rmax[mt][r]);
        sc[mt][s][r] = e;
        sSum += e;
      }
      sSum += __shfl_xor(sSum, 1);
      sSum += __shfl_xor(sSum, 2);
      sSum += __shfl_xor(sSum, 4);
      sSum += __shfl_xor(sSum, 8);
      rsum[mt][r] = sSum;
    }
  }
  if (l15 == 0) {
#pragma unroll
    for (int mt = 0; mt < 4; ++mt)
#pragma unroll
      for (int r = 0; r < 4; ++r)
        red2[wv * 64 + mt * 16 + l4 * 4 + r] = rsum[mt][r];
  }
  __syncthreads();
  float rinv[4][4];
#pragma unroll
  for (int mt = 0; mt < 4; ++mt) {
#pragma unroll
    for (int r = 0; r < 4; ++r) {
      const int row = mt * 16 + l4 * 4 + r;
      rinv[mt][r] = 1.0f / (red2[row] + red2[64 + row] + red2[128 + row] + red2[192 + row]);
    }
  }

  // column sums of A over this chunk's 64 rows -> cbufg
#pragma unroll
  for (int s = 0; s < 6; ++s) {
    float v = 0.f;
#pragma unroll
    for (int mt = 0; mt < 4; ++mt)
#pragma unroll
      for (int r = 0; r < 4; ++r)
        v += sc[mt][s][r] * rinv[mt][r];
    v += __shfl_xor(v, 16);
    v += __shfl_xor(v, 32);
    if (lane < 16)
      atomicAdd(&cbufg[p * NEPI + s * 64 + wv * 16 + lane], v);
  }
}

// ---------------- output part A: u[p][d] partial over one f-third ----------------
// block = (p, third); reads 8 grps (128 f) of Zsw, LDS-reduce, atomicAdd into ubufg.

__global__ __launch_bounds__(256) void outa_kernel(
    const unsigned short* __restrict__ Zsw, const float* __restrict__ cbufg,
    float* __restrict__ ubufg) {
  __shared__ float cb[128];
  __shared__ float part[16][257];
  const int p = blockIdx.x / 3, th = blockIdx.x % 3, g0 = th * 8;
  const int t = threadIdx.x;
  const int lane = t & 63, wv = t >> 6;
  const int l15 = lane & 15, l4 = lane >> 4;
  if (t < 128) cb[t] = cbufg[p * NEPI + g0 * 16 + t];
  __syncthreads();
  const unsigned short* Zsp = Zsw + (size_t)p * 98304;
  float a16[16];
#pragma unroll
  for (int j = 0; j < 16; ++j) a16[j] = 0.f;
#pragma unroll
  for (int gr = 0; gr < 8; ++gr) {
    const int grp = g0 + gr;
    const float w = cb[gr * 16 + l15];
    const uint4 z0 = *reinterpret_cast<const uint4*>(Zsp + grp * 4096 + wv * 512 + lane * 8);
    const uint4 z1 = *reinterpret_cast<const uint4*>(Zsp + grp * 4096 + (wv + 4) * 512 + lane * 8);
    a16[0] = fmaf(w, bf2f(z0.x & 0xffffu), a16[0]);
    a16[1] = fmaf(w, bf2f(z0.x >> 16), a16[1]);
    a16[2] = fmaf(w, bf2f(z0.y & 0xffffu), a16[2]);
    a16[3] = fmaf(w, bf2f(z0.y >> 16), a16[3]);
    a16[4] = fmaf(w, bf2f(z0.z & 0xffffu), a16[4]);
    a16[5] = fmaf(w, bf2f(z0.z >> 16), a16[5]);
    a16[6] = fmaf(w, bf2f(z0.w & 0xffffu), a16[6]);
    a16[7] = fmaf(w, bf2f(z0.w >> 16), a16[7]);
    a16[8]  = fmaf(w, bf2f(z1.x & 0xffffu), a16[8]);
    a16[9]  = fmaf(w, bf2f(z1.x >> 16), a16[9]);
    a16[10] = fmaf(w, bf2f(z1.y & 0xffffu), a16[10]);
    a16[11] = fmaf(w, bf2f(z1.y >> 16), a16[11]);
    a16[12] = fmaf(w, bf2f(z1.z & 0xffffu), a16[12]);
    a16[13] = fmaf(w, bf2f(z1.z >> 16), a16[13]);
    a16[14] = fmaf(w, bf2f(z1.w & 0xffffu), a16[14]);
    a16[15] = fmaf(w, bf2f(z1.w >> 16), a16[15]);
  }
#pragma unroll
  for (int j = 0; j < 8; ++j) part[l15][wv * 32 + l4 * 8 + j] = a16[j];
#pragma unroll
  for (int j = 0; j < 8; ++j) part[l15][128 + wv * 32 + l4 * 8 + j] = a16[8 + j];
  __syncthreads();
  float uu = 0.f;
#pragma unroll
  for (int g = 0; g < 16; ++g) uu += part[g][t];
  atomicAdd(&ubufg[p * DD + t], uu);
}

// ---------------- output part B: out[p] = (ftri + u@wv + 384*bv)/384 ----------------

__global__ __launch_bounds__(256) void out2_kernel(
    const float* __restrict__ ubufg, const float* __restrict__ ftri,
    const float* __restrict__ wvw, const float* __restrict__ wvb,
    float* __restrict__ out) {
  __shared__ float u[DD];
  const int p = blockIdx.x, t = threadIdx.x;
  u[t] = ubufg[p * DD + t];
  __syncthreads();
  float acc = ftri[p * DD + t] + 384.0f * wvb[t];
#pragma unroll 8
  for (int d = 0; d < DD; ++d)
    acc = fmaf(u[d], wvw[d * DD + t], acc);
  out[p * DD + t] = acc * (1.0f / 384.0f);
}

// ---------------- launch ----------------

extern "C" void kernel_launch(void* const* d_in, const int* in_sizes, int n_in,
                              void* d_out, int out_size, void* d_ws, size_t ws_size,
                              hipStream_t stream) {
  (void)in_sizes; (void)n_in; (void)out_size; (void)ws_size;
  const float* H = (const float*)d_in[0];
  const float* X = (const float*)d_in[1];
  const float* res_w1 = (const float*)d_in[4];
  const float* res_b1 = (const float*)d_in[5];
  const float* res_w2 = (const float*)d_in[6];
  const float* res_b2 = (const float*)d_in[7];
  const float* atom_w1 = (const float*)d_in[8];
  const float* atom_b1 = (const float*)d_in[9];
  const float* atom_w2 = (const float*)d_in[10];
  const float* atom_b2 = (const float*)d_in[11];
  const float* simw = (const float*)d_in[12];
  const float* int_w1 = (const float*)d_in[13];
  const float* int_b1 = (const float*)d_in[14];
  const float* int_w2 = (const float*)d_in[15];
  const float* int_b2 = (const float*)d_in[16];
  const float* wl = (const float*)d_in[17];
  const float* wr = (const float*)d_in[18];
  const float* wg_w = (const float*)d_in[19];
  const float* wg_b = (const float*)d_in[20];
  const float* wq_w = (const float*)d_in[21];
  const float* wq_b = (const float*)d_in[22];
  const float* wk_w = (const float*)d_in[23];
  const float* wv_w = (const float*)d_in[25];
  const float* wv_b = (const float*)d_in[26];

  char* ws = (char*)d_ws;
  unsigned short* wpack = (unsigned short*)(ws + 0);      //  655360 B (5 slots)
  float* MrF   = (float*)(ws + 655360);                   //  262144 B
  float* MaF   = (float*)(ws + 917504);                   //  262144 B
  float* WqkF  = (float*)(ws + 1179648);                  //  262144 B
  float* cvec  = (float*)(ws + 1441792);                  //    1024 B
  float* gv    = (float*)(ws + 1442816);                  //    1024 B
  float* P1    = (float*)(ws + 1443840);                  //  393216 B
  float* P2    = (float*)(ws + 1837056);                  //  393216 B
  float* Hpl   = (float*)(ws + 2230272);                  //  393216 B
  float* Her   = (float*)(ws + 2623488);                  //  393216 B
  float* ftri  = (float*)(ws + 3016704);                  //  393216 B
  float* cbufg = (float*)(ws + 3409920);                  //  589824 B
  float* ubufg = (float*)(ws + 3999744);                  //  393216 B
  unsigned short* Zsw = (unsigned short*)(ws + 4392960);  // 75497472 B
  unsigned short* tab = (unsigned short*)(ws + 79890432); //  2097152 B

  // single memset covering ftri + cbufg + ubufg (contiguous)
  hipMemsetAsync(ftri, 0, 393216 + 589824 + 393216, stream);
  prep_kernel<<<2369, 256, 0, stream>>>(H, wl, wr, int_w1, res_w2, atom_w2,
                                        res_b2, atom_b2, int_b1, simw, wq_b, wk_w, wq_w,
                                        Hpl, Her, P1, P2, MrF, MaF, cvec, gv, WqkF);
  pack_kernel<<<1280, 256, 0, stream>>>(MrF, MaF, int_w2, wg_w, WqkF, wpack);
  tab_kernel<<<NTAB / 64, 256, 0, stream>>>(res_w1, res_b1, atom_w1, atom_b1, wpack, tab);
  pair_kernel<<<2304, 256, 0, stream>>>(X, tab, int_b2, wg_b, wpack, cvec,
                                        P1, P2, Hpl, Her, ftri, Zsw);
  attn_kernel<<<2304, 256, 0, stream>>>(Zsw, gv, wpack, cbufg);
  outa_kernel<<<1152, 256, 0, stream>>>(Zsw, cbufg, ubufg);
  out2_kernel<<<384, 256, 0, stream>>>(ubufg, ftri, wv_w, wv_b, (float*)d_out);
  hipMemcpyAsync((float*)d_out + NPAR * DD, H + NPAR * DD,
                 (1024 - NPAR) * DD * sizeof(float), hipMemcpyDeviceToDevice, stream);
}

// Round 14
// 340.843 us; speedup vs baseline: 1.0742x; 1.0069x over previous
//
#include <hip/hip_runtime.h>

#define NPAR 384
#define NEPI 384
#define DD   256
#define NTAB 4096
#define SMAX 96.0f
#define SDELTA (SMAX / NTAB)
#define SINVD (NTAB / SMAX)

using bf16x8 = __bf16 __attribute__((ext_vector_type(8)));
using bf16x2 = __bf16 __attribute__((ext_vector_type(2)));
using f32x4  = float __attribute__((ext_vector_type(4)));

#if defined(__has_builtin)
#if __has_builtin(__builtin_amdgcn_cvt_pk_bf16_f32)
#define HAVE_PK_BF16 1
#endif
#endif

__device__ __forceinline__ float sigm(float x) { return 1.0f / (1.0f + __expf(-x)); }
__device__ __forceinline__ float silu(float x) { return x / (1.0f + __expf(-x)); }
__device__ __forceinline__ unsigned short f2bf(float f) {
  unsigned u = __float_as_uint(f);
  u += 0x7fffu + ((u >> 16) & 1u);
  return (unsigned short)(u >> 16);
}
__device__ __forceinline__ float bf2f(unsigned u16) {
  return __uint_as_float(u16 << 16);
}
__device__ __forceinline__ float bf2f_lo(unsigned w) {
  return __uint_as_float(w << 16);
}
__device__ __forceinline__ float bf2f_hi(unsigned w) {
  return __uint_as_float(w & 0xffff0000u);
}
__device__ __forceinline__ uint2 pack4(float a, float b, float c, float d) {
  uint2 r;
#ifdef HAVE_PK_BF16
  bf16x2 lo = __builtin_amdgcn_cvt_pk_bf16_f32(a, b);
  bf16x2 hi = __builtin_amdgcn_cvt_pk_bf16_f32(c, d);
  r.x = __builtin_bit_cast(unsigned, lo);
  r.y = __builtin_bit_cast(unsigned, hi);
#else
  r.x = (unsigned)f2bf(a) | ((unsigned)f2bf(b) << 16);
  r.y = (unsigned)f2bf(c) | ((unsigned)f2bf(d) << 16);
#endif
  return r;
}

// ---------------- fused precompute kernel ----------------
// block ranges: [0,512) fold Mr/Ma ; [512] cvec ; [513,577) gvec ;
// [577,833) Wqk = wq@wk^T ; [833,2369) mm_rows4

__global__ void prep_kernel(
    const float* __restrict__ H, const float* __restrict__ wl,
    const float* __restrict__ wr, const float* __restrict__ int_w1,
    const float* __restrict__ res_w2, const float* __restrict__ atom_w2,
    const float* __restrict__ res_b2, const float* __restrict__ atom_b2,
    const float* __restrict__ int_b1, const float* __restrict__ simw,
    const float* __restrict__ wq_b, const float* __restrict__ wk_w,
    const float* __restrict__ wq_w,
    float* __restrict__ Hpl, float* __restrict__ Her,
    float* __restrict__ P1, float* __restrict__ P2,
    float* __restrict__ MrF, float* __restrict__ MaF,
    float* __restrict__ cvec, float* __restrict__ gv,
    float* __restrict__ WqkF) {
  __shared__ float sbuf[256];
  const int b = blockIdx.x, t = threadIdx.x;
  if (b < 512) {
    const int i = b & 255;
    const bool isMa = b >= 256;
    const float wmix = 1.0f / (1.0f + __expf(-simw[0]));
    const float sc = isMa ? (1.0f - wmix) : wmix;
    const float* W2 = isMa ? atom_w2 : res_w2;
    float acc = 0.f;
#pragma unroll 8
    for (int k = 0; k < 256; ++k)
      acc += W2[i * 256 + k] * int_w1[(512 + k) * 256 + t];
    (isMa ? MaF : MrF)[i * 256 + t] = acc * sc;
  } else if (b == 512) {
    const float wmix = 1.0f / (1.0f + __expf(-simw[0]));
    float acc = int_b1[t];
#pragma unroll 8
    for (int k = 0; k < 256; ++k) {
      float bm = wmix * res_b2[k] + (1.0f - wmix) * atom_b2[k];
      acc += bm * int_w1[(512 + k) * 256 + t];
    }
    cvec[t] = acc;
  } else if (b < 577) {
    const int lane = t & 63, w = t >> 6;
    const int d = (b - 513) * 4 + w;
    float acc = 0.f;
#pragma unroll
    for (int i = 0; i < 4; ++i) {
      const int c = i * 64 + lane;
      acc += wk_w[d * 256 + c] * wq_b[c];
    }
    acc += __shfl_xor(acc, 1);
    acc += __shfl_xor(acc, 2);
    acc += __shfl_xor(acc, 4);
    acc += __shfl_xor(acc, 8);
    acc += __shfl_xor(acc, 16);
    acc += __shfl_xor(acc, 32);
    if (lane == 0) gv[d] = acc;
  } else if (b < 833) {
    const int r = b - 577;
    sbuf[t] = wq_w[r * 256 + t];
    __syncthreads();
    const float* wkrow = wk_w + t * 256;
    float a0 = 0.f, a1 = 0.f, a2 = 0.f, a3 = 0.f;
#pragma unroll 4
    for (int k = 0; k < 256; k += 4) {
      const f32x4 wv4 = *reinterpret_cast<const f32x4*>(&wkrow[k]);
      a0 = fmaf(sbuf[k + 0], wv4[0], a0);
      a1 = fmaf(sbuf[k + 1], wv4[1], a1);
      a2 = fmaf(sbuf[k + 2], wv4[2], a2);
      a3 = fmaf(sbuf[k + 3], wv4[3], a3);
    }
    WqkF[r * 256 + t] = (a0 + a1) + (a2 + a3);
  } else {
    const int idx = b - 833;
    const int seg = idx / 384, r = idx % 384;
    const float* A;
    const float* B;
    float* C;
    switch (seg) {
      case 0:  A = H + r * 256;            B = wl;              C = Hpl + r * 256; break;
      case 1:  A = H + (NPAR + r) * 256;   B = wr;              C = Her + r * 256; break;
      case 2:  A = H + r * 256;            B = int_w1;          C = P1 + r * 256;  break;
      default: A = H + (NPAR + r) * 256;   B = int_w1 + 65536;  C = P2 + r * 256;  break;
    }
    float acc = 0.f;
#pragma unroll 8
    for (int k = 0; k < 256; ++k)
      acc += A[k] * B[k * 256 + t];
    C[t] = acc;
  }
}

// pack 5 [256,256] matrices into MFMA fragment order:
// slots: 0=Mr 1=Ma 2=int_w2 3=wg 4=Wqk
__global__ void pack_kernel(const float* __restrict__ MrF, const float* __restrict__ MaF,
                            const float* __restrict__ w2, const float* __restrict__ wg,
                            const float* __restrict__ WqkF, unsigned short* __restrict__ wpack) {
  const int idx = blockIdx.x * 256 + threadIdx.x;
  const int m = idx >> 16;
  const int r = idx & 65535;
  const int chunk = r >> 9;
  const int lane = (r >> 3) & 63;
  const int j = r & 7;
  const int k = (chunk >> 4) * 32 + (lane >> 4) * 8 + j;
  const int n = (chunk & 15) * 16 + (lane & 15);
  const float* src;
  switch (m) {
    case 0: src = MrF; break;
    case 1: src = MaF; break;
    case 2: src = w2; break;
    case 3: src = wg; break;
    default: src = WqkF; break;
  }
  wpack[idx] = f2bf(src[k * 256 + n]);
}

// ---------------- shared GEMM helpers ----------------

__device__ __forceinline__ void zero_acc4(f32x4 (&acc)[4][4]) {
#pragma unroll
  for (int mt = 0; mt < 4; ++mt)
#pragma unroll
    for (int nt = 0; nt < 4; ++nt)
      acc[mt][nt] = (f32x4){0.f, 0.f, 0.f, 0.f};
}

// transposed-acc: mfma(Wfrag, ActFrag) -> acc^T[d][e]
__device__ __forceinline__ void gemm4(f32x4 (&acc)[4][4],
                                      const unsigned short* __restrict__ wp,
                                      const unsigned short* ub, int lane, int wv) {
  const int l15 = lane & 15, l4 = lane >> 4;
#pragma unroll
  for (int ks = 0; ks < 8; ++ks) {
    bf16x8 a[4];
#pragma unroll
    for (int mt = 0; mt < 4; ++mt)
      a[mt] = *reinterpret_cast<const bf16x8*>(wp + ((ks * 16 + wv * 4 + mt) * 64 + lane) * 8);
#pragma unroll
    for (int nt = 0; nt < 4; ++nt) {
      bf16x8 b = *reinterpret_cast<const bf16x8*>(ub + (nt * 16 + l15) * 264 + ks * 32 + l4 * 8);
#pragma unroll
      for (int mt = 0; mt < 4; ++mt)
        acc[mt][nt] = __builtin_amdgcn_mfma_f32_16x16x32_bf16(a[mt], b, acc[mt][nt], 0, 0, 0);
    }
  }
}

// fill ubuf[e][d] = silu(Sv[e]*w1[d] + b1[d])
__device__ __forceinline__ void fill_u(unsigned short* ub, const float* Sv,
                                       const float* __restrict__ w1,
                                       const float* __restrict__ b1, int t) {
  const int dg = t & 31, rb = t >> 5;
  const f32x4 w1a = *reinterpret_cast<const f32x4*>(&w1[dg * 8]);
  const f32x4 w1b = *reinterpret_cast<const f32x4*>(&w1[dg * 8 + 4]);
  const f32x4 b1a = *reinterpret_cast<const f32x4*>(&b1[dg * 8]);
  const f32x4 b1b = *reinterpret_cast<const f32x4*>(&b1[dg * 8 + 4]);
#pragma unroll
  for (int i = 0; i < 8; ++i) {
    const int e = rb + i * 8;
    const float s = Sv[e];
    uint2 lo = pack4(silu(fmaf(s, w1a[0], b1a[0])), silu(fmaf(s, w1a[1], b1a[1])),
                     silu(fmaf(s, w1a[2], b1a[2])), silu(fmaf(s, w1a[3], b1a[3])));
    uint2 hi = pack4(silu(fmaf(s, w1b[0], b1b[0])), silu(fmaf(s, w1b[1], b1b[1])),
                     silu(fmaf(s, w1b[2], b1b[2])), silu(fmaf(s, w1b[3], b1b[3])));
    uint4 pk = {lo.x, lo.y, hi.x, hi.y};
    *reinterpret_cast<uint4*>(&ub[e * 264 + dg * 8]) = pk;
  }
}

// ---------------- table build: tab[n][d] = F(n*SDELTA)[d] (wpack slots 0,1) ----------------

__global__ __launch_bounds__(256, 3) void tab_kernel(
    const float* __restrict__ res_w1, const float* __restrict__ res_b1,
    const float* __restrict__ atom_w1, const float* __restrict__ atom_b1,
    const unsigned short* __restrict__ wpack, unsigned short* __restrict__ tab) {
  __shared__ __align__(16) unsigned short ubuf[64 * 264];
  __shared__ float Sv[64];
  const int t = threadIdx.x, lane = t & 63, wv = t >> 6;
  const int l15 = lane & 15, l4 = lane >> 4;
  const int n0 = blockIdx.x * 64;
  if (t < 64) Sv[t] = (n0 + t) * SDELTA;
  __syncthreads();
  f32x4 acc[4][4];
  zero_acc4(acc);
  fill_u(ubuf, Sv, res_w1, res_b1, t);
  __syncthreads();
  gemm4(acc, wpack + 0 * 65536, ubuf, lane, wv);
  __syncthreads();
  fill_u(ubuf, Sv, atom_w1, atom_b1, t);
  __syncthreads();
  gemm4(acc, wpack + 1 * 65536, ubuf, lane, wv);
#pragma unroll
  for (int mt = 0; mt < 4; ++mt) {
    const int d = wv * 64 + mt * 16 + l4 * 4;
#pragma unroll
    for (int nt = 0; nt < 4; ++nt) {
      const int n = n0 + nt * 16 + l15;
      *reinterpret_cast<uint2*>(&tab[n * 256 + d]) =
          pack4(acc[mt][nt][0], acc[mt][nt][1], acc[mt][nt][2], acc[mt][nt][3]);
    }
  }
}

// ---------------- pairwise kernel (64-row tiles): table-interp h + 2 GEMMs ----------------
// r14: __launch_bounds__(256,4) — VGPR use is 76 <= 512/4=128 cap, LDS 4x35.3KB fits.

__global__ __launch_bounds__(256, 4) void pair_kernel(
    const float* __restrict__ Xg, const unsigned short* __restrict__ tab,
    const float* __restrict__ int_b2, const float* __restrict__ wg_b,
    const unsigned short* __restrict__ wpack, const float* __restrict__ cvec,
    const float* __restrict__ P1, const float* __restrict__ P2,
    const float* __restrict__ Hpl, const float* __restrict__ Her,
    float* __restrict__ ftri, unsigned short* __restrict__ Zsw) {
  __shared__ __align__(16) unsigned short ubuf[64 * 264];
  __shared__ float Sv[64];
  __shared__ float pc[DD];
  const int t = threadIdx.x, lane = t & 63, wv = t >> 6;
  const int l15 = lane & 15, l4 = lane >> 4;
  const int p = blockIdx.x / 6, cc = blockIdx.x % 6, e0 = cc * 64;
  const int d0 = wv * 64;

  if (t < 64) {
    const int e = e0 + t;
    float dx = Xg[p * 42 + 3] - Xg[(NPAR + e) * 42 + 3];
    float dy = Xg[p * 42 + 4] - Xg[(NPAR + e) * 42 + 4];
    float dz = Xg[p * 42 + 5] - Xg[(NPAR + e) * 42 + 5];
    Sv[t] = dx * dx + dy * dy + dz * dz;
  }
  pc[t] = P1[p * DD + t] + cvec[t];
  __syncthreads();

  // h-fill: h[e][d] = silu(lerp(tab, S[e])[d] + pc[d] + P2[e][d]) -> ubuf
  {
    const int dg = t & 31, rb = t >> 5;
    const f32x4 pca = *reinterpret_cast<const f32x4*>(&pc[dg * 8]);
    const f32x4 pcb = *reinterpret_cast<const f32x4*>(&pc[dg * 8 + 4]);
#pragma unroll
    for (int i = 0; i < 8; ++i) {
      const int e = rb + i * 8;
      float sv = Sv[e] * SINVD;
      int idx = (int)sv;
      idx = idx > (NTAB - 2) ? (NTAB - 2) : idx;
      const float fr = sv - (float)idx;
      const uint4 t0 = *reinterpret_cast<const uint4*>(&tab[idx * 256 + dg * 8]);
      const uint4 t1 = *reinterpret_cast<const uint4*>(&tab[(idx + 1) * 256 + dg * 8]);
      const f32x4 p2a = *reinterpret_cast<const f32x4*>(&P2[(e0 + e) * DD + dg * 8]);
      const f32x4 p2b = *reinterpret_cast<const f32x4*>(&P2[(e0 + e) * DD + dg * 8 + 4]);
      float z0 = bf2f_lo(t0.x), z1 = bf2f_hi(t0.x), z2 = bf2f_lo(t0.y), z3 = bf2f_hi(t0.y);
      float z4 = bf2f_lo(t0.z), z5 = bf2f_hi(t0.z), z6 = bf2f_lo(t0.w), z7 = bf2f_hi(t0.w);
      z0 = fmaf(fr, bf2f_lo(t1.x) - z0, z0) + pca[0] + p2a[0];
      z1 = fmaf(fr, bf2f_hi(t1.x) - z1, z1) + pca[1] + p2a[1];
      z2 = fmaf(fr, bf2f_lo(t1.y) - z2, z2) + pca[2] + p2a[2];
      z3 = fmaf(fr, bf2f_hi(t1.y) - z3, z3) + pca[3] + p2a[3];
      z4 = fmaf(fr, bf2f_lo(t1.z) - z4, z4) + pcb[0] + p2b[0];
      z5 = fmaf(fr, bf2f_hi(t1.z) - z5, z5) + pcb[1] + p2b[1];
      z6 = fmaf(fr, bf2f_lo(t1.w) - z6, z6) + pcb[2] + p2b[2];
      z7 = fmaf(fr, bf2f_hi(t1.w) - z7, z7) + pcb[3] + p2b[3];
      uint2 lo = pack4(silu(z0), silu(z1), silu(z2), silu(z3));
      uint2 hi = pack4(silu(z4), silu(z5), silu(z6), silu(z7));
      uint4 pk = {lo.x, lo.y, hi.x, hi.y};
      *reinterpret_cast<uint4*>(&ubuf[e * 264 + dg * 8]) = pk;
    }
  }
  __syncthreads();

  // Z = h @ int_w2 + int_b2 -> ubuf
  f32x4 acc[4][4];
  zero_acc4(acc);
  gemm4(acc, wpack + 2 * 65536, ubuf, lane, wv);
  __syncthreads();
#pragma unroll
  for (int mt = 0; mt < 4; ++mt) {
    const int d = d0 + mt * 16 + l4 * 4;
    const f32x4 bb = *reinterpret_cast<const f32x4*>(&int_b2[d]);
#pragma unroll
    for (int nt = 0; nt < 4; ++nt) {
      const int e = nt * 16 + l15;
      *reinterpret_cast<uint2*>(&ubuf[e * 264 + d]) =
          pack4(acc[mt][nt][0] + bb[0], acc[mt][nt][1] + bb[1],
                acc[mt][nt][2] + bb[2], acc[mt][nt][3] + bb[3]);
    }
  }
  __syncthreads();

  // swizzled MFMA-fragment-order store: grp = cc*4 + wv, e = grp*16 + l15
  {
    unsigned short* Zd = Zsw + (size_t)p * 98304 + (size_t)(cc * 4 + wv) * 4096 + lane * 8;
#pragma unroll
    for (int ks = 0; ks < 8; ++ks) {
      *reinterpret_cast<uint4*>(Zd + ks * 512) =
          *reinterpret_cast<const uint4*>(&ubuf[(wv * 16 + l15) * 264 + ks * 32 + l4 * 8]);
    }
  }

  // gate: f_tri[d] += Hpl[p][d] * sum_e sigm(Z@wg + b) * Her[e][d]
  zero_acc4(acc);
  gemm4(acc, wpack + 3 * 65536, ubuf, lane, wv);
#pragma unroll
  for (int mt = 0; mt < 4; ++mt) {
    const int d = d0 + mt * 16 + l4 * 4;
    const f32x4 bb = *reinterpret_cast<const f32x4*>(&wg_b[d]);
    const f32x4 hl = *reinterpret_cast<const f32x4*>(&Hpl[p * DD + d]);
    f32x4 fs = (f32x4){0.f, 0.f, 0.f, 0.f};
#pragma unroll
    for (int nt = 0; nt < 4; ++nt) {
      const int e = e0 + nt * 16 + l15;
      const f32x4 hr = *reinterpret_cast<const f32x4*>(&Her[e * DD + d]);
#pragma unroll
      for (int r = 0; r < 4; ++r)
        fs[r] += sigm(acc[mt][nt][r] + bb[r]) * hr[r];
    }
#pragma unroll
    for (int r = 0; r < 4; ++r) {
      float v = fs[r] * hl[r];
      v += __shfl_xor(v, 1);
      v += __shfl_xor(v, 2);
      v += __shfl_xor(v, 4);
      v += __shfl_xor(v, 8);
      if (l15 == 0) atomicAdd(&ftri[p * DD + d + r], v);
    }
  }
}

// ---------------- fused attention kernel: block = (p, 64-row chunk) ----------------
// scores = (Z_c Wqk + 1*gv^T) Z^T / 16 — gv and 1/16 folded into T.
// col-sums of softmax -> cbufg[p].  S-phase full 6+6 double-buffer.

__global__ __launch_bounds__(256, 3) void attn_kernel(
    const unsigned short* __restrict__ Zsw, const float* __restrict__ gv,
    const unsigned short* __restrict__ wpack, float* __restrict__ cbufg) {
  __shared__ __align__(16) unsigned short Tc[64 * 264];
  __shared__ float red[256];
  __shared__ float red2[256];
  const int t = threadIdx.x, lane = t & 63, wv = t >> 6;
  const int l15 = lane & 15, l4 = lane >> 4;
  // XCD swizzle: all 6 chunks of one p land on the same XCD (xcd = blk % 8)
  const int xcd = blockIdx.x & 7, inner = blockIdx.x >> 3;
  const int p = (inner / 6) * 8 + xcd, c = inner % 6;
  const unsigned short* Zsp = Zsw + (size_t)p * 98304;
  const unsigned short* wqk = wpack + 4 * 65536;

  // T' = (Zc @ Wqk + gv) / 16, b-frags double-buffered from Zsw
  {
    f32x4 ta[4][4];
    zero_acc4(ta);
    const unsigned short* Tb = Zsp + (size_t)(c * 4) * 4096 + lane * 8;
    bf16x8 bcur[4], bnxt[4];
#pragma unroll
    for (int nt = 0; nt < 4; ++nt)
      bcur[nt] = *reinterpret_cast<const bf16x8*>(Tb + nt * 4096);
#pragma unroll
    for (int ks = 0; ks < 8; ++ks) {
      if (ks < 7) {
#pragma unroll
        for (int nt = 0; nt < 4; ++nt)
          bnxt[nt] = *reinterpret_cast<const bf16x8*>(Tb + nt * 4096 + (ks + 1) * 512);
      }
      bf16x8 a[4];
#pragma unroll
      for (int mt = 0; mt < 4; ++mt)
        a[mt] = *reinterpret_cast<const bf16x8*>(wqk + ((ks * 16 + wv * 4 + mt) * 64 + lane) * 8);
#pragma unroll
      for (int nt = 0; nt < 4; ++nt)
#pragma unroll
        for (int mt = 0; mt < 4; ++mt)
          ta[mt][nt] = __builtin_amdgcn_mfma_f32_16x16x32_bf16(a[mt], bcur[nt], ta[mt][nt], 0, 0, 0);
      if (ks < 7) {
#pragma unroll
        for (int nt = 0; nt < 4; ++nt) bcur[nt] = bnxt[nt];
      }
    }
#pragma unroll
    for (int mt = 0; mt < 4; ++mt) {
      const int d = wv * 64 + mt * 16 + l4 * 4;
      const f32x4 gq = *reinterpret_cast<const f32x4*>(&gv[d]);
#pragma unroll
      for (int nt = 0; nt < 4; ++nt) {
        const int e = nt * 16 + l15;
        *reinterpret_cast<uint2*>(&Tc[e * 264 + d]) =
            pack4((ta[mt][nt][0] + gq[0]) * 0.0625f, (ta[mt][nt][1] + gq[1]) * 0.0625f,
                  (ta[mt][nt][2] + gq[2]) * 0.0625f, (ta[mt][nt][3] + gq[3]) * 0.0625f);
      }
    }
  }
  __syncthreads();

  // S = Tc @ Z^T; a-frags from LDS, b-frags full 6+6 double-buffer from Zsw
  f32x4 sc[4][6];
#pragma unroll
  for (int mt = 0; mt < 4; ++mt)
#pragma unroll
    for (int s = 0; s < 6; ++s) sc[mt][s] = (f32x4){0.f, 0.f, 0.f, 0.f};

  {
    const unsigned short* Sb = Zsp + (size_t)wv * 4096 + lane * 8;
    bf16x8 bcur[6], bnxt[6];
#pragma unroll
    for (int s = 0; s < 6; ++s)
      bcur[s] = *reinterpret_cast<const bf16x8*>(Sb + s * 16384);
#pragma unroll
    for (int ks = 0; ks < 8; ++ks) {
      if (ks < 7) {
#pragma unroll
        for (int s = 0; s < 6; ++s)
          bnxt[s] = *reinterpret_cast<const bf16x8*>(Sb + s * 16384 + (ks + 1) * 512);
      }
      bf16x8 a[4];
#pragma unroll
      for (int mt = 0; mt < 4; ++mt)
        a[mt] = *reinterpret_cast<const bf16x8*>(&Tc[(mt * 16 + l15) * 264 + ks * 32 + l4 * 8]);
#pragma unroll
      for (int s = 0; s < 6; ++s)
#pragma unroll
        for (int mt = 0; mt < 4; ++mt)
          sc[mt][s] = __builtin_amdgcn_mfma_f32_16x16x32_bf16(a[mt], bcur[s], sc[mt][s], 0, 0, 0);
      if (ks < 7) {
#pragma unroll
        for (int s = 0; s < 6; ++s) bcur[s] = bnxt[s];
      }
    }
  }

  // softmax over f (384 cols), rows e = mt*16 + l4*4 + r; sc already scaled
  float rmax[4][4];
#pragma unroll
  for (int mt = 0; mt < 4; ++mt) {
#pragma unroll
    for (int r = 0; r < 4; ++r) {
      float m = -1e30f;
#pragma unroll
      for (int s = 0; s < 6; ++s) m = fmaxf(m, sc[mt][s][r]);
      m = fmaxf(m, __shfl_xor(m, 1));
      m = fmaxf(m, __shfl_xor(m, 2));
      m = fmaxf(m, __shfl_xor(m, 4));
      m = fmaxf(m, __shfl_xor(m, 8));
      rmax[mt][r] = m;
    }
  }
  if (l15 == 0) {
#pragma unroll
    for (int mt = 0; mt < 4; ++mt)
#pragma unroll
      for (int r = 0; r < 4; ++r)
        red[wv * 64 + mt * 16 + l4 * 4 + r] = rmax[mt][r];
  }
  __syncthreads();
#pragma unroll
  for (int mt = 0; mt < 4; ++mt) {
#pragma unroll
    for (int r = 0; r < 4; ++r) {
      const int row = mt * 16 + l4 * 4 + r;
      rmax[mt][r] = fmaxf(fmaxf(red[row], red[64 + row]), fmaxf(red[128 + row], red[192 + row]));
    }
  }

  float rsum[4][4];
#pragma unroll
  for (int mt = 0; mt < 4; ++mt) {
#pragma unroll
    for (int r = 0; r < 4; ++r) {
      float sSum = 0.f;
#pragma unroll
      for (int s = 0; s < 6; ++s) {
        float e = __expf(sc[mt][s][r] - rmax[mt][r]);
        sc[mt][s][r] = e;
        sSum += e;
      }
      sSum += __shfl_xor(sSum, 1);
      sSum += __shfl_xor(sSum, 2);
      sSum += __shfl_xor(sSum, 4);
      sSum += __shfl_xor(sSum, 8);
      rsum[mt][r] = sSum;
    }
  }
  if (l15 == 0) {
#pragma unroll
    for (int mt = 0; mt < 4; ++mt)
#pragma unroll
      for (int r = 0; r < 4; ++r)
        red2[wv * 64 + mt * 16 + l4 * 4 + r] = rsum[mt][r];
  }
  __syncthreads();
  float rinv[4][4];
#pragma unroll
  for (int mt = 0; mt < 4; ++mt) {
#pragma unroll
    for (int r = 0; r < 4; ++r) {
      const int row = mt * 16 + l4 * 4 + r;
      rinv[mt][r] = 1.0f / (red2[row] + red2[64 + row] + red2[128 + row] + red2[192 + row]);
    }
  }

  // column sums of A over this chunk's 64 rows -> cbufg
#pragma unroll
  for (int s = 0; s < 6; ++s) {
    float v = 0.f;
#pragma unroll
    for (int mt = 0; mt < 4; ++mt)
#pragma unroll
      for (int r = 0; r < 4; ++r)
        v += sc[mt][s][r] * rinv[mt][r];
    v += __shfl_xor(v, 16);
    v += __shfl_xor(v, 32);
    if (lane < 16)
      atomicAdd(&cbufg[p * NEPI + s * 64 + wv * 16 + lane], v);
  }
}

// ---------------- output part A: u[p][d] partial over one f-third ----------------

__global__ __launch_bounds__(256) void outa_kernel(
    const unsigned short* __restrict__ Zsw, const float* __restrict__ cbufg,
    float* __restrict__ ubufg) {
  __shared__ float cb[128];
  __shared__ float part[16][257];
  const int p = blockIdx.x / 3, th = blockIdx.x % 3, g0 = th * 8;
  const int t = threadIdx.x;
  const int lane = t & 63, wv = t >> 6;
  const int l15 = lane & 15, l4 = lane >> 4;
  if (t < 128) cb[t] = cbufg[p * NEPI + g0 * 16 + t];
  __syncthreads();
  const unsigned short* Zsp = Zsw + (size_t)p * 98304;
  float a16[16];
#pragma unroll
  for (int j = 0; j < 16; ++j) a16[j] = 0.f;
#pragma unroll
  for (int gr = 0; gr < 8; ++gr) {
    const int grp = g0 + gr;
    const float w = cb[gr * 16 + l15];
    const uint4 z0 = *reinterpret_cast<const uint4*>(Zsp + grp * 4096 + wv * 512 + lane * 8);
    const uint4 z1 = *reinterpret_cast<const uint4*>(Zsp + grp * 4096 + (wv + 4) * 512 + lane * 8);
    a16[0] = fmaf(w, bf2f(z0.x & 0xffffu), a16[0]);
    a16[1] = fmaf(w, bf2f(z0.x >> 16), a16[1]);
    a16[2] = fmaf(w, bf2f(z0.y & 0xffffu), a16[2]);
    a16[3] = fmaf(w, bf2f(z0.y >> 16), a16[3]);
    a16[4] = fmaf(w, bf2f(z0.z & 0xffffu), a16[4]);
    a16[5] = fmaf(w, bf2f(z0.z >> 16), a16[5]);
    a16[6] = fmaf(w, bf2f(z0.w & 0xffffu), a16[6]);
    a16[7] = fmaf(w, bf2f(z0.w >> 16), a16[7]);
    a16[8]  = fmaf(w, bf2f(z1.x & 0xffffu), a16[8]);
    a16[9]  = fmaf(w, bf2f(z1.x >> 16), a16[9]);
    a16[10] = fmaf(w, bf2f(z1.y & 0xffffu), a16[10]);
    a16[11] = fmaf(w, bf2f(z1.y >> 16), a16[11]);
    a16[12] = fmaf(w, bf2f(z1.z & 0xffffu), a16[12]);
    a16[13] = fmaf(w, bf2f(z1.z >> 16), a16[13]);
    a16[14] = fmaf(w, bf2f(z1.w & 0xffffu), a16[14]);
    a16[15] = fmaf(w, bf2f(z1.w >> 16), a16[15]);
  }
#pragma unroll
  for (int j = 0; j < 8; ++j) part[l15][wv * 32 + l4 * 8 + j] = a16[j];
#pragma unroll
  for (int j = 0; j < 8; ++j) part[l15][128 + wv * 32 + l4 * 8 + j] = a16[8 + j];
  __syncthreads();
  float uu = 0.f;
#pragma unroll
  for (int g = 0; g < 16; ++g) uu += part[g][t];
  atomicAdd(&ubufg[p * DD + t], uu);
}

// ---------------- output part B: out[p] = (ftri + u@wv + 384*bv)/384 ----------------

__global__ __launch_bounds__(256) void out2_kernel(
    const float* __restrict__ ubufg, const float* __restrict__ ftri,
    const float* __restrict__ wvw, const float* __restrict__ wvb,
    float* __restrict__ out) {
  __shared__ float u[DD];
  const int p = blockIdx.x, t = threadIdx.x;
  u[t] = ubufg[p * DD + t];
  __syncthreads();
  float acc = ftri[p * DD + t] + 384.0f * wvb[t];
#pragma unroll 8
  for (int d = 0; d < DD; ++d)
    acc = fmaf(u[d], wvw[d * DD + t], acc);
  out[p * DD + t] = acc * (1.0f / 384.0f);
}

// ---------------- launch ----------------

extern "C" void kernel_launch(void* const* d_in, const int* in_sizes, int n_in,
                              void* d_out, int out_size, void* d_ws, size_t ws_size,
                              hipStream_t stream) {
  (void)in_sizes; (void)n_in; (void)out_size; (void)ws_size;
  const float* H = (const float*)d_in[0];
  const float* X = (const float*)d_in[1];
  const float* res_w1 = (const float*)d_in[4];
  const float* res_b1 = (const float*)d_in[5];
  const float* res_w2 = (const float*)d_in[6];
  const float* res_b2 = (const float*)d_in[7];
  const float* atom_w1 = (const float*)d_in[8];
  const float* atom_b1 = (const float*)d_in[9];
  const float* atom_w2 = (const float*)d_in[10];
  const float* atom_b2 = (const float*)d_in[11];
  const float* simw = (const float*)d_in[12];
  const float* int_w1 = (const float*)d_in[13];
  const float* int_b1 = (const float*)d_in[14];
  const float* int_w2 = (const float*)d_in[15];
  const float* int_b2 = (const float*)d_in[16];
  const float* wl = (const float*)d_in[17];
  const float* wr = (const float*)d_in[18];
  const float* wg_w = (const float*)d_in[19];
  const float* wg_b = (const float*)d_in[20];
  const float* wq_w = (const float*)d_in[21];
  const float* wq_b = (const float*)d_in[22];
  const float* wk_w = (const float*)d_in[23];
  const float* wv_w = (const float*)d_in[25];
  const float* wv_b = (const float*)d_in[26];

  char* ws = (char*)d_ws;
  unsigned short* wpack = (unsigned short*)(ws + 0);      //  655360 B (5 slots)
  float* MrF   = (float*)(ws + 655360);                   //  262144 B
  float* MaF   = (float*)(ws + 917504);                   //  262144 B
  float* WqkF  = (float*)(ws + 1179648);                  //  262144 B
  float* cvec  = (float*)(ws + 1441792);                  //    1024 B
  float* gv    = (float*)(ws + 1442816);                  //    1024 B
  float* P1    = (float*)(ws + 1443840);                  //  393216 B
  float* P2    = (float*)(ws + 1837056);                  //  393216 B
  float* Hpl   = (float*)(ws + 2230272);                  //  393216 B
  float* Her   = (float*)(ws + 2623488);                  //  393216 B
  float* ftri  = (float*)(ws + 3016704);                  //  393216 B
  float* cbufg = (float*)(ws + 3409920);                  //  589824 B
  float* ubufg = (float*)(ws + 3999744);                  //  393216 B
  unsigned short* Zsw = (unsigned short*)(ws + 4392960);  // 75497472 B
  unsigned short* tab = (unsigned short*)(ws + 79890432); //  2097152 B

  hipMemsetAsync(ftri, 0, 393216 + 589824 + 393216, stream);
  prep_kernel<<<2369, 256, 0, stream>>>(H, wl, wr, int_w1, res_w2, atom_w2,
                                        res_b2, atom_b2, int_b1, simw, wq_b, wk_w, wq_w,
                                        Hpl, Her, P1, P2, MrF, MaF, cvec, gv, WqkF);
  pack_kernel<<<1280, 256, 0, stream>>>(MrF, MaF, int_w2, wg_w, WqkF, wpack);
  tab_kernel<<<NTAB / 64, 256, 0, stream>>>(res_w1, res_b1, atom_w1, atom_b1, wpack, tab);
  pair_kernel<<<2304, 256, 0, stream>>>(X, tab, int_b2, wg_b, wpack, cvec,
                                        P1, P2, Hpl, Her, ftri, Zsw);
  attn_kernel<<<2304, 256, 0, stream>>>(Zsw, gv, wpack, cbufg);
  outa_kernel<<<1152, 256, 0, stream>>>(Zsw, cbufg, ubufg);
  out2_kernel<<<384, 256, 0, stream>>>(ubufg, ftri, wv_w, wv_b, (float*)d_out);
  hipMemcpyAsync((float*)d_out + NPAR * DD, H + NPAR * DD,
                 (1024 - NPAR) * DD * sizeof(float), hipMemcpyDeviceToDevice, stream);
}

// Round 15
// 335.416 us; speedup vs baseline: 1.0916x; 1.0162x over previous
//
#include <hip/hip_runtime.h>

#define NPAR 384
#define NEPI 384
#define DD   256
#define NTAB 4096
#define SMAX 96.0f
#define SDELTA (SMAX / NTAB)
#define SINVD (NTAB / SMAX)

using bf16x8 = __bf16 __attribute__((ext_vector_type(8)));
using bf16x2 = __bf16 __attribute__((ext_vector_type(2)));
using f32x4  = float __attribute__((ext_vector_type(4)));

#if defined(__has_builtin)
#if __has_builtin(__builtin_amdgcn_cvt_pk_bf16_f32)
#define HAVE_PK_BF16 1
#endif
#endif

__device__ __forceinline__ float sigm(float x) { return 1.0f / (1.0f + __expf(-x)); }
__device__ __forceinline__ float silu(float x) { return x / (1.0f + __expf(-x)); }
__device__ __forceinline__ unsigned short f2bf(float f) {
  unsigned u = __float_as_uint(f);
  u += 0x7fffu + ((u >> 16) & 1u);
  return (unsigned short)(u >> 16);
}
__device__ __forceinline__ float bf2f(unsigned u16) {
  return __uint_as_float(u16 << 16);
}
__device__ __forceinline__ float bf2f_lo(unsigned w) {
  return __uint_as_float(w << 16);
}
__device__ __forceinline__ float bf2f_hi(unsigned w) {
  return __uint_as_float(w & 0xffff0000u);
}
__device__ __forceinline__ uint2 pack4(float a, float b, float c, float d) {
  uint2 r;
#ifdef HAVE_PK_BF16
  bf16x2 lo = __builtin_amdgcn_cvt_pk_bf16_f32(a, b);
  bf16x2 hi = __builtin_amdgcn_cvt_pk_bf16_f32(c, d);
  r.x = __builtin_bit_cast(unsigned, lo);
  r.y = __builtin_bit_cast(unsigned, hi);
#else
  r.x = (unsigned)f2bf(a) | ((unsigned)f2bf(b) << 16);
  r.y = (unsigned)f2bf(c) | ((unsigned)f2bf(d) << 16);
#endif
  return r;
}

// ---------------- fused precompute kernel ----------------
// block ranges: [0,256) fold Mr/Ma (2 rows/block) ; [256] cvec ; [257,321) gvec ;
// [321,577) Wqk = wq@wk^T ; [577,961) mm_rows4 (4 rows/block)

__global__ void prep_kernel(
    const float* __restrict__ H, const float* __restrict__ wl,
    const float* __restrict__ wr, const float* __restrict__ int_w1,
    const float* __restrict__ res_w2, const float* __restrict__ atom_w2,
    const float* __restrict__ res_b2, const float* __restrict__ atom_b2,
    const float* __restrict__ int_b1, const float* __restrict__ simw,
    const float* __restrict__ wq_b, const float* __restrict__ wk_w,
    const float* __restrict__ wq_w,
    float* __restrict__ Hpl, float* __restrict__ Her,
    float* __restrict__ P1, float* __restrict__ P2,
    float* __restrict__ MrF, float* __restrict__ MaF,
    float* __restrict__ cvec, float* __restrict__ gv,
    float* __restrict__ WqkF) {
  __shared__ float sbuf[1024];
  const int b = blockIdx.x, t = threadIdx.x;
  if (b < 256) {
    const bool isMa = b >= 128;
    const int i0 = (b & 127) * 2;
    const float wmix = 1.0f / (1.0f + __expf(-simw[0]));
    const float sc = isMa ? (1.0f - wmix) : wmix;
    const float* W2 = isMa ? atom_w2 : res_w2;
    sbuf[t] = W2[i0 * 256 + t];
    sbuf[256 + t] = W2[(i0 + 1) * 256 + t];
    __syncthreads();
    float a0 = 0.f, a1 = 0.f;
#pragma unroll 8
    for (int k = 0; k < 256; ++k) {
      const float w = int_w1[(512 + k) * 256 + t];
      a0 = fmaf(sbuf[k], w, a0);
      a1 = fmaf(sbuf[256 + k], w, a1);
    }
    float* dst = isMa ? MaF : MrF;
    dst[i0 * 256 + t] = a0 * sc;
    dst[(i0 + 1) * 256 + t] = a1 * sc;
  } else if (b == 256) {
    const float wmix = 1.0f / (1.0f + __expf(-simw[0]));
    float acc = int_b1[t];
#pragma unroll 8
    for (int k = 0; k < 256; ++k) {
      float bm = wmix * res_b2[k] + (1.0f - wmix) * atom_b2[k];
      acc += bm * int_w1[(512 + k) * 256 + t];
    }
    cvec[t] = acc;
  } else if (b < 321) {
    const int lane = t & 63, w = t >> 6;
    const int d = (b - 257) * 4 + w;
    float acc = 0.f;
#pragma unroll
    for (int i = 0; i < 4; ++i) {
      const int c = i * 64 + lane;
      acc += wk_w[d * 256 + c] * wq_b[c];
    }
    acc += __shfl_xor(acc, 1);
    acc += __shfl_xor(acc, 2);
    acc += __shfl_xor(acc, 4);
    acc += __shfl_xor(acc, 8);
    acc += __shfl_xor(acc, 16);
    acc += __shfl_xor(acc, 32);
    if (lane == 0) gv[d] = acc;
  } else if (b < 577) {
    const int r = b - 321;
    sbuf[t] = wq_w[r * 256 + t];
    __syncthreads();
    const float* wkrow = wk_w + t * 256;
    float a0 = 0.f, a1 = 0.f, a2 = 0.f, a3 = 0.f;
#pragma unroll 4
    for (int k = 0; k < 256; k += 4) {
      const f32x4 wv4 = *reinterpret_cast<const f32x4*>(&wkrow[k]);
      a0 = fmaf(sbuf[k + 0], wv4[0], a0);
      a1 = fmaf(sbuf[k + 1], wv4[1], a1);
      a2 = fmaf(sbuf[k + 2], wv4[2], a2);
      a3 = fmaf(sbuf[k + 3], wv4[3], a3);
    }
    WqkF[r * 256 + t] = (a0 + a1) + (a2 + a3);
  } else {
    const int idx = b - 577;
    const int seg = idx / 96, r0 = (idx % 96) * 4;
    const float* A;
    const float* B;
    float* C;
    switch (seg) {
      case 0:  A = H + r0 * 256;            B = wl;              C = Hpl + r0 * 256; break;
      case 1:  A = H + (NPAR + r0) * 256;   B = wr;              C = Her + r0 * 256; break;
      case 2:  A = H + r0 * 256;            B = int_w1;          C = P1 + r0 * 256;  break;
      default: A = H + (NPAR + r0) * 256;   B = int_w1 + 65536;  C = P2 + r0 * 256;  break;
    }
#pragma unroll
    for (int j = 0; j < 4; ++j) sbuf[j * 256 + t] = A[j * 256 + t];
    __syncthreads();
    float a0 = 0.f, a1 = 0.f, a2 = 0.f, a3 = 0.f;
#pragma unroll 8
    for (int k = 0; k < 256; ++k) {
      const float bv = B[k * 256 + t];
      a0 = fmaf(sbuf[k], bv, a0);
      a1 = fmaf(sbuf[256 + k], bv, a1);
      a2 = fmaf(sbuf[512 + k], bv, a2);
      a3 = fmaf(sbuf[768 + k], bv, a3);
    }
    C[t] = a0;
    C[256 + t] = a1;
    C[512 + t] = a2;
    C[768 + t] = a3;
  }
}

// pack 5 [256,256] matrices into MFMA fragment order:
// slots: 0=Mr 1=Ma 2=int_w2 3=wg 4=Wqk
__global__ void pack_kernel(const float* __restrict__ MrF, const float* __restrict__ MaF,
                            const float* __restrict__ w2, const float* __restrict__ wg,
                            const float* __restrict__ WqkF, unsigned short* __restrict__ wpack) {
  const int idx = blockIdx.x * 256 + threadIdx.x;
  const int m = idx >> 16;
  const int r = idx & 65535;
  const int chunk = r >> 9;
  const int lane = (r >> 3) & 63;
  const int j = r & 7;
  const int k = (chunk >> 4) * 32 + (lane >> 4) * 8 + j;
  const int n = (chunk & 15) * 16 + (lane & 15);
  const float* src;
  switch (m) {
    case 0: src = MrF; break;
    case 1: src = MaF; break;
    case 2: src = w2; break;
    case 3: src = wg; break;
    default: src = WqkF; break;
  }
  wpack[idx] = f2bf(src[k * 256 + n]);
}

// ---------------- shared GEMM helpers ----------------

__device__ __forceinline__ void zero_acc4(f32x4 (&acc)[4][4]) {
#pragma unroll
  for (int mt = 0; mt < 4; ++mt)
#pragma unroll
    for (int nt = 0; nt < 4; ++nt)
      acc[mt][nt] = (f32x4){0.f, 0.f, 0.f, 0.f};
}

// transposed-acc: mfma(Wfrag, ActFrag) -> acc^T[d][e]
__device__ __forceinline__ void gemm4(f32x4 (&acc)[4][4],
                                      const unsigned short* __restrict__ wp,
                                      const unsigned short* ub, int lane, int wv) {
  const int l15 = lane & 15, l4 = lane >> 4;
#pragma unroll
  for (int ks = 0; ks < 8; ++ks) {
    bf16x8 a[4];
#pragma unroll
    for (int mt = 0; mt < 4; ++mt)
      a[mt] = *reinterpret_cast<const bf16x8*>(wp + ((ks * 16 + wv * 4 + mt) * 64 + lane) * 8);
#pragma unroll
    for (int nt = 0; nt < 4; ++nt) {
      bf16x8 b = *reinterpret_cast<const bf16x8*>(ub + (nt * 16 + l15) * 264 + ks * 32 + l4 * 8);
#pragma unroll
      for (int mt = 0; mt < 4; ++mt)
        acc[mt][nt] = __builtin_amdgcn_mfma_f32_16x16x32_bf16(a[mt], b, acc[mt][nt], 0, 0, 0);
    }
  }
}

// fill ubuf[e][d] = silu(Sv[e]*w1[d] + b1[d])
__device__ __forceinline__ void fill_u(unsigned short* ub, const float* Sv,
                                       const float* __restrict__ w1,
                                       const float* __restrict__ b1, int t) {
  const int dg = t & 31, rb = t >> 5;
  const f32x4 w1a = *reinterpret_cast<const f32x4*>(&w1[dg * 8]);
  const f32x4 w1b = *reinterpret_cast<const f32x4*>(&w1[dg * 8 + 4]);
  const f32x4 b1a = *reinterpret_cast<const f32x4*>(&b1[dg * 8]);
  const f32x4 b1b = *reinterpret_cast<const f32x4*>(&b1[dg * 8 + 4]);
#pragma unroll
  for (int i = 0; i < 8; ++i) {
    const int e = rb + i * 8;
    const float s = Sv[e];
    uint2 lo = pack4(silu(fmaf(s, w1a[0], b1a[0])), silu(fmaf(s, w1a[1], b1a[1])),
                     silu(fmaf(s, w1a[2], b1a[2])), silu(fmaf(s, w1a[3], b1a[3])));
    uint2 hi = pack4(silu(fmaf(s, w1b[0], b1b[0])), silu(fmaf(s, w1b[1], b1b[1])),
                     silu(fmaf(s, w1b[2], b1b[2])), silu(fmaf(s, w1b[3], b1b[3])));
    uint4 pk = {lo.x, lo.y, hi.x, hi.y};
    *reinterpret_cast<uint4*>(&ub[e * 264 + dg * 8]) = pk;
  }
}

// ---------------- table build: tab[n][d] = F(n*SDELTA)[d] (wpack slots 0,1) ----------------

__global__ __launch_bounds__(256, 3) void tab_kernel(
    const float* __restrict__ res_w1, const float* __restrict__ res_b1,
    const float* __restrict__ atom_w1, const float* __restrict__ atom_b1,
    const unsigned short* __restrict__ wpack, unsigned short* __restrict__ tab) {
  __shared__ __align__(16) unsigned short ubuf[64 * 264];
  __shared__ float Sv[64];
  const int t = threadIdx.x, lane = t & 63, wv = t >> 6;
  const int l15 = lane & 15, l4 = lane >> 4;
  const int n0 = blockIdx.x * 64;
  if (t < 64) Sv[t] = (n0 + t) * SDELTA;
  __syncthreads();
  f32x4 acc[4][4];
  zero_acc4(acc);
  fill_u(ubuf, Sv, res_w1, res_b1, t);
  __syncthreads();
  gemm4(acc, wpack + 0 * 65536, ubuf, lane, wv);
  __syncthreads();
  fill_u(ubuf, Sv, atom_w1, atom_b1, t);
  __syncthreads();
  gemm4(acc, wpack + 1 * 65536, ubuf, lane, wv);
#pragma unroll
  for (int mt = 0; mt < 4; ++mt) {
    const int d = wv * 64 + mt * 16 + l4 * 4;
#pragma unroll
    for (int nt = 0; nt < 4; ++nt) {
      const int n = n0 + nt * 16 + l15;
      *reinterpret_cast<uint2*>(&tab[n * 256 + d]) =
          pack4(acc[mt][nt][0], acc[mt][nt][1], acc[mt][nt][2], acc[mt][nt][3]);
    }
  }
}

// ---------------- pairwise kernel (64-row tiles): table-interp h + 2 GEMMs ----------------

__global__ __launch_bounds__(256, 4) void pair_kernel(
    const float* __restrict__ Xg, const unsigned short* __restrict__ tab,
    const float* __restrict__ int_b2, const float* __restrict__ wg_b,
    const unsigned short* __restrict__ wpack, const float* __restrict__ cvec,
    const float* __restrict__ P1, const float* __restrict__ P2,
    const float* __restrict__ Hpl, const float* __restrict__ Her,
    float* __restrict__ ftri, unsigned short* __restrict__ Zsw) {
  __shared__ __align__(16) unsigned short ubuf[64 * 264];
  __shared__ float Sv[64];
  __shared__ float pc[DD];
  const int t = threadIdx.x, lane = t & 63, wv = t >> 6;
  const int l15 = lane & 15, l4 = lane >> 4;
  const int p = blockIdx.x / 6, cc = blockIdx.x % 6, e0 = cc * 64;
  const int d0 = wv * 64;

  if (t < 64) {
    const int e = e0 + t;
    float dx = Xg[p * 42 + 3] - Xg[(NPAR + e) * 42 + 3];
    float dy = Xg[p * 42 + 4] - Xg[(NPAR + e) * 42 + 4];
    float dz = Xg[p * 42 + 5] - Xg[(NPAR + e) * 42 + 5];
    Sv[t] = dx * dx + dy * dy + dz * dz;
  }
  pc[t] = P1[p * DD + t] + cvec[t];
  __syncthreads();

  // h-fill: h[e][d] = silu(lerp(tab, S[e])[d] + pc[d] + P2[e][d]) -> ubuf
  {
    const int dg = t & 31, rb = t >> 5;
    const f32x4 pca = *reinterpret_cast<const f32x4*>(&pc[dg * 8]);
    const f32x4 pcb = *reinterpret_cast<const f32x4*>(&pc[dg * 8 + 4]);
#pragma unroll
    for (int i = 0; i < 8; ++i) {
      const int e = rb + i * 8;
      float sv = Sv[e] * SINVD;
      int idx = (int)sv;
      idx = idx > (NTAB - 2) ? (NTAB - 2) : idx;
      const float fr = sv - (float)idx;
      const uint4 t0 = *reinterpret_cast<const uint4*>(&tab[idx * 256 + dg * 8]);
      const uint4 t1 = *reinterpret_cast<const uint4*>(&tab[(idx + 1) * 256 + dg * 8]);
      const f32x4 p2a = *reinterpret_cast<const f32x4*>(&P2[(e0 + e) * DD + dg * 8]);
      const f32x4 p2b = *reinterpret_cast<const f32x4*>(&P2[(e0 + e) * DD + dg * 8 + 4]);
      float z0 = bf2f_lo(t0.x), z1 = bf2f_hi(t0.x), z2 = bf2f_lo(t0.y), z3 = bf2f_hi(t0.y);
      float z4 = bf2f_lo(t0.z), z5 = bf2f_hi(t0.z), z6 = bf2f_lo(t0.w), z7 = bf2f_hi(t0.w);
      z0 = fmaf(fr, bf2f_lo(t1.x) - z0, z0) + pca[0] + p2a[0];
      z1 = fmaf(fr, bf2f_hi(t1.x) - z1, z1) + pca[1] + p2a[1];
      z2 = fmaf(fr, bf2f_lo(t1.y) - z2, z2) + pca[2] + p2a[2];
      z3 = fmaf(fr, bf2f_hi(t1.y) - z3, z3) + pca[3] + p2a[3];
      z4 = fmaf(fr, bf2f_lo(t1.z) - z4, z4) + pcb[0] + p2b[0];
      z5 = fmaf(fr, bf2f_hi(t1.z) - z5, z5) + pcb[1] + p2b[1];
      z6 = fmaf(fr, bf2f_lo(t1.w) - z6, z6) + pcb[2] + p2b[2];
      z7 = fmaf(fr, bf2f_hi(t1.w) - z7, z7) + pcb[3] + p2b[3];
      uint2 lo = pack4(silu(z0), silu(z1), silu(z2), silu(z3));
      uint2 hi = pack4(silu(z4), silu(z5), silu(z6), silu(z7));
      uint4 pk = {lo.x, lo.y, hi.x, hi.y};
      *reinterpret_cast<uint4*>(&ubuf[e * 264 + dg * 8]) = pk;
    }
  }
  __syncthreads();

  // Z = h @ int_w2 + int_b2 -> ubuf
  f32x4 acc[4][4];
  zero_acc4(acc);
  gemm4(acc, wpack + 2 * 65536, ubuf, lane, wv);
  __syncthreads();
#pragma unroll
  for (int mt = 0; mt < 4; ++mt) {
    const int d = d0 + mt * 16 + l4 * 4;
    const f32x4 bb = *reinterpret_cast<const f32x4*>(&int_b2[d]);
#pragma unroll
    for (int nt = 0; nt < 4; ++nt) {
      const int e = nt * 16 + l15;
      *reinterpret_cast<uint2*>(&ubuf[e * 264 + d]) =
          pack4(acc[mt][nt][0] + bb[0], acc[mt][nt][1] + bb[1],
                acc[mt][nt][2] + bb[2], acc[mt][nt][3] + bb[3]);
    }
  }
  __syncthreads();

  // swizzled MFMA-fragment-order store: grp = cc*4 + wv, e = grp*16 + l15
  {
    unsigned short* Zd = Zsw + (size_t)p * 98304 + (size_t)(cc * 4 + wv) * 4096 + lane * 8;
#pragma unroll
    for (int ks = 0; ks < 8; ++ks) {
      *reinterpret_cast<uint4*>(Zd + ks * 512) =
          *reinterpret_cast<const uint4*>(&ubuf[(wv * 16 + l15) * 264 + ks * 32 + l4 * 8]);
    }
  }

  // gate: f_tri[d] += Hpl[p][d] * sum_e sigm(Z@wg + b) * Her[e][d]
  zero_acc4(acc);
  gemm4(acc, wpack + 3 * 65536, ubuf, lane, wv);
#pragma unroll
  for (int mt = 0; mt < 4; ++mt) {
    const int d = d0 + mt * 16 + l4 * 4;
    const f32x4 bb = *reinterpret_cast<const f32x4*>(&wg_b[d]);
    const f32x4 hl = *reinterpret_cast<const f32x4*>(&Hpl[p * DD + d]);
    f32x4 fs = (f32x4){0.f, 0.f, 0.f, 0.f};
#pragma unroll
    for (int nt = 0; nt < 4; ++nt) {
      const int e = e0 + nt * 16 + l15;
      const f32x4 hr = *reinterpret_cast<const f32x4*>(&Her[e * DD + d]);
#pragma unroll
      for (int r = 0; r < 4; ++r)
        fs[r] += sigm(acc[mt][nt][r] + bb[r]) * hr[r];
    }
#pragma unroll
    for (int r = 0; r < 4; ++r) {
      float v = fs[r] * hl[r];
      v += __shfl_xor(v, 1);
      v += __shfl_xor(v, 2);
      v += __shfl_xor(v, 4);
      v += __shfl_xor(v, 8);
      if (l15 == 0) atomicAdd(&ftri[p * DD + d + r], v);
    }
  }
}

// ---------------- fused attention kernel: block = (p, 32-row chunk) ----------------
// r15: 32-row chunks, 4608 blocks, 4 blocks/CU. Tc LDS 16.9 KB; sc[2][6];
// S-phase 3+3 rolling prefetch (peak ~120 VGPR under the 128 cap).

__global__ __launch_bounds__(256, 4) void attn_kernel(
    const unsigned short* __restrict__ Zsw, const float* __restrict__ gv,
    const unsigned short* __restrict__ wpack, float* __restrict__ cbufg) {
  __shared__ __align__(16) unsigned short Tc[32 * 264];
  __shared__ float red[128];
  __shared__ float red2[128];
  const int t = threadIdx.x, lane = t & 63, wv = t >> 6;
  const int l15 = lane & 15, l4 = lane >> 4;
  // XCD swizzle: all 12 chunks of one p land on the same XCD
  const int xcd = blockIdx.x & 7, inner = blockIdx.x >> 3;
  const int p = (inner / 12) * 8 + xcd, c = inner % 12;
  const unsigned short* Zsp = Zsw + (size_t)p * 98304;
  const unsigned short* wqk = wpack + 4 * 65536;

  // T' = (Zc @ Wqk + gv) / 16 for 32 rows (groups 2c, 2c+1), double-buffered
  {
    f32x4 ta[4][2];
#pragma unroll
    for (int mt = 0; mt < 4; ++mt)
#pragma unroll
      for (int nt = 0; nt < 2; ++nt) ta[mt][nt] = (f32x4){0.f, 0.f, 0.f, 0.f};
    const unsigned short* Tb = Zsp + (size_t)(c * 2) * 4096 + lane * 8;
    bf16x8 bcur[2], bnxt[2];
#pragma unroll
    for (int nt = 0; nt < 2; ++nt)
      bcur[nt] = *reinterpret_cast<const bf16x8*>(Tb + nt * 4096);
#pragma unroll
    for (int ks = 0; ks < 8; ++ks) {
      if (ks < 7) {
#pragma unroll
        for (int nt = 0; nt < 2; ++nt)
          bnxt[nt] = *reinterpret_cast<const bf16x8*>(Tb + nt * 4096 + (ks + 1) * 512);
      }
      bf16x8 a[4];
#pragma unroll
      for (int mt = 0; mt < 4; ++mt)
        a[mt] = *reinterpret_cast<const bf16x8*>(wqk + ((ks * 16 + wv * 4 + mt) * 64 + lane) * 8);
#pragma unroll
      for (int nt = 0; nt < 2; ++nt)
#pragma unroll
        for (int mt = 0; mt < 4; ++mt)
          ta[mt][nt] = __builtin_amdgcn_mfma_f32_16x16x32_bf16(a[mt], bcur[nt], ta[mt][nt], 0, 0, 0);
      if (ks < 7) {
#pragma unroll
        for (int nt = 0; nt < 2; ++nt) bcur[nt] = bnxt[nt];
      }
    }
#pragma unroll
    for (int mt = 0; mt < 4; ++mt) {
      const int d = wv * 64 + mt * 16 + l4 * 4;
      const f32x4 gq = *reinterpret_cast<const f32x4*>(&gv[d]);
#pragma unroll
      for (int nt = 0; nt < 2; ++nt) {
        const int e = nt * 16 + l15;
        *reinterpret_cast<uint2*>(&Tc[e * 264 + d]) =
            pack4((ta[mt][nt][0] + gq[0]) * 0.0625f, (ta[mt][nt][1] + gq[1]) * 0.0625f,
                  (ta[mt][nt][2] + gq[2]) * 0.0625f, (ta[mt][nt][3] + gq[3]) * 0.0625f);
      }
    }
  }
  __syncthreads();

  // S = Tc @ Z^T; a-frags from LDS (rows mt*16+l15, mt in {0,1}),
  // b-frags 3+3 rolling prefetch; wave wv owns f-groups {s*4 + wv}.
  f32x4 sc[2][6];
#pragma unroll
  for (int mt = 0; mt < 2; ++mt)
#pragma unroll
    for (int s = 0; s < 6; ++s) sc[mt][s] = (f32x4){0.f, 0.f, 0.f, 0.f};

  {
    const unsigned short* Sb = Zsp + (size_t)wv * 4096 + lane * 8;
    bf16x8 b0[3], b1[3];
#pragma unroll
    for (int j = 0; j < 3; ++j)
      b0[j] = *reinterpret_cast<const bf16x8*>(Sb + j * 16384);
#pragma unroll
    for (int ks = 0; ks < 8; ++ks) {
#pragma unroll
      for (int j = 0; j < 3; ++j)
        b1[j] = *reinterpret_cast<const bf16x8*>(Sb + (3 + j) * 16384 + ks * 512);
      bf16x8 a[2];
#pragma unroll
      for (int mt = 0; mt < 2; ++mt)
        a[mt] = *reinterpret_cast<const bf16x8*>(&Tc[(mt * 16 + l15) * 264 + ks * 32 + l4 * 8]);
#pragma unroll
      for (int j = 0; j < 3; ++j)
#pragma unroll
        for (int mt = 0; mt < 2; ++mt)
          sc[mt][j] = __builtin_amdgcn_mfma_f32_16x16x32_bf16(a[mt], b0[j], sc[mt][j], 0, 0, 0);
      if (ks < 7) {
#pragma unroll
        for (int j = 0; j < 3; ++j)
          b0[j] = *reinterpret_cast<const bf16x8*>(Sb + j * 16384 + (ks + 1) * 512);
      }
#pragma unroll
      for (int j = 0; j < 3; ++j)
#pragma unroll
        for (int mt = 0; mt < 2; ++mt)
          sc[mt][3 + j] = __builtin_amdgcn_mfma_f32_16x16x32_bf16(a[mt], b1[j], sc[mt][3 + j], 0, 0, 0);
    }
  }

  // softmax over f (384 cols), rows e = mt*16 + l4*4 + r (32 rows)
  float rmax[2][4];
#pragma unroll
  for (int mt = 0; mt < 2; ++mt) {
#pragma unroll
    for (int r = 0; r < 4; ++r) {
      float m = -1e30f;
#pragma unroll
      for (int s = 0; s < 6; ++s) m = fmaxf(m, sc[mt][s][r]);
      m = fmaxf(m, __shfl_xor(m, 1));
      m = fmaxf(m, __shfl_xor(m, 2));
      m = fmaxf(m, __shfl_xor(m, 4));
      m = fmaxf(m, __shfl_xor(m, 8));
      rmax[mt][r] = m;
    }
  }
  if (l15 == 0) {
#pragma unroll
    for (int mt = 0; mt < 2; ++mt)
#pragma unroll
      for (int r = 0; r < 4; ++r)
        red[wv * 32 + mt * 16 + l4 * 4 + r] = rmax[mt][r];
  }
  __syncthreads();
#pragma unroll
  for (int mt = 0; mt < 2; ++mt) {
#pragma unroll
    for (int r = 0; r < 4; ++r) {
      const int row = mt * 16 + l4 * 4 + r;
      rmax[mt][r] = fmaxf(fmaxf(red[row], red[32 + row]), fmaxf(red[64 + row], red[96 + row]));
    }
  }

  float rsum[2][4];
#pragma unroll
  for (int mt = 0; mt < 2; ++mt) {
#pragma unroll
    for (int r = 0; r < 4; ++r) {
      float sSum = 0.f;
#pragma unroll
      for (int s = 0; s < 6; ++s) {
        float e = __expf(sc[mt][s][r] - rmax[mt][r]);
        sc[mt][s][r] = e;
        sSum += e;
      }
      sSum += __shfl_xor(sSum, 1);
      sSum += __shfl_xor(sSum, 2);
      sSum += __shfl_xor(sSum, 4);
      sSum += __shfl_xor(sSum, 8);
      rsum[mt][r] = sSum;
    }
  }
  if (l15 == 0) {
#pragma unroll
    for (int mt = 0; mt < 2; ++mt)
#pragma unroll
      for (int r = 0; r < 4; ++r)
        red2[wv * 32 + mt * 16 + l4 * 4 + r] = rsum[mt][r];
  }
  __syncthreads();
  float rinv[2][4];
#pragma unroll
  for (int mt = 0; mt < 2; ++mt) {
#pragma unroll
    for (int r = 0; r < 4; ++r) {
      const int row = mt * 16 + l4 * 4 + r;
      rinv[mt][r] = 1.0f / (red2[row] + red2[32 + row] + red2[64 + row] + red2[96 + row]);
    }
  }

  // column sums of A over this chunk's 32 rows -> cbufg
#pragma unroll
  for (int s = 0; s < 6; ++s) {
    float v = 0.f;
#pragma unroll
    for (int mt = 0; mt < 2; ++mt)
#pragma unroll
      for (int r = 0; r < 4; ++r)
        v += sc[mt][s][r] * rinv[mt][r];
    v += __shfl_xor(v, 16);
    v += __shfl_xor(v, 32);
    if (lane < 16)
      atomicAdd(&cbufg[p * NEPI + (s * 4 + wv) * 16 + lane], v);
  }
}

// ---------------- output part A: u[p][d] partial over one f-third ----------------

__global__ __launch_bounds__(256) void outa_kernel(
    const unsigned short* __restrict__ Zsw, const float* __restrict__ cbufg,
    float* __restrict__ ubufg) {
  __shared__ float cb[128];
  __shared__ float part[16][257];
  const int p = blockIdx.x / 3, th = blockIdx.x % 3, g0 = th * 8;
  const int t = threadIdx.x;
  const int lane = t & 63, wv = t >> 6;
  const int l15 = lane & 15, l4 = lane >> 4;
  if (t < 128) cb[t] = cbufg[p * NEPI + g0 * 16 + t];
  __syncthreads();
  const unsigned short* Zsp = Zsw + (size_t)p * 98304;
  float a16[16];
#pragma unroll
  for (int j = 0; j < 16; ++j) a16[j] = 0.f;
#pragma unroll
  for (int gr = 0; gr < 8; ++gr) {
    const int grp = g0 + gr;
    const float w = cb[gr * 16 + l15];
    const uint4 z0 = *reinterpret_cast<const uint4*>(Zsp + grp * 4096 + wv * 512 + lane * 8);
    const uint4 z1 = *reinterpret_cast<const uint4*>(Zsp + grp * 4096 + (wv + 4) * 512 + lane * 8);
    a16[0] = fmaf(w, bf2f(z0.x & 0xffffu), a16[0]);
    a16[1] = fmaf(w, bf2f(z0.x >> 16), a16[1]);
    a16[2] = fmaf(w, bf2f(z0.y & 0xffffu), a16[2]);
    a16[3] = fmaf(w, bf2f(z0.y >> 16), a16[3]);
    a16[4] = fmaf(w, bf2f(z0.z & 0xffffu), a16[4]);
    a16[5] = fmaf(w, bf2f(z0.z >> 16), a16[5]);
    a16[6] = fmaf(w, bf2f(z0.w & 0xffffu), a16[6]);
    a16[7] = fmaf(w, bf2f(z0.w >> 16), a16[7]);
    a16[8]  = fmaf(w, bf2f(z1.x & 0xffffu), a16[8]);
    a16[9]  = fmaf(w, bf2f(z1.x >> 16), a16[9]);
    a16[10] = fmaf(w, bf2f(z1.y & 0xffffu), a16[10]);
    a16[11] = fmaf(w, bf2f(z1.y >> 16), a16[11]);
    a16[12] = fmaf(w, bf2f(z1.z & 0xffffu), a16[12]);
    a16[13] = fmaf(w, bf2f(z1.z >> 16), a16[13]);
    a16[14] = fmaf(w, bf2f(z1.w & 0xffffu), a16[14]);
    a16[15] = fmaf(w, bf2f(z1.w >> 16), a16[15]);
  }
#pragma unroll
  for (int j = 0; j < 8; ++j) part[l15][wv * 32 + l4 * 8 + j] = a16[j];
#pragma unroll
  for (int j = 0; j < 8; ++j) part[l15][128 + wv * 32 + l4 * 8 + j] = a16[8 + j];
  __syncthreads();
  float uu = 0.f;
#pragma unroll
  for (int g = 0; g < 16; ++g) uu += part[g][t];
  atomicAdd(&ubufg[p * DD + t], uu);
}

// ---------------- output part B: out[p] = (ftri + u@wv + 384*bv)/384 ----------------

__global__ __launch_bounds__(256) void out2_kernel(
    const float* __restrict__ ubufg, const float* __restrict__ ftri,
    const float* __restrict__ wvw, const float* __restrict__ wvb,
    float* __restrict__ out) {
  __shared__ float u[DD];
  const int p = blockIdx.x, t = threadIdx.x;
  u[t] = ubufg[p * DD + t];
  __syncthreads();
  float acc = ftri[p * DD + t] + 384.0f * wvb[t];
#pragma unroll 8
  for (int d = 0; d < DD; ++d)
    acc = fmaf(u[d], wvw[d * DD + t], acc);
  out[p * DD + t] = acc * (1.0f / 384.0f);
}

// ---------------- launch ----------------

extern "C" void kernel_launch(void* const* d_in, const int* in_sizes, int n_in,
                              void* d_out, int out_size, void* d_ws, size_t ws_size,
                              hipStream_t stream) {
  (void)in_sizes; (void)n_in; (void)out_size; (void)ws_size;
  const float* H = (const float*)d_in[0];
  const float* X = (const float*)d_in[1];
  const float* res_w1 = (const float*)d_in[4];
  const float* res_b1 = (const float*)d_in[5];
  const float* res_w2 = (const float*)d_in[6];
  const float* res_b2 = (const float*)d_in[7];
  const float* atom_w1 = (const float*)d_in[8];
  const float* atom_b1 = (const float*)d_in[9];
  const float* atom_w2 = (const float*)d_in[10];
  const float* atom_b2 = (const float*)d_in[11];
  const float* simw = (const float*)d_in[12];
  const float* int_w1 = (const float*)d_in[13];
  const float* int_b1 = (const float*)d_in[14];
  const float* int_w2 = (const float*)d_in[15];
  const float* int_b2 = (const float*)d_in[16];
  const float* wl = (const float*)d_in[17];
  const float* wr = (const float*)d_in[18];
  const float* wg_w = (const float*)d_in[19];
  const float* wg_b = (const float*)d_in[20];
  const float* wq_w = (const float*)d_in[21];
  const float* wq_b = (const float*)d_in[22];
  const float* wk_w = (const float*)d_in[23];
  const float* wv_w = (const float*)d_in[25];
  const float* wv_b = (const float*)d_in[26];

  char* ws = (char*)d_ws;
  unsigned short* wpack = (unsigned short*)(ws + 0);      //  655360 B (5 slots)
  float* MrF   = (float*)(ws + 655360);                   //  262144 B
  float* MaF   = (float*)(ws + 917504);                   //  262144 B
  float* WqkF  = (float*)(ws + 1179648);                  //  262144 B
  float* cvec  = (float*)(ws + 1441792);                  //    1024 B
  float* gv    = (float*)(ws + 1442816);                  //    1024 B
  float* P1    = (float*)(ws + 1443840);                  //  393216 B
  float* P2    = (float*)(ws + 1837056);                  //  393216 B
  float* Hpl   = (float*)(ws + 2230272);                  //  393216 B
  float* Her   = (float*)(ws + 2623488);                  //  393216 B
  float* ftri  = (float*)(ws + 3016704);                  //  393216 B
  float* cbufg = (float*)(ws + 3409920);                  //  589824 B
  float* ubufg = (float*)(ws + 3999744);                  //  393216 B
  unsigned short* Zsw = (unsigned short*)(ws + 4392960);  // 75497472 B
  unsigned short* tab = (unsigned short*)(ws + 79890432); //  2097152 B

  hipMemsetAsync(ftri, 0, 393216 + 589824 + 393216, stream);
  prep_kernel<<<961, 256, 0, stream>>>(H, wl, wr, int_w1, res_w2, atom_w2,
                                       res_b2, atom_b2, int_b1, simw, wq_b, wk_w, wq_w,
                                       Hpl, Her, P1, P2, MrF, MaF, cvec, gv, WqkF);
  pack_kernel<<<1280, 256, 0, stream>>>(MrF, MaF, int_w2, wg_w, WqkF, wpack);
  tab_kernel<<<NTAB / 64, 256, 0, stream>>>(res_w1, res_b1, atom_w1, atom_b1, wpack, tab);
  pair_kernel<<<2304, 256, 0, stream>>>(X, tab, int_b2, wg_b, wpack, cvec,
                                        P1, P2, Hpl, Her, ftri, Zsw);
  attn_kernel<<<4608, 256, 0, stream>>>(Zsw, gv, wpack, cbufg);
  outa_kernel<<<1152, 256, 0, stream>>>(Zsw, cbufg, ubufg);
  out2_kernel<<<384, 256, 0, stream>>>(ubufg, ftri, wv_w, wv_b, (float*)d_out);
  hipMemcpyAsync((float*)d_out + NPAR * DD, H + NPAR * DD,
                 (1024 - NPAR) * DD * sizeof(float), hipMemcpyDeviceToDevice, stream);
}

// Round 16
// 328.241 us; speedup vs baseline: 1.1155x; 1.0219x over previous
//
#include <hip/hip_runtime.h>

#define NPAR 384
#define NEPI 384
#define DD   256
#define NTAB 4096
#define SMAX 96.0f
#define SDELTA (SMAX / NTAB)
#define SINVD (NTAB / SMAX)

using bf16x8 = __bf16 __attribute__((ext_vector_type(8)));
using bf16x2 = __bf16 __attribute__((ext_vector_type(2)));
using f32x4  = float __attribute__((ext_vector_type(4)));

#if defined(__has_builtin)
#if __has_builtin(__builtin_amdgcn_cvt_pk_bf16_f32)
#define HAVE_PK_BF16 1
#endif
#endif

__device__ __forceinline__ float sigm(float x) { return 1.0f / (1.0f + __expf(-x)); }
__device__ __forceinline__ float silu(float x) { return x / (1.0f + __expf(-x)); }
__device__ __forceinline__ unsigned short f2bf(float f) {
  unsigned u = __float_as_uint(f);
  u += 0x7fffu + ((u >> 16) & 1u);
  return (unsigned short)(u >> 16);
}
__device__ __forceinline__ float bf2f(unsigned u16) {
  return __uint_as_float(u16 << 16);
}
__device__ __forceinline__ uint2 pack4(float a, float b, float c, float d) {
  uint2 r;
#ifdef HAVE_PK_BF16
  bf16x2 lo = __builtin_amdgcn_cvt_pk_bf16_f32(a, b);
  bf16x2 hi = __builtin_amdgcn_cvt_pk_bf16_f32(c, d);
  r.x = __builtin_bit_cast(unsigned, lo);
  r.y = __builtin_bit_cast(unsigned, hi);
#else
  r.x = (unsigned)f2bf(a) | ((unsigned)f2bf(b) << 16);
  r.y = (unsigned)f2bf(c) | ((unsigned)f2bf(d) << 16);
#endif
  return r;
}

// write one element into MFMA-packed layout: wpack[slot][k][n]
__device__ __forceinline__ void store_packed(unsigned short* __restrict__ wp,
                                             int slot, int k, int n, float v) {
  const int ks = k >> 5, lhi = (k >> 3) & 3, j = k & 7;
  const int tile = n >> 4, llo = n & 15;
  const int lane = lhi * 16 + llo;
  wp[slot * 65536 + (((ks * 16 + tile) * 64 + lane) << 3) + j] = f2bf(v);
}

// ---------------- fused precompute kernel ----------------
// [0,256) fold Mr/Ma (2 rows/block, writes wpack slots 0/1 packed) ; [256] cvec ;
// [257,321) gvec ; [321,577) Wqk = wq@wk^T (writes slot 4 packed) ;
// [577,961) mm_rows4 (4 rows/block) ; [961,1473) pack int_w2 (slot 2) / wg (slot 3)

__global__ void prep_kernel(
    const float* __restrict__ H, const float* __restrict__ wl,
    const float* __restrict__ wr, const float* __restrict__ int_w1,
    const float* __restrict__ res_w2, const float* __restrict__ atom_w2,
    const float* __restrict__ res_b2, const float* __restrict__ atom_b2,
    const float* __restrict__ int_b1, const float* __restrict__ simw,
    const float* __restrict__ wq_b, const float* __restrict__ wk_w,
    const float* __restrict__ wq_w, const float* __restrict__ int_w2,
    const float* __restrict__ wg_w,
    float* __restrict__ Hpl, float* __restrict__ Her,
    float* __restrict__ P1, float* __restrict__ P2,
    float* __restrict__ cvec, float* __restrict__ gv,
    unsigned short* __restrict__ wpack) {
  __shared__ float sbuf[1024];
  const int b = blockIdx.x, t = threadIdx.x;
  if (b < 256) {
    const bool isMa = b >= 128;
    const int i0 = (b & 127) * 2;
    const float wmix = 1.0f / (1.0f + __expf(-simw[0]));
    const float sc = isMa ? (1.0f - wmix) : wmix;
    const float* W2 = isMa ? atom_w2 : res_w2;
    sbuf[t] = W2[i0 * 256 + t];
    sbuf[256 + t] = W2[(i0 + 1) * 256 + t];
    __syncthreads();
    float a0 = 0.f, a1 = 0.f;
#pragma unroll 8
    for (int k = 0; k < 256; ++k) {
      const float w = int_w1[(512 + k) * 256 + t];
      a0 = fmaf(sbuf[k], w, a0);
      a1 = fmaf(sbuf[256 + k], w, a1);
    }
    const int slot = isMa ? 1 : 0;
    store_packed(wpack, slot, i0, t, a0 * sc);
    store_packed(wpack, slot, i0 + 1, t, a1 * sc);
  } else if (b == 256) {
    const float wmix = 1.0f / (1.0f + __expf(-simw[0]));
    float acc = int_b1[t];
#pragma unroll 8
    for (int k = 0; k < 256; ++k) {
      float bm = wmix * res_b2[k] + (1.0f - wmix) * atom_b2[k];
      acc += bm * int_w1[(512 + k) * 256 + t];
    }
    cvec[t] = acc;
  } else if (b < 321) {
    const int lane = t & 63, w = t >> 6;
    const int d = (b - 257) * 4 + w;
    float acc = 0.f;
#pragma unroll
    for (int i = 0; i < 4; ++i) {
      const int c = i * 64 + lane;
      acc += wk_w[d * 256 + c] * wq_b[c];
    }
    acc += __shfl_xor(acc, 1);
    acc += __shfl_xor(acc, 2);
    acc += __shfl_xor(acc, 4);
    acc += __shfl_xor(acc, 8);
    acc += __shfl_xor(acc, 16);
    acc += __shfl_xor(acc, 32);
    if (lane == 0) gv[d] = acc;
  } else if (b < 577) {
    const int r = b - 321;
    sbuf[t] = wq_w[r * 256 + t];
    __syncthreads();
    const float* wkrow = wk_w + t * 256;
    float a0 = 0.f, a1 = 0.f, a2 = 0.f, a3 = 0.f;
#pragma unroll 4
    for (int k = 0; k < 256; k += 4) {
      const f32x4 wv4 = *reinterpret_cast<const f32x4*>(&wkrow[k]);
      a0 = fmaf(sbuf[k + 0], wv4[0], a0);
      a1 = fmaf(sbuf[k + 1], wv4[1], a1);
      a2 = fmaf(sbuf[k + 2], wv4[2], a2);
      a3 = fmaf(sbuf[k + 3], wv4[3], a3);
    }
    store_packed(wpack, 4, r, t, (a0 + a1) + (a2 + a3));
  } else if (b < 961) {
    const int idx = b - 577;
    const int seg = idx / 96, r0 = (idx % 96) * 4;
    const float* A;
    const float* B;
    float* C;
    switch (seg) {
      case 0:  A = H + r0 * 256;            B = wl;              C = Hpl + r0 * 256; break;
      case 1:  A = H + (NPAR + r0) * 256;   B = wr;              C = Her + r0 * 256; break;
      case 2:  A = H + r0 * 256;            B = int_w1;          C = P1 + r0 * 256;  break;
      default: A = H + (NPAR + r0) * 256;   B = int_w1 + 65536;  C = P2 + r0 * 256;  break;
    }
#pragma unroll
    for (int j = 0; j < 4; ++j) sbuf[j * 256 + t] = A[j * 256 + t];
    __syncthreads();
    float a0 = 0.f, a1 = 0.f, a2 = 0.f, a3 = 0.f;
#pragma unroll 8
    for (int k = 0; k < 256; ++k) {
      const float bv = B[k * 256 + t];
      a0 = fmaf(sbuf[k], bv, a0);
      a1 = fmaf(sbuf[256 + k], bv, a1);
      a2 = fmaf(sbuf[512 + k], bv, a2);
      a3 = fmaf(sbuf[768 + k], bv, a3);
    }
    C[t] = a0;
    C[256 + t] = a1;
    C[512 + t] = a2;
    C[768 + t] = a3;
  } else {
    // pack int_w2 -> slot 2, wg -> slot 3 (same indexing as old pack_kernel)
    const int idx = (b - 961) * 256 + t;       // 0 .. 2*65536-1
    const int m = idx >> 16;                   // 0 or 1
    const int r = idx & 65535;
    const int chunk = r >> 9;
    const int lane = (r >> 3) & 63;
    const int j = r & 7;
    const int k = (chunk >> 4) * 32 + (lane >> 4) * 8 + j;
    const int n = (chunk & 15) * 16 + (lane & 15);
    const float* src = (m == 0) ? int_w2 : wg_w;
    wpack[(2 + m) * 65536 + r] = f2bf(src[k * 256 + n]);
  }
}

// ---------------- shared GEMM helpers ----------------

__device__ __forceinline__ void zero_acc4(f32x4 (&acc)[4][4]) {
#pragma unroll
  for (int mt = 0; mt < 4; ++mt)
#pragma unroll
    for (int nt = 0; nt < 4; ++nt)
      acc[mt][nt] = (f32x4){0.f, 0.f, 0.f, 0.f};
}

// transposed-acc: mfma(Wfrag, ActFrag) -> acc^T[d][e]
__device__ __forceinline__ void gemm4(f32x4 (&acc)[4][4],
                                      const unsigned short* __restrict__ wp,
                                      const unsigned short* ub, int lane, int wv) {
  const int l15 = lane & 15, l4 = lane >> 4;
#pragma unroll
  for (int ks = 0; ks < 8; ++ks) {
    bf16x8 a[4];
#pragma unroll
    for (int mt = 0; mt < 4; ++mt)
      a[mt] = *reinterpret_cast<const bf16x8*>(wp + ((ks * 16 + wv * 4 + mt) * 64 + lane) * 8);
#pragma unroll
    for (int nt = 0; nt < 4; ++nt) {
      bf16x8 b = *reinterpret_cast<const bf16x8*>(ub + (nt * 16 + l15) * 264 + ks * 32 + l4 * 8);
#pragma unroll
      for (int mt = 0; mt < 4; ++mt)
        acc[mt][nt] = __builtin_amdgcn_mfma_f32_16x16x32_bf16(a[mt], b, acc[mt][nt], 0, 0, 0);
    }
  }
}

// fill ubuf[e][d] = silu(Sv[e]*w1[d] + b1[d])
__device__ __forceinline__ void fill_u(unsigned short* ub, const float* Sv,
                                       const float* __restrict__ w1,
                                       const float* __restrict__ b1, int t) {
  const int dg = t & 31, rb = t >> 5;
  const f32x4 w1a = *reinterpret_cast<const f32x4*>(&w1[dg * 8]);
  const f32x4 w1b = *reinterpret_cast<const f32x4*>(&w1[dg * 8 + 4]);
  const f32x4 b1a = *reinterpret_cast<const f32x4*>(&b1[dg * 8]);
  const f32x4 b1b = *reinterpret_cast<const f32x4*>(&b1[dg * 8 + 4]);
#pragma unroll
  for (int i = 0; i < 8; ++i) {
    const int e = rb + i * 8;
    const float s = Sv[e];
    uint2 lo = pack4(silu(fmaf(s, w1a[0], b1a[0])), silu(fmaf(s, w1a[1], b1a[1])),
                     silu(fmaf(s, w1a[2], b1a[2])), silu(fmaf(s, w1a[3], b1a[3])));
    uint2 hi = pack4(silu(fmaf(s, w1b[0], b1b[0])), silu(fmaf(s, w1b[1], b1b[1])),
                     silu(fmaf(s, w1b[2], b1b[2])), silu(fmaf(s, w1b[3], b1b[3])));
    uint4 pk = {lo.x, lo.y, hi.x, hi.y};
    *reinterpret_cast<uint4*>(&ub[e * 264 + dg * 8]) = pk;
  }
}

// ---------------- table build: tabF[n][d] = F(n*SDELTA)[d], fp32 out ----------------

__global__ __launch_bounds__(256, 3) void tab_kernel(
    const float* __restrict__ res_w1, const float* __restrict__ res_b1,
    const float* __restrict__ atom_w1, const float* __restrict__ atom_b1,
    const unsigned short* __restrict__ wpack, float* __restrict__ tabF) {
  __shared__ __align__(16) unsigned short ubuf[64 * 264];
  __shared__ float Sv[64];
  const int t = threadIdx.x, lane = t & 63, wv = t >> 6;
  const int l15 = lane & 15, l4 = lane >> 4;
  const int n0 = blockIdx.x * 64;
  if (t < 64) Sv[t] = (n0 + t) * SDELTA;
  __syncthreads();
  f32x4 acc[4][4];
  zero_acc4(acc);
  fill_u(ubuf, Sv, res_w1, res_b1, t);
  __syncthreads();
  gemm4(acc, wpack + 0 * 65536, ubuf, lane, wv);
  __syncthreads();
  fill_u(ubuf, Sv, atom_w1, atom_b1, t);
  __syncthreads();
  gemm4(acc, wpack + 1 * 65536, ubuf, lane, wv);
#pragma unroll
  for (int mt = 0; mt < 4; ++mt) {
    const int d = wv * 64 + mt * 16 + l4 * 4;
#pragma unroll
    for (int nt = 0; nt < 4; ++nt) {
      const int n = n0 + nt * 16 + l15;
      *reinterpret_cast<f32x4*>(&tabF[n * 256 + d]) = acc[mt][nt];
    }
  }
}

// ---------------- pairwise kernel (64-row tiles): fp32-table-interp h + 2 GEMMs -------

__global__ __launch_bounds__(256, 4) void pair_kernel(
    const float* __restrict__ Xg, const float* __restrict__ tabF,
    const float* __restrict__ int_b2, const float* __restrict__ wg_b,
    const unsigned short* __restrict__ wpack, const float* __restrict__ cvec,
    const float* __restrict__ P1, const float* __restrict__ P2,
    const float* __restrict__ Hpl, const float* __restrict__ Her,
    float* __restrict__ ftri, unsigned short* __restrict__ Zsw) {
  __shared__ __align__(16) unsigned short ubuf[64 * 264];
  __shared__ float Sv[64];
  __shared__ float pc[DD];
  const int t = threadIdx.x, lane = t & 63, wv = t >> 6;
  const int l15 = lane & 15, l4 = lane >> 4;
  const int p = blockIdx.x / 6, cc = blockIdx.x % 6, e0 = cc * 64;
  const int d0 = wv * 64;

  if (t < 64) {
    const int e = e0 + t;
    float dx = Xg[p * 42 + 3] - Xg[(NPAR + e) * 42 + 3];
    float dy = Xg[p * 42 + 4] - Xg[(NPAR + e) * 42 + 4];
    float dz = Xg[p * 42 + 5] - Xg[(NPAR + e) * 42 + 5];
    Sv[t] = dx * dx + dy * dy + dz * dz;
  }
  pc[t] = P1[p * DD + t] + cvec[t];
  __syncthreads();

  // h-fill: h[e][d] = silu(lerp(tabF, S[e])[d] + pc[d] + P2[e][d]) -> ubuf
  {
    const int dg = t & 31, rb = t >> 5;
    const f32x4 pca = *reinterpret_cast<const f32x4*>(&pc[dg * 8]);
    const f32x4 pcb = *reinterpret_cast<const f32x4*>(&pc[dg * 8 + 4]);
#pragma unroll
    for (int i = 0; i < 8; ++i) {
      const int e = rb + i * 8;
      float sv = Sv[e] * SINVD;
      int idx = (int)sv;
      idx = idx > (NTAB - 2) ? (NTAB - 2) : idx;
      const float fr = sv - (float)idx;
      const f32x4 t0a = *reinterpret_cast<const f32x4*>(&tabF[idx * 256 + dg * 8]);
      const f32x4 t0b = *reinterpret_cast<const f32x4*>(&tabF[idx * 256 + dg * 8 + 4]);
      const f32x4 t1a = *reinterpret_cast<const f32x4*>(&tabF[(idx + 1) * 256 + dg * 8]);
      const f32x4 t1b = *reinterpret_cast<const f32x4*>(&tabF[(idx + 1) * 256 + dg * 8 + 4]);
      const f32x4 p2a = *reinterpret_cast<const f32x4*>(&P2[(e0 + e) * DD + dg * 8]);
      const f32x4 p2b = *reinterpret_cast<const f32x4*>(&P2[(e0 + e) * DD + dg * 8 + 4]);
      float z0 = fmaf(fr, t1a[0] - t0a[0], t0a[0]) + pca[0] + p2a[0];
      float z1 = fmaf(fr, t1a[1] - t0a[1], t0a[1]) + pca[1] + p2a[1];
      float z2 = fmaf(fr, t1a[2] - t0a[2], t0a[2]) + pca[2] + p2a[2];
      float z3 = fmaf(fr, t1a[3] - t0a[3], t0a[3]) + pca[3] + p2a[3];
      float z4 = fmaf(fr, t1b[0] - t0b[0], t0b[0]) + pcb[0] + p2b[0];
      float z5 = fmaf(fr, t1b[1] - t0b[1], t0b[1]) + pcb[1] + p2b[1];
      float z6 = fmaf(fr, t1b[2] - t0b[2], t0b[2]) + pcb[2] + p2b[2];
      float z7 = fmaf(fr, t1b[3] - t0b[3], t0b[3]) + pcb[3] + p2b[3];
      uint2 lo = pack4(silu(z0), silu(z1), silu(z2), silu(z3));
      uint2 hi = pack4(silu(z4), silu(z5), silu(z6), silu(z7));
      uint4 pk = {lo.x, lo.y, hi.x, hi.y};
      *reinterpret_cast<uint4*>(&ubuf[e * 264 + dg * 8]) = pk;
    }
  }
  __syncthreads();

  // Z = h @ int_w2 + int_b2 -> ubuf
  f32x4 acc[4][4];
  zero_acc4(acc);
  gemm4(acc, wpack + 2 * 65536, ubuf, lane, wv);
  __syncthreads();
#pragma unroll
  for (int mt = 0; mt < 4; ++mt) {
    const int d = d0 + mt * 16 + l4 * 4;
    const f32x4 bb = *reinterpret_cast<const f32x4*>(&int_b2[d]);
#pragma unroll
    for (int nt = 0; nt < 4; ++nt) {
      const int e = nt * 16 + l15;
      *reinterpret_cast<uint2*>(&ubuf[e * 264 + d]) =
          pack4(acc[mt][nt][0] + bb[0], acc[mt][nt][1] + bb[1],
                acc[mt][nt][2] + bb[2], acc[mt][nt][3] + bb[3]);
    }
  }
  __syncthreads();

  // swizzled MFMA-fragment-order store: grp = cc*4 + wv, e = grp*16 + l15
  {
    unsigned short* Zd = Zsw + (size_t)p * 98304 + (size_t)(cc * 4 + wv) * 4096 + lane * 8;
#pragma unroll
    for (int ks = 0; ks < 8; ++ks) {
      *reinterpret_cast<uint4*>(Zd + ks * 512) =
          *reinterpret_cast<const uint4*>(&ubuf[(wv * 16 + l15) * 264 + ks * 32 + l4 * 8]);
    }
  }

  // gate: f_tri[d] += Hpl[p][d] * sum_e sigm(Z@wg + b) * Her[e][d]
  zero_acc4(acc);
  gemm4(acc, wpack + 3 * 65536, ubuf, lane, wv);
#pragma unroll
  for (int mt = 0; mt < 4; ++mt) {
    const int d = d0 + mt * 16 + l4 * 4;
    const f32x4 bb = *reinterpret_cast<const f32x4*>(&wg_b[d]);
    const f32x4 hl = *reinterpret_cast<const f32x4*>(&Hpl[p * DD + d]);
    f32x4 fs = (f32x4){0.f, 0.f, 0.f, 0.f};
#pragma unroll
    for (int nt = 0; nt < 4; ++nt) {
      const int e = e0 + nt * 16 + l15;
      const f32x4 hr = *reinterpret_cast<const f32x4*>(&Her[e * DD + d]);
#pragma unroll
      for (int r = 0; r < 4; ++r)
        fs[r] += sigm(acc[mt][nt][r] + bb[r]) * hr[r];
    }
#pragma unroll
    for (int r = 0; r < 4; ++r) {
      float v = fs[r] * hl[r];
      v += __shfl_xor(v, 1);
      v += __shfl_xor(v, 2);
      v += __shfl_xor(v, 4);
      v += __shfl_xor(v, 8);
      if (l15 == 0) atomicAdd(&ftri[p * DD + d + r], v);
    }
  }
}

// ---------------- fused attention kernel: block = (p, 32-row chunk) ----------------

__global__ __launch_bounds__(256, 4) void attn_kernel(
    const unsigned short* __restrict__ Zsw, const float* __restrict__ gv,
    const unsigned short* __restrict__ wpack, float* __restrict__ cbufg) {
  __shared__ __align__(16) unsigned short Tc[32 * 264];
  __shared__ float red[128];
  __shared__ float red2[128];
  const int t = threadIdx.x, lane = t & 63, wv = t >> 6;
  const int l15 = lane & 15, l4 = lane >> 4;
  const int xcd = blockIdx.x & 7, inner = blockIdx.x >> 3;
  const int p = (inner / 12) * 8 + xcd, c = inner % 12;
  const unsigned short* Zsp = Zsw + (size_t)p * 98304;
  const unsigned short* wqk = wpack + 4 * 65536;

  // T' = (Zc @ Wqk + gv) / 16 for 32 rows (groups 2c, 2c+1), double-buffered
  {
    f32x4 ta[4][2];
#pragma unroll
    for (int mt = 0; mt < 4; ++mt)
#pragma unroll
      for (int nt = 0; nt < 2; ++nt) ta[mt][nt] = (f32x4){0.f, 0.f, 0.f, 0.f};
    const unsigned short* Tb = Zsp + (size_t)(c * 2) * 4096 + lane * 8;
    bf16x8 bcur[2], bnxt[2];
#pragma unroll
    for (int nt = 0; nt < 2; ++nt)
      bcur[nt] = *reinterpret_cast<const bf16x8*>(Tb + nt * 4096);
#pragma unroll
    for (int ks = 0; ks < 8; ++ks) {
      if (ks < 7) {
#pragma unroll
        for (int nt = 0; nt < 2; ++nt)
          bnxt[nt] = *reinterpret_cast<const bf16x8*>(Tb + nt * 4096 + (ks + 1) * 512);
      }
      bf16x8 a[4];
#pragma unroll
      for (int mt = 0; mt < 4; ++mt)
        a[mt] = *reinterpret_cast<const bf16x8*>(wqk + ((ks * 16 + wv * 4 + mt) * 64 + lane) * 8);
#pragma unroll
      for (int nt = 0; nt < 2; ++nt)
#pragma unroll
        for (int mt = 0; mt < 4; ++mt)
          ta[mt][nt] = __builtin_amdgcn_mfma_f32_16x16x32_bf16(a[mt], bcur[nt], ta[mt][nt], 0, 0, 0);
      if (ks < 7) {
#pragma unroll
        for (int nt = 0; nt < 2; ++nt) bcur[nt] = bnxt[nt];
      }
    }
#pragma unroll
    for (int mt = 0; mt < 4; ++mt) {
      const int d = wv * 64 + mt * 16 + l4 * 4;
      const f32x4 gq = *reinterpret_cast<const f32x4*>(&gv[d]);
#pragma unroll
      for (int nt = 0; nt < 2; ++nt) {
        const int e = nt * 16 + l15;
        *reinterpret_cast<uint2*>(&Tc[e * 264 + d]) =
            pack4((ta[mt][nt][0] + gq[0]) * 0.0625f, (ta[mt][nt][1] + gq[1]) * 0.0625f,
                  (ta[mt][nt][2] + gq[2]) * 0.0625f, (ta[mt][nt][3] + gq[3]) * 0.0625f);
      }
    }
  }
  __syncthreads();

  // S = Tc @ Z^T; a-frags from LDS, b-frags 3+3 rolling prefetch
  f32x4 sc[2][6];
#pragma unroll
  for (int mt = 0; mt < 2; ++mt)
#pragma unroll
    for (int s = 0; s < 6; ++s) sc[mt][s] = (f32x4){0.f, 0.f, 0.f, 0.f};

  {
    const unsigned short* Sb = Zsp + (size_t)wv * 4096 + lane * 8;
    bf16x8 b0[3], b1[3];
#pragma unroll
    for (int j = 0; j < 3; ++j)
      b0[j] = *reinterpret_cast<const bf16x8*>(Sb + j * 16384);
#pragma unroll
    for (int ks = 0; ks < 8; ++ks) {
#pragma unroll
      for (int j = 0; j < 3; ++j)
        b1[j] = *reinterpret_cast<const bf16x8*>(Sb + (3 + j) * 16384 + ks * 512);
      bf16x8 a[2];
#pragma unroll
      for (int mt = 0; mt < 2; ++mt)
        a[mt] = *reinterpret_cast<const bf16x8*>(&Tc[(mt * 16 + l15) * 264 + ks * 32 + l4 * 8]);
#pragma unroll
      for (int j = 0; j < 3; ++j)
#pragma unroll
        for (int mt = 0; mt < 2; ++mt)
          sc[mt][j] = __builtin_amdgcn_mfma_f32_16x16x32_bf16(a[mt], b0[j], sc[mt][j], 0, 0, 0);
      if (ks < 7) {
#pragma unroll
        for (int j = 0; j < 3; ++j)
          b0[j] = *reinterpret_cast<const bf16x8*>(Sb + j * 16384 + (ks + 1) * 512);
      }
#pragma unroll
      for (int j = 0; j < 3; ++j)
#pragma unroll
        for (int mt = 0; mt < 2; ++mt)
          sc[mt][3 + j] = __builtin_amdgcn_mfma_f32_16x16x32_bf16(a[mt], b1[j], sc[mt][3 + j], 0, 0, 0);
    }
  }

  // softmax over f (384 cols), rows e = mt*16 + l4*4 + r (32 rows)
  float rmax[2][4];
#pragma unroll
  for (int mt = 0; mt < 2; ++mt) {
#pragma unroll
    for (int r = 0; r < 4; ++r) {
      float m = -1e30f;
#pragma unroll
      for (int s = 0; s < 6; ++s) m = fmaxf(m, sc[mt][s][r]);
      m = fmaxf(m, __shfl_xor(m, 1));
      m = fmaxf(m, __shfl_xor(m, 2));
      m = fmaxf(m, __shfl_xor(m, 4));
      m = fmaxf(m, __shfl_xor(m, 8));
      rmax[mt][r] = m;
    }
  }
  if (l15 == 0) {
#pragma unroll
    for (int mt = 0; mt < 2; ++mt)
#pragma unroll
      for (int r = 0; r < 4; ++r)
        red[wv * 32 + mt * 16 + l4 * 4 + r] = rmax[mt][r];
  }
  __syncthreads();
#pragma unroll
  for (int mt = 0; mt < 2; ++mt) {
#pragma unroll
    for (int r = 0; r < 4; ++r) {
      const int row = mt * 16 + l4 * 4 + r;
      rmax[mt][r] = fmaxf(fmaxf(red[row], red[32 + row]), fmaxf(red[64 + row], red[96 + row]));
    }
  }

  float rsum[2][4];
#pragma unroll
  for (int mt = 0; mt < 2; ++mt) {
#pragma unroll
    for (int r = 0; r < 4; ++r) {
      float sSum = 0.f;
#pragma unroll
      for (int s = 0; s < 6; ++s) {
        float e = __expf(sc[mt][s][r] - rmax[mt][r]);
        sc[mt][s][r] = e;
        sSum += e;
      }
      sSum += __shfl_xor(sSum, 1);
      sSum += __shfl_xor(sSum, 2);
      sSum += __shfl_xor(sSum, 4);
      sSum += __shfl_xor(sSum, 8);
      rsum[mt][r] = sSum;
    }
  }
  if (l15 == 0) {
#pragma unroll
    for (int mt = 0; mt < 2; ++mt)
#pragma unroll
      for (int r = 0; r < 4; ++r)
        red2[wv * 32 + mt * 16 + l4 * 4 + r] = rsum[mt][r];
  }
  __syncthreads();
  float rinv[2][4];
#pragma unroll
  for (int mt = 0; mt < 2; ++mt) {
#pragma unroll
    for (int r = 0; r < 4; ++r) {
      const int row = mt * 16 + l4 * 4 + r;
      rinv[mt][r] = 1.0f / (red2[row] + red2[32 + row] + red2[64 + row] + red2[96 + row]);
    }
  }

  // column sums of A over this chunk's 32 rows -> cbufg
#pragma unroll
  for (int s = 0; s < 6; ++s) {
    float v = 0.f;
#pragma unroll
    for (int mt = 0; mt < 2; ++mt)
#pragma unroll
      for (int r = 0; r < 4; ++r)
        v += sc[mt][s][r] * rinv[mt][r];
    v += __shfl_xor(v, 16);
    v += __shfl_xor(v, 32);
    if (lane < 16)
      atomicAdd(&cbufg[p * NEPI + (s * 4 + wv) * 16 + lane], v);
  }
}

// ---------------- output part A: u[p][d] partial over one f-third ----------------

__global__ __launch_bounds__(256) void outa_kernel(
    const unsigned short* __restrict__ Zsw, const float* __restrict__ cbufg,
    float* __restrict__ ubufg) {
  __shared__ float cb[128];
  __shared__ float part[16][257];
  const int p = blockIdx.x / 3, th = blockIdx.x % 3, g0 = th * 8;
  const int t = threadIdx.x;
  const int lane = t & 63, wv = t >> 6;
  const int l15 = lane & 15, l4 = lane >> 4;
  if (t < 128) cb[t] = cbufg[p * NEPI + g0 * 16 + t];
  __syncthreads();
  const unsigned short* Zsp = Zsw + (size_t)p * 98304;
  float a16[16];
#pragma unroll
  for (int j = 0; j < 16; ++j) a16[j] = 0.f;
#pragma unroll
  for (int gr = 0; gr < 8; ++gr) {
    const int grp = g0 + gr;
    const float w = cb[gr * 16 + l15];
    const uint4 z0 = *reinterpret_cast<const uint4*>(Zsp + grp * 4096 + wv * 512 + lane * 8);
    const uint4 z1 = *reinterpret_cast<const uint4*>(Zsp + grp * 4096 + (wv + 4) * 512 + lane * 8);
    a16[0] = fmaf(w, bf2f(z0.x & 0xffffu), a16[0]);
    a16[1] = fmaf(w, bf2f(z0.x >> 16), a16[1]);
    a16[2] = fmaf(w, bf2f(z0.y & 0xffffu), a16[2]);
    a16[3] = fmaf(w, bf2f(z0.y >> 16), a16[3]);
    a16[4] = fmaf(w, bf2f(z0.z & 0xffffu), a16[4]);
    a16[5] = fmaf(w, bf2f(z0.z >> 16), a16[5]);
    a16[6] = fmaf(w, bf2f(z0.w & 0xffffu), a16[6]);
    a16[7] = fmaf(w, bf2f(z0.w >> 16), a16[7]);
    a16[8]  = fmaf(w, bf2f(z1.x & 0xffffu), a16[8]);
    a16[9]  = fmaf(w, bf2f(z1.x >> 16), a16[9]);
    a16[10] = fmaf(w, bf2f(z1.y & 0xffffu), a16[10]);
    a16[11] = fmaf(w, bf2f(z1.y >> 16), a16[11]);
    a16[12] = fmaf(w, bf2f(z1.z & 0xffffu), a16[12]);
    a16[13] = fmaf(w, bf2f(z1.z >> 16), a16[13]);
    a16[14] = fmaf(w, bf2f(z1.w & 0xffffu), a16[14]);
    a16[15] = fmaf(w, bf2f(z1.w >> 16), a16[15]);
  }
#pragma unroll
  for (int j = 0; j < 8; ++j) part[l15][wv * 32 + l4 * 8 + j] = a16[j];
#pragma unroll
  for (int j = 0; j < 8; ++j) part[l15][128 + wv * 32 + l4 * 8 + j] = a16[8 + j];
  __syncthreads();
  float uu = 0.f;
#pragma unroll
  for (int g = 0; g < 16; ++g) uu += part[g][t];
  atomicAdd(&ubufg[p * DD + t], uu);
}

// ---------------- output part B: out[p] = (ftri + u@wv + 384*bv)/384 ----------------

__global__ __launch_bounds__(256) void out2_kernel(
    const float* __restrict__ ubufg, const float* __restrict__ ftri,
    const float* __restrict__ wvw, const float* __restrict__ wvb,
    float* __restrict__ out) {
  __shared__ float u[DD];
  const int p = blockIdx.x, t = threadIdx.x;
  u[t] = ubufg[p * DD + t];
  __syncthreads();
  float acc = ftri[p * DD + t] + 384.0f * wvb[t];
#pragma unroll 8
  for (int d = 0; d < DD; ++d)
    acc = fmaf(u[d], wvw[d * DD + t], acc);
  out[p * DD + t] = acc * (1.0f / 384.0f);
}

// ---------------- launch ----------------

extern "C" void kernel_launch(void* const* d_in, const int* in_sizes, int n_in,
                              void* d_out, int out_size, void* d_ws, size_t ws_size,
                              hipStream_t stream) {
  (void)in_sizes; (void)n_in; (void)out_size; (void)ws_size;
  const float* H = (const float*)d_in[0];
  const float* X = (const float*)d_in[1];
  const float* res_w1 = (const float*)d_in[4];
  const float* res_b1 = (const float*)d_in[5];
  const float* res_w2 = (const float*)d_in[6];
  const float* res_b2 = (const float*)d_in[7];
  const float* atom_w1 = (const float*)d_in[8];
  const float* atom_b1 = (const float*)d_in[9];
  const float* atom_w2 = (const float*)d_in[10];
  const float* atom_b2 = (const float*)d_in[11];
  const float* simw = (const float*)d_in[12];
  const float* int_w1 = (const float*)d_in[13];
  const float* int_b1 = (const float*)d_in[14];
  const float* int_w2 = (const float*)d_in[15];
  const float* int_b2 = (const float*)d_in[16];
  const float* wl = (const float*)d_in[17];
  const float* wr = (const float*)d_in[18];
  const float* wg_w = (const float*)d_in[19];
  const float* wg_b = (const float*)d_in[20];
  const float* wq_w = (const float*)d_in[21];
  const float* wq_b = (const float*)d_in[22];
  const float* wk_w = (const float*)d_in[23];
  const float* wv_w = (const float*)d_in[25];
  const float* wv_b = (const float*)d_in[26];

  char* ws = (char*)d_ws;
  unsigned short* wpack = (unsigned short*)(ws + 0);      //  655360 B (5 slots)
  float* cvec  = (float*)(ws + 655360);                   //    1024 B
  float* gv    = (float*)(ws + 656384);                   //    1024 B
  float* P1    = (float*)(ws + 657408);                   //  393216 B
  float* P2    = (float*)(ws + 1050624);                  //  393216 B
  float* Hpl   = (float*)(ws + 1443840);                  //  393216 B
  float* Her   = (float*)(ws + 1837056);                  //  393216 B
  float* ftri  = (float*)(ws + 2230272);                  //  393216 B
  float* cbufg = (float*)(ws + 2623488);                  //  589824 B
  float* ubufg = (float*)(ws + 3213312);                  //  393216 B
  unsigned short* Zsw = (unsigned short*)(ws + 3606528);  // 75497472 B
  float* tabF  = (float*)(ws + 79104000);                 //  4194304 B (NTAB x 256 fp32)

  hipMemsetAsync(ftri, 0, 393216 + 589824 + 393216, stream);
  prep_kernel<<<1473, 256, 0, stream>>>(H, wl, wr, int_w1, res_w2, atom_w2,
                                        res_b2, atom_b2, int_b1, simw, wq_b, wk_w,
                                        wq_w, int_w2, wg_w,
                                        Hpl, Her, P1, P2, cvec, gv, wpack);
  tab_kernel<<<NTAB / 64, 256, 0, stream>>>(res_w1, res_b1, atom_w1, atom_b1, wpack, tabF);
  pair_kernel<<<2304, 256, 0, stream>>>(X, tabF, int_b2, wg_b, wpack, cvec,
                                        P1, P2, Hpl, Her, ftri, Zsw);
  attn_kernel<<<4608, 256, 0, stream>>>(Zsw, gv, wpack, cbufg);
  outa_kernel<<<1152, 256, 0, stream>>>(Zsw, cbufg, ubufg);
  out2_kernel<<<384, 256, 0, stream>>>(ubufg, ftri, wv_w, wv_b, (float*)d_out);
  hipMemcpyAsync((float*)d_out + NPAR * DD, H + NPAR * DD,
                 (1024 - NPAR) * DD * sizeof(float), hipMemcpyDeviceToDevice, stream);
}